// Round 8
// baseline (464.335 us; speedup 1.0000x reference)
//
#include <hip/hip_runtime.h>
#include <hip/hip_bf16.h>

#define N_NODES 10000
#define N_EDGES 160000
#define D_IN    128
#define D_EMB   512
#define D_HID   256
#define DMAX    512

typedef unsigned short u16;
typedef __attribute__((ext_vector_type(8))) short short8;
typedef __attribute__((ext_vector_type(4))) float floatx4;

__device__ __forceinline__ float bf2f(u16 u) {
    union { unsigned int i; float f; } v; v.i = ((unsigned int)u) << 16; return v.f;
}
__device__ __forceinline__ u16 f2bf(float f) {
    union { float f; unsigned int i; } v; v.f = f;
    unsigned int x = v.i;
    return (u16)((x + 0x7fffu + ((x >> 16) & 1u)) >> 16);  // RNE
}
__device__ __forceinline__ float inval(const void* p, int fp32, int idx) {
    return fp32 ? ((const float*)p)[idx] : bf2f(((const u16*)p)[idx]);
}

// async global->LDS, 16 bytes/lane; lds base must be wave-uniform.
__device__ __forceinline__ void gld_lds16(const u16* g, u16* l) {
    __builtin_amdgcn_global_load_lds((const __attribute__((address_space(1))) void*)g,
                                     (__attribute__((address_space(3))) void*)l,
                                     16, 0, 0);
}

// flag[0]: edge_index is int64-viewed-as-int32-pairs; flag[1]: floats are fp32
__device__ __forceinline__ int edge_src(const int* __restrict__ ei, int flg, int e) {
    int v = flg ? ei[2 * e] : ei[e];
    return min(max(v, 0), N_NODES - 1);
}
__device__ __forceinline__ int edge_dst(const int* __restrict__ ei, int flg, int e) {
    int v = flg ? ei[2 * N_EDGES + 2 * e] : ei[N_EDGES + e];
    return min(max(v, 0), N_NODES - 1);
}

// ---------------------------------------------------------------------------
__global__ void sentinel_kernel(float* out, int n) {
    int i = blockIdx.x * 256 + threadIdx.x;
    if (i < n) out[i] = 1.0f;   // => workspace too small
}

// detect dtypes + zero counts/logits/ghist, one dispatch (block 0 = census)
__global__ __launch_bounds__(256)
void detect_zero_kernel(const int* __restrict__ ei, const u16* __restrict__ xu,
                        int* flag, int* counts, float* logits, int* ghist) {
    int gid = blockIdx.x * 256 + threadIdx.x;
    for (int i = gid; i < N_NODES; i += gridDim.x * 256) { counts[i] = 0; logits[i] = 0.f; }
    for (int i = gid; i < DMAX; i += gridDim.x * 256) ghist[i] = 0;
    if (blockIdx.x != 0) return;
    __shared__ int s_or[256];
    __shared__ int s_cnt[256];
    int t = threadIdx.x;
    int v = 0;
    for (int k = t; k < 4096; k += 256) v |= ei[1 + 2 * k];
    int c = 0;
    for (int k = t; k < 4096; k += 256) {
        u16 u = xu[k];
        int ex = (u >> 7) & 0xFF;
        bool plaus = (u == 0) || (ex >= 64 && ex <= 191);
        if (!plaus) c++;
    }
    s_or[t] = v; s_cnt[t] = c;
    __syncthreads();
    for (int off = 128; off > 0; off >>= 1) {
        if (t < off) { s_or[t] |= s_or[t + off]; s_cnt[t] += s_cnt[t + off]; }
        __syncthreads();
    }
    if (t == 0) {
        flag[0] = (s_or[0] == 0) ? 1 : 0;
        flag[1] = (s_cnt[0] > 256) ? 1 : 0;
    }
}

// ---------------------------------------------------------------------------
// Fused preconversion; dl == nullptr -> hi only.
// ---------------------------------------------------------------------------
struct ConvJobs {
    const void* src[10];
    u16* dh[10];
    u16* dl[10];
    int rows[10], cols[10], trans[10];
    int cum[11];
    int njobs;
};

__global__ __launch_bounds__(256)
void convert_fused_kernel(ConvJobs jobs, const int* __restrict__ flag) {
    int idx = blockIdx.x * 256 + threadIdx.x;
    if (idx >= jobs.cum[jobs.njobs]) return;
    int fp32 = flag[1];
    int jb = 0;
    while (idx >= jobs.cum[jb + 1]) jb++;
    int local = idx - jobs.cum[jb];
    float v = inval(jobs.src[jb], fp32, local);
    u16 hi = f2bf(v);
    int o;
    if (jobs.trans[jb]) {
        int r = local / jobs.cols[jb], c = local % jobs.cols[jb];
        o = c * jobs.rows[jb] + r;
    } else o = local;
    jobs.dh[jb][o] = hi;
    if (jobs.dl[jb]) jobs.dl[jb][o] = f2bf(v - bf2f(hi));
}

// ---------------------------------------------------------------------------
// CSR build
// ---------------------------------------------------------------------------
__global__ void count_edges_kernel(const int* __restrict__ ei, const int* __restrict__ flag,
                                   int* counts) {
    int e = blockIdx.x * 256 + threadIdx.x;
    if (e < N_EDGES) atomicAdd(&counts[edge_dst(ei, flag[0], e)], 1);
}

__global__ __launch_bounds__(256)
void scan_counts_kernel(int* counts, int* rowptr) {
    __shared__ int part[256];
    int tid = threadIdx.x;
    const int CH = 40;
    int base = tid * CH;
    int loc[CH];
    int s = 0;
    #pragma unroll
    for (int i = 0; i < CH; i++) {
        int idx = base + i;
        int c = (idx < N_NODES) ? counts[idx] : 0;
        loc[i] = s; s += c;
    }
    part[tid] = s;
    __syncthreads();
    for (int off = 1; off < 256; off <<= 1) {
        int v = part[tid];
        int add = (tid >= off) ? part[tid - off] : 0;
        __syncthreads();
        part[tid] = v + add;
        __syncthreads();
    }
    int pre = (tid > 0) ? part[tid - 1] : 0;
    #pragma unroll
    for (int i = 0; i < CH; i++) {
        int idx = base + i;
        if (idx < N_NODES) { int v = pre + loc[i]; rowptr[idx] = v; counts[idx] = v; }
    }
    if (tid == 255) rowptr[N_NODES] = part[255];
}

__global__ void fill_esrcp_kernel(const int* __restrict__ ei, const int* __restrict__ flag,
                                  int* counts, int* esrcp) {
    int e = blockIdx.x * 256 + threadIdx.x;
    if (e < N_EDGES) {
        int flg = flag[0];
        int pos = atomicAdd(&counts[edge_dst(ei, flg, e)], 1);
        if (pos >= 0 && pos < N_EDGES) esrcp[pos] = edge_src(ei, flg, e);
    }
}

// ---------------------------------------------------------------------------
// Degree-descending node order (LPT), multi-block (one node per thread).
// ---------------------------------------------------------------------------
__global__ __launch_bounds__(256)
void lpt_hist_kernel(const int* __restrict__ rowptr, int* __restrict__ ghist) {
    __shared__ int lhist[DMAX];
    int t = threadIdx.x;
    for (int d = t; d < DMAX; d += 256) lhist[d] = 0;
    __syncthreads();
    int n = blockIdx.x * 256 + t;
    if (n < N_NODES) {
        int d = min(rowptr[n + 1] - rowptr[n], DMAX - 1);
        atomicAdd(&lhist[d], 1);
    }
    __syncthreads();
    for (int d = t; d < DMAX; d += 256) {
        int c = lhist[d];
        if (c > 0) atomicAdd(&ghist[d], c);
    }
}

// doff[d] = number of nodes with degree > d (descending exclusive scan)
__global__ __launch_bounds__(256)
void lpt_scan_kernel(const int* __restrict__ ghist, int* __restrict__ doff) {
    __shared__ int part[256];
    int t = threadIdx.x;
    int d0 = (DMAX - 1) - 2 * t;        // thread t owns degrees d0, d0-1
    int d1 = d0 - 1;
    int c0 = ghist[d0], c1 = ghist[d1];
    part[t] = c0 + c1;
    __syncthreads();
    for (int o = 1; o < 256; o <<= 1) {
        int v = part[t];
        int add = (t >= o) ? part[t - o] : 0;
        __syncthreads();
        part[t] = v + add;
        __syncthreads();
    }
    int pre = (t > 0) ? part[t - 1] : 0;
    doff[d0] = pre;
    doff[d1] = pre + c0;
}

__global__ __launch_bounds__(256)
void lpt_scatter_kernel(const int* __restrict__ rowptr, int* __restrict__ doff,
                        int* __restrict__ order) {
    __shared__ int lhist[DMAX];
    __shared__ int lbase[DMAX];
    int t = threadIdx.x;
    for (int d = t; d < DMAX; d += 256) lhist[d] = 0;
    __syncthreads();
    int n = blockIdx.x * 256 + t;
    int dg = 0;
    if (n < N_NODES) {
        dg = min(rowptr[n + 1] - rowptr[n], DMAX - 1);
        atomicAdd(&lhist[dg], 1);
    }
    __syncthreads();
    // reserve a contiguous chunk per nonempty bucket; reset lhist for ranking
    for (int d = t; d < DMAX; d += 256) {
        int c = lhist[d];
        lbase[d] = (c > 0) ? atomicAdd(&doff[d], c) : 0;
        lhist[d] = 0;
    }
    __syncthreads();
    if (n < N_NODES) {
        int rank = atomicAdd(&lhist[dg], 1);
        int pos = lbase[dg] + rank;
        if (pos >= 0 && pos < N_NODES) order[pos] = n;
    }
}

// ---------------------------------------------------------------------------
// Dual 128x128-tile GEMM, 2 MFMA passes, async global_load_lds staging,
// XOR-swizzled unpadded LDS. C0 (xl) stored bf16; C1 (xr) stored fp32.
// ---------------------------------------------------------------------------
__global__ __launch_bounds__(256)
void gemm_dual_kernel(const u16* __restrict__ Ah, const u16* __restrict__ Al,
                      const u16* __restrict__ B0h, const u16* __restrict__ B1h,
                      u16* __restrict__ C0, float* __restrict__ C1,
                      int M, int N, int K)
{
    __shared__ u16 sAh[128 * 32];
    __shared__ u16 sAl[128 * 32];
    __shared__ u16 sBh[128 * 32];
    int nb = N >> 7;
    int half = (int)blockIdx.x >= nb;
    int bx = half ? (blockIdx.x - nb) : blockIdx.x;
    const u16* BTh = half ? B1h : B0h;

    int tid = threadIdx.x;
    int lane = tid & 63, wv = tid >> 6;
    int l15 = lane & 15, l4 = lane >> 4;
    int wr = (wv >> 1) * 64, wc = (wv & 1) * 64;
    int m0 = blockIdx.y * 128, n0 = bx * 128;

    int i0 = tid, i1 = tid + 256;
    int r0 = i0 >> 2, b0 = i0 & 3, sb0 = b0 ^ ((r0 >> 1) & 3);
    int r1 = i1 >> 2, b1 = i1 & 3, sb1 = b1 ^ ((r1 >> 1) & 3);
    int gr0 = min(m0 + r0, M - 1), gr1 = min(m0 + r1, M - 1);
    const u16* a0p = Ah + (size_t)gr0 * K + sb0 * 8;
    const u16* a1p = Ah + (size_t)gr1 * K + sb1 * 8;
    const u16* l0p = Al + (size_t)gr0 * K + sb0 * 8;
    const u16* l1p = Al + (size_t)gr1 * K + sb1 * 8;
    const u16* bb0p = BTh + (size_t)(n0 + r0) * K + sb0 * 8;
    const u16* bb1p = BTh + (size_t)(n0 + r1) * K + sb1 * 8;
    u16* lA0 = &sAh[(size_t)(wv * 64) * 8];
    u16* lA1 = &sAh[(size_t)(256 + wv * 64) * 8];
    u16* lL0 = &sAl[(size_t)(wv * 64) * 8];
    u16* lL1 = &sAl[(size_t)(256 + wv * 64) * 8];
    u16* lB0 = &sBh[(size_t)(wv * 64) * 8];
    u16* lB1 = &sBh[(size_t)(256 + wv * 64) * 8];

    floatx4 acc[4][4];
    #pragma unroll
    for (int i = 0; i < 4; i++)
        #pragma unroll
        for (int j = 0; j < 4; j++) acc[i][j] = (floatx4){0.f, 0.f, 0.f, 0.f};

    int aoff[4], boff[4];
    #pragma unroll
    for (int i = 0; i < 4; i++) {
        int arow = wr + i * 16 + l15;
        aoff[i] = arow * 32 + ((l4 ^ ((arow >> 1) & 3)) << 3);
        int bcol = wc + i * 16 + l15;
        boff[i] = bcol * 32 + ((l4 ^ ((bcol >> 1) & 3)) << 3);
    }

    for (int kk = 0; kk < K; kk += 32) {
        __syncthreads();
        gld_lds16(a0p + kk, lA0);
        gld_lds16(a1p + kk, lA1);
        gld_lds16(l0p + kk, lL0);
        gld_lds16(l1p + kk, lL1);
        gld_lds16(bb0p + kk, lB0);
        gld_lds16(bb1p + kk, lB1);
        __syncthreads();

        short8 ah[4], al[4];
        #pragma unroll
        for (int i = 0; i < 4; i++) {
            ah[i] = *(const short8*)(&sAh[aoff[i]]);
            al[i] = *(const short8*)(&sAl[aoff[i]]);
        }
        #pragma unroll
        for (int j = 0; j < 4; j++) {
            short8 bh = *(const short8*)(&sBh[boff[j]]);
            #pragma unroll
            for (int i = 0; i < 4; i++) {
                acc[i][j] = __builtin_amdgcn_mfma_f32_16x16x32_bf16(ah[i], bh, acc[i][j], 0, 0, 0);
                acc[i][j] = __builtin_amdgcn_mfma_f32_16x16x32_bf16(al[i], bh, acc[i][j], 0, 0, 0);
            }
        }
    }

    #pragma unroll
    for (int j = 0; j < 4; j++) {
        int col = n0 + wc + j * 16 + l15;
        #pragma unroll
        for (int i = 0; i < 4; i++) {
            #pragma unroll
            for (int r = 0; r < 4; r++) {
                int row = m0 + wr + i * 16 + l4 * 4 + r;
                if (row < M) {
                    if (half) C1[(size_t)row * N + col] = acc[i][j][r];
                    else      C0[(size_t)row * N + col] = f2bf(acc[i][j][r]);
                }
            }
        }
    }
}

// ---------------------------------------------------------------------------
// MLP GEMM, 64x64 tile, async staging + swizzle, bias+leaky.
// FUSE=0: store hi/lo pair. FUSE=1: fused logit GEMV via atomics (no stores).
// (c3 dropped: softmax is shift-invariant.)
// ---------------------------------------------------------------------------
template<int FUSE>
__global__ __launch_bounds__(256)
void gemm_mlp64_kernel(const u16* __restrict__ Ah, const u16* __restrict__ Al,
                       const u16* __restrict__ BTh,
                       u16* __restrict__ Ch, u16* __restrict__ Cl,
                       const void* __restrict__ biasraw,
                       const void* __restrict__ A3raw, float* __restrict__ logits,
                       const int* __restrict__ flag,
                       int M, int N, int K)
{
    __shared__ u16 sAh[64 * 32];
    __shared__ u16 sAl[64 * 32];
    __shared__ u16 sBh[64 * 32];
    int tid = threadIdx.x;
    int lane = tid & 63, wv = tid >> 6;
    int l15 = lane & 15, l4 = lane >> 4;
    int m0 = blockIdx.y * 64, n0 = blockIdx.x * 64;

    int r = (tid >> 2), blk = tid & 3, sb = blk ^ ((r >> 1) & 3);
    int gr = min(m0 + r, M - 1);
    const u16* ap = Ah + (size_t)gr * K + sb * 8;
    const u16* lp = Al + (size_t)gr * K + sb * 8;
    const u16* bp = BTh + (size_t)(n0 + r) * K + sb * 8;
    u16* lA = &sAh[(size_t)(wv * 64) * 8];
    u16* lL = &sAl[(size_t)(wv * 64) * 8];
    u16* lB = &sBh[(size_t)(wv * 64) * 8];

    floatx4 acc[4];
    #pragma unroll
    for (int j = 0; j < 4; j++) acc[j] = (floatx4){0.f, 0.f, 0.f, 0.f};

    int arow = wv * 16 + l15;
    int aoff = arow * 32 + ((l4 ^ ((arow >> 1) & 3)) << 3);
    int boff[4];
    #pragma unroll
    for (int j = 0; j < 4; j++) {
        int bcol = j * 16 + l15;
        boff[j] = bcol * 32 + ((l4 ^ ((bcol >> 1) & 3)) << 3);
    }

    for (int kk = 0; kk < K; kk += 32) {
        __syncthreads();
        gld_lds16(ap + kk, lA);
        gld_lds16(lp + kk, lL);
        gld_lds16(bp + kk, lB);
        __syncthreads();

        short8 ah = *(const short8*)(&sAh[aoff]);
        short8 al = *(const short8*)(&sAl[aoff]);
        #pragma unroll
        for (int j = 0; j < 4; j++) {
            short8 bh = *(const short8*)(&sBh[boff[j]]);
            acc[j] = __builtin_amdgcn_mfma_f32_16x16x32_bf16(ah, bh, acc[j], 0, 0, 0);
            acc[j] = __builtin_amdgcn_mfma_f32_16x16x32_bf16(al, bh, acc[j], 0, 0, 0);
        }
    }

    const int fp32 = flag[1];
    float lsum[4] = {0.f, 0.f, 0.f, 0.f};
    #pragma unroll
    for (int j = 0; j < 4; j++) {
        int col = n0 + j * 16 + l15;
        float bv = inval(biasraw, fp32, col);
        float a3 = FUSE ? inval(A3raw, fp32, col) : 0.f;
        #pragma unroll
        for (int rr = 0; rr < 4; rr++) {
            int row = m0 + wv * 16 + l4 * 4 + rr;
            if (row < M) {
                float v = acc[j][rr] + bv;
                v = v > 0.f ? v : 0.1f * v;
                if (FUSE) {
                    lsum[rr] += v * a3;
                } else {
                    u16 hi = f2bf(v);
                    Ch[(size_t)row * N + col] = hi;
                    Cl[(size_t)row * N + col] = f2bf(v - bf2f(hi));
                }
            }
        }
    }
    if (FUSE) {
        #pragma unroll
        for (int rr = 0; rr < 4; rr++) {
            float s = lsum[rr];
            s += __shfl_xor(s, 1);
            s += __shfl_xor(s, 2);
            s += __shfl_xor(s, 4);
            s += __shfl_xor(s, 8);
            int row = m0 + wv * 16 + l4 * 4 + rr;
            if (l15 == 0 && row < M) atomicAdd(&logits[row], s);
        }
    }
}

// ---------------------------------------------------------------------------
// GATv2, R21: TWO independent chains per wave (nodes from LPT slots 2i, 2i+1,
// similar degree). One-fill regime => ILP is the only lever: while chain A
// waits on its gathers, chain B's compute issues from the SAME wave. Each
// chain keeps the R18 depth-1 register pipeline + masked padding.
// ---------------------------------------------------------------------------
__global__ __launch_bounds__(256)
void gat_wave_kernel(const int* __restrict__ rowptr, const int* __restrict__ esrcp,
                     const int* __restrict__ order,
                     const u16* __restrict__ xlb, const float* __restrict__ xr,
                     const void* __restrict__ att, const void* __restrict__ bias,
                     const int* __restrict__ flag,
                     u16* __restrict__ hh, u16* __restrict__ hl)
{
    int lane = threadIdx.x & 63, wv = threadIdx.x >> 6;
    int slot0 = blockIdx.x * 8 + wv * 2;
    if (slot0 >= N_NODES) return;
    int slot1 = slot0 + 1;
    bool hasB = (slot1 < N_NODES);

    int nA = min(max(order[slot0], 0), N_NODES - 1);
    int nB = hasB ? min(max(order[slot1], 0), N_NODES - 1) : nA;

    int fp32 = flag[1];
    int d0 = lane * 8;
    int l3 = lane & 3;
    const u16* xbase = xlb + d0;        // lane's 16B chunk within any row

    int begA = rowptr[nA], endA = rowptr[nA + 1];
    int begB = 0, endB = 0;
    if (hasB) { begB = rowptr[nB]; endB = rowptr[nB + 1]; }
    int ngA = (endA - begA + 3) >> 2;
    int ngB = (endB - begB + 3) >> 2;

    // xr rows for both chains (issue early, independent)
    const float* xrrA = xr + (size_t)nA * D_EMB;
    const float* xrrB = xr + (size_t)nB * D_EMB;
    float4 a0 = *(const float4*)(xrrA + d0);
    float4 a1 = *(const float4*)(xrrA + d0 + 4);
    float4 b0v = *(const float4*)(xrrB + d0);
    float4 b1v = *(const float4*)(xrrB + d0 + 4);
    float xrvA[8] = {a0.x, a0.y, a0.z, a0.w, a1.x, a1.y, a1.z, a1.w};
    float xrvB[8] = {b0v.x, b0v.y, b0v.z, b0v.w, b1v.x, b1v.y, b1v.z, b1v.w};
    float attv[8];
    #pragma unroll
    for (int k = 0; k < 8; k++) attv[k] = inval(att, fp32, d0 + k);

    float mA = -3.4e38f, sA = 0.f, mB = -3.4e38f, sB = 0.f;
    float accA[8] = {0.f, 0.f, 0.f, 0.f, 0.f, 0.f, 0.f, 0.f};
    float accB[8] = {0.f, 0.f, 0.f, 0.f, 0.f, 0.f, 0.f, 0.f};

    auto ldidx = [&](int beg, int g) -> int {
        return esrcp[min(beg + 4 * g + l3, N_EDGES - 1)];
    };
    auto gather = [&](uint4* C, int iv) {
        int s0 = __shfl(iv, 0), s1 = __shfl(iv, 1), s2 = __shfl(iv, 2), s3 = __shfl(iv, 3);
        C[0] = *(const uint4*)(xbase + (size_t)s0 * D_EMB);
        C[1] = *(const uint4*)(xbase + (size_t)s1 * D_EMB);
        C[2] = *(const uint4*)(xbase + (size_t)s2 * D_EMB);
        C[3] = *(const uint4*)(xbase + (size_t)s3 * D_EMB);
    };
    auto dotgrp = [&](const uint4* C, const float* xrv, int beg, int end, int g,
                      float& m_run, float& s_run, float* acc) {
        union { uint4 q; u16 us[8]; } u0, u1, u2, u3;
        u0.q = C[0]; u1.q = C[1]; u2.q = C[2]; u3.q = C[3];
        float v0[8], v1[8], v2[8], v3[8];
        #pragma unroll
        for (int k = 0; k < 8; k++) {
            v0[k] = bf2f(u0.us[k]); v1[k] = bf2f(u1.us[k]);
            v2[k] = bf2f(u2.us[k]); v3[k] = bf2f(u3.us[k]);
        }
        float e0 = 0.f, e1 = 0.f, e2 = 0.f, e3 = 0.f;
        #pragma unroll
        for (int k = 0; k < 8; k++) {
            float t0 = v0[k] + xrv[k]; t0 = fmaxf(t0, 0.2f * t0); e0 += attv[k] * t0;
            float t1 = v1[k] + xrv[k]; t1 = fmaxf(t1, 0.2f * t1); e1 += attv[k] * t1;
            float t2 = v2[k] + xrv[k]; t2 = fmaxf(t2, 0.2f * t2); e2 += attv[k] * t2;
            float t3 = v3[k] + xrv[k]; t3 = fmaxf(t3, 0.2f * t3); e3 += attv[k] * t3;
        }
        #pragma unroll
        for (int o = 32; o > 0; o >>= 1) {
            e0 += __shfl_xor(e0, o);
            e1 += __shfl_xor(e1, o);
            e2 += __shfl_xor(e2, o);
            e3 += __shfl_xor(e3, o);
        }
        int base = beg + 4 * g;         // mask padded (dead) edges
        if (base + 1 >= end) e1 = -3.4e38f;
        if (base + 2 >= end) e2 = -3.4e38f;
        if (base + 3 >= end) e3 = -3.4e38f;
        float m4 = fmaxf(fmaxf(e0, e1), fmaxf(e2, e3));
        float m_new = fmaxf(m_run, m4);
        float sc = __expf(m_run - m_new);   // 0 on first group
        float w0 = __expf(e0 - m_new), w1 = __expf(e1 - m_new);
        float w2 = __expf(e2 - m_new), w3 = __expf(e3 - m_new);
        s_run = s_run * sc + (w0 + w1) + (w2 + w3);
        #pragma unroll
        for (int k = 0; k < 8; k++)
            acc[k] = acc[k] * sc + w0 * v0[k] + w1 * v1[k] + w2 * v2[k] + w3 * v3[k];
        m_run = m_new;
    };

    uint4 A[4], B[4];
    // prologue: both chains' idx + gathers in flight before any compute
    int i0A = (ngA > 0) ? ldidx(begA, 0) : 0;
    int i0B = (ngB > 0) ? ldidx(begB, 0) : 0;
    if (ngA > 0) gather(A, i0A);
    if (ngB > 0) gather(B, i0B);
    int nidxA = (ngA > 1) ? ldidx(begA, 1) : 0;
    int nidxB = (ngB > 1) ? ldidx(begB, 1) : 0;

    int gmax = max(ngA, ngB);
    for (int g = 0; g < gmax; g++) {
        uint4 NA[4], NB[4];
        bool nextA = (g + 1 < ngA), nextB = (g + 1 < ngB);
        // issue next-group gathers for BOTH chains first: their latency is
        // covered by BOTH computes below (~2x the cover of one chain).
        if (nextA) gather(NA, nidxA);
        if (nextB) gather(NB, nidxB);
        if (g + 2 < ngA) nidxA = ldidx(begA, g + 2);
        if (g + 2 < ngB) nidxB = ldidx(begB, g + 2);
        if (g < ngA) dotgrp(A, xrvA, begA, endA, g, mA, sA, accA);
        if (g < ngB) dotgrp(B, xrvB, begB, endB, g, mB, sB, accB);
        if (nextA) { A[0] = NA[0]; A[1] = NA[1]; A[2] = NA[2]; A[3] = NA[3]; }
        if (nextB) { B[0] = NB[0]; B[1] = NB[1]; B[2] = NB[2]; B[3] = NB[3]; }
    }

    // epilogue: finalize both chains
    {
        float inv = 1.f / (sA + 1e-16f);
        union { uint4 q; u16 us[8]; } ph, pl;
        #pragma unroll
        for (int k = 0; k < 8; k++) {
            float h = tanhf(accA[k] * inv + inval(bias, fp32, d0 + k));
            u16 hi = f2bf(h);
            ph.us[k] = hi;
            pl.us[k] = f2bf(h - bf2f(hi));
        }
        *(uint4*)(&hh[(size_t)nA * D_EMB + d0]) = ph.q;
        *(uint4*)(&hl[(size_t)nA * D_EMB + d0]) = pl.q;
    }
    if (hasB) {
        float inv = 1.f / (sB + 1e-16f);
        union { uint4 q; u16 us[8]; } ph, pl;
        #pragma unroll
        for (int k = 0; k < 8; k++) {
            float h = tanhf(accB[k] * inv + inval(bias, fp32, d0 + k));
            u16 hi = f2bf(h);
            ph.us[k] = hi;
            pl.us[k] = f2bf(h - bf2f(hi));
        }
        *(uint4*)(&hh[(size_t)nB * D_EMB + d0]) = ph.q;
        *(uint4*)(&hl[(size_t)nB * D_EMB + d0]) = pl.q;
    }
}

// ---------------------------------------------------------------------------
__global__ __launch_bounds__(256)
void softmax_kernel(const float* __restrict__ logits, float* __restrict__ out)
{
    __shared__ float red[4];
    __shared__ float s_m, s_s;
    int tid = threadIdx.x, lane = tid & 63, wv = tid >> 6;
    float m = -3.4e38f;
    for (int i = tid; i < N_NODES; i += 256) m = fmaxf(m, logits[i]);
    #pragma unroll
    for (int o = 32; o > 0; o >>= 1) m = fmaxf(m, __shfl_down(m, o));
    if (lane == 0) red[wv] = m;
    __syncthreads();
    if (tid == 0) {
        float mm = red[0];
        for (int i = 1; i < 4; i++) mm = fmaxf(mm, red[i]);
        s_m = mm;
    }
    __syncthreads();
    float mm = s_m;
    float s = 0.f;
    for (int i = tid; i < N_NODES; i += 256) s += __expf(logits[i] - mm);
    #pragma unroll
    for (int o = 32; o > 0; o >>= 1) s += __shfl_down(s, o);
    if (lane == 0) red[wv] = s;
    __syncthreads();
    if (tid == 0) {
        float ss = 0.f;
        for (int i = 0; i < 4; i++) ss += red[i];
        s_s = ss;
    }
    __syncthreads();
    float invs = 1.f / s_s;
    for (int i = tid; i < N_NODES; i += 256) out[i] = __expf(logits[i] - mm) * invs;
}

// ---------------------------------------------------------------------------
extern "C" void kernel_launch(void* const* d_in, const int* in_sizes, int n_in,
                              void* d_out, int out_size, void* d_ws, size_t ws_size,
                              hipStream_t stream)
{
    const void* x   = d_in[0];
    const int*  ei  = (const int*)d_in[1];
    const void* Wl[3]  = {d_in[2],  d_in[6],  d_in[10]};
    const void* Wr[3]  = {d_in[3],  d_in[7],  d_in[11]};
    const void* att[3] = {d_in[4],  d_in[8],  d_in[12]};
    const void* bia[3] = {d_in[5],  d_in[9],  d_in[13]};
    const void* A1 = d_in[14];
    const void* c1 = d_in[15];
    const void* A2 = d_in[16];
    const void* c2 = d_in[17];
    const void* A3 = d_in[18];

    char* p = (char*)d_ws;
    auto alloc = [&](size_t bytes) {
        char* r = p;
        p += (bytes + 255) & ~(size_t)255;
        return r;
    };
    u16*   xlb    = (u16*)  alloc((size_t)N_NODES * D_EMB * 4);   // bf16 xl (first half) + MLP aliases
    float* xr     = (float*)alloc((size_t)N_NODES * D_EMB * 4);
    u16*   hh     = (u16*)  alloc((size_t)N_NODES * D_EMB * 2);
    u16*   hl     = (u16*)  alloc((size_t)N_NODES * D_EMB * 2);
    int*   esrcp  = (int*)  alloc((size_t)N_EDGES * 4);
    int*   rowptr = (int*)  alloc((size_t)(N_NODES + 1) * 4);
    int*   counts = (int*)  alloc((size_t)N_NODES * 4);
    int*   flag   = (int*)  alloc(256);
    float* logits = (float*)alloc((size_t)N_NODES * 4);
    int*   ghist  = (int*)  alloc(DMAX * 4);
    int*   doff   = (int*)  alloc(DMAX * 4);
    int*   order  = (int*)  alloc((size_t)N_NODES * 4);
    u16* wl1h = (u16*)alloc(D_EMB * D_IN  * 2);
    u16* wr1h = (u16*)alloc(D_EMB * D_IN  * 2);
    u16* wl2h = (u16*)alloc(D_EMB * D_EMB * 2);
    u16* wr2h = (u16*)alloc(D_EMB * D_EMB * 2);
    u16* wl3h = (u16*)alloc(D_EMB * D_EMB * 2);
    u16* wr3h = (u16*)alloc(D_EMB * D_EMB * 2);
    u16* a1h  = (u16*)alloc(D_EMB * D_HID * 2);
    u16* a2h  = (u16*)alloc(D_HID * D_HID * 2);
    u16* xph  = (u16*)alloc((size_t)N_NODES * D_IN * 2);
    u16* xpl  = (u16*)alloc((size_t)N_NODES * D_IN * 2);
    size_t needed = (size_t)(p - (char*)d_ws);

    if (ws_size < needed) {
        sentinel_kernel<<<(out_size + 255) / 256, 256, 0, stream>>>((float*)d_out, out_size);
        return;
    }

    u16* m1h = (u16*)xlb;
    u16* m1l = (u16*)((char*)xlb + 5120000);

    // detect + zero counts/logits/ghist fused
    detect_zero_kernel<<<40, 256, 0, stream>>>(ei, (const u16*)x, flag, counts, logits, ghist);
    count_edges_kernel<<<(N_EDGES + 255) / 256, 256, 0, stream>>>(ei, flag, counts);
    scan_counts_kernel<<<1, 256, 0, stream>>>(counts, rowptr);
    fill_esrcp_kernel<<<(N_EDGES + 255) / 256, 256, 0, stream>>>(ei, flag, counts, esrcp);

    // LPT node order, multi-block (one node per thread; reused by all 3 layers)
    int nblk = (N_NODES + 255) / 256;
    lpt_hist_kernel<<<nblk, 256, 0, stream>>>(rowptr, ghist);
    lpt_scan_kernel<<<1, 256, 0, stream>>>(ghist, doff);
    lpt_scatter_kernel<<<nblk, 256, 0, stream>>>(rowptr, doff, order);

    // fused preconversion: x -> hi/lo; weights -> hi only (transposed)
    ConvJobs jobs;
    auto setjob = [&](int i, const void* s, u16* dh, u16* dl, int r, int c, int tr) {
        jobs.src[i] = s; jobs.dh[i] = dh; jobs.dl[i] = dl;
        jobs.rows[i] = r; jobs.cols[i] = c; jobs.trans[i] = tr;
    };
    setjob(0, x,     xph,  xpl,     N_NODES, D_IN, 0);
    setjob(1, Wl[0], wl1h, nullptr, D_IN,  D_EMB, 1);
    setjob(2, Wr[0], wr1h, nullptr, D_IN,  D_EMB, 1);
    setjob(3, Wl[1], wl2h, nullptr, D_EMB, D_EMB, 1);
    setjob(4, Wr[1], wr2h, nullptr, D_EMB, D_EMB, 1);
    setjob(5, Wl[2], wl3h, nullptr, D_EMB, D_EMB, 1);
    setjob(6, Wr[2], wr3h, nullptr, D_EMB, D_EMB, 1);
    setjob(7, A1,    a1h,  nullptr, D_EMB, D_HID, 1);
    setjob(8, A2,    a2h,  nullptr, D_HID, D_HID, 1);
    jobs.njobs = 9;
    jobs.cum[0] = 0;
    for (int i = 0; i < 9; i++) jobs.cum[i + 1] = jobs.cum[i] + jobs.rows[i] * jobs.cols[i];
    int ctotal = jobs.cum[9];
    convert_fused_kernel<<<(ctotal + 255) / 256, 256, 0, stream>>>(jobs, flag);

    dim3 gdual(2 * D_EMB / 128, (N_NODES + 127) / 128);   // (8, 79)
    dim3 gmlp64(D_HID / 64, (N_NODES + 63) / 64);         // (4, 157)
    int gatgrid = (N_NODES + 7) / 8;                      // 2 nodes per wave

    // layer 1
    gemm_dual_kernel<<<gdual, 256, 0, stream>>>(xph, xpl, wl1h, wr1h, xlb, xr, N_NODES, D_EMB, D_IN);
    gat_wave_kernel<<<gatgrid, 256, 0, stream>>>(rowptr, esrcp, order, xlb, xr, att[0], bia[0], flag, hh, hl);
    // layer 2
    gemm_dual_kernel<<<gdual, 256, 0, stream>>>(hh, hl, wl2h, wr2h, xlb, xr, N_NODES, D_EMB, D_EMB);
    gat_wave_kernel<<<gatgrid, 256, 0, stream>>>(rowptr, esrcp, order, xlb, xr, att[1], bia[1], flag, hh, hl);
    // layer 3
    gemm_dual_kernel<<<gdual, 256, 0, stream>>>(hh, hl, wl3h, wr3h, xlb, xr, N_NODES, D_EMB, D_EMB);
    gat_wave_kernel<<<gatgrid, 256, 0, stream>>>(rowptr, esrcp, order, xlb, xr, att[2], bia[2], flag, hh, hl);

    // MLP: GEMM1 stores pair; GEMM2 fuses the A3 logit GEMV via atomics
    gemm_mlp64_kernel<0><<<gmlp64, 256, 0, stream>>>(hh, hl, a1h, m1h, m1l, c1, nullptr, nullptr, flag, N_NODES, D_HID, D_EMB);
    gemm_mlp64_kernel<1><<<gmlp64, 256, 0, stream>>>(m1h, m1l, a2h, nullptr, nullptr, c2, A3, logits, flag, N_NODES, D_HID, D_HID);
    softmax_kernel<<<1, 256, 0, stream>>>(logits, (float*)d_out);
}

// Round 9
// 421.432 us; speedup vs baseline: 1.1018x; 1.1018x over previous
//
#include <hip/hip_runtime.h>
#include <hip/hip_bf16.h>

#define N_NODES 10000
#define N_EDGES 160000
#define D_IN    128
#define D_EMB   512
#define D_HID   256
#define DMAX    512

typedef unsigned short u16;
typedef __attribute__((ext_vector_type(8))) short short8;
typedef __attribute__((ext_vector_type(4))) float floatx4;

__device__ __forceinline__ float bf2f(u16 u) {
    union { unsigned int i; float f; } v; v.i = ((unsigned int)u) << 16; return v.f;
}
__device__ __forceinline__ u16 f2bf(float f) {
    union { float f; unsigned int i; } v; v.f = f;
    unsigned int x = v.i;
    return (u16)((x + 0x7fffu + ((x >> 16) & 1u)) >> 16);  // RNE
}
__device__ __forceinline__ float inval(const void* p, int fp32, int idx) {
    return fp32 ? ((const float*)p)[idx] : bf2f(((const u16*)p)[idx]);
}

// async global->LDS, 16 bytes/lane; lds base must be wave-uniform.
__device__ __forceinline__ void gld_lds16(const u16* g, u16* l) {
    __builtin_amdgcn_global_load_lds((const __attribute__((address_space(1))) void*)g,
                                     (__attribute__((address_space(3))) void*)l,
                                     16, 0, 0);
}

// flag[0]: edge_index is int64-viewed-as-int32-pairs; flag[1]: floats are fp32
__device__ __forceinline__ int edge_src(const int* __restrict__ ei, int flg, int e) {
    int v = flg ? ei[2 * e] : ei[e];
    return min(max(v, 0), N_NODES - 1);
}
__device__ __forceinline__ int edge_dst(const int* __restrict__ ei, int flg, int e) {
    int v = flg ? ei[2 * N_EDGES + 2 * e] : ei[N_EDGES + e];
    return min(max(v, 0), N_NODES - 1);
}

// ---------------------------------------------------------------------------
__global__ void sentinel_kernel(float* out, int n) {
    int i = blockIdx.x * 256 + threadIdx.x;
    if (i < n) out[i] = 1.0f;   // => workspace too small
}

// detect dtypes + zero counts/logits/ghist, one dispatch (block 0 = census)
__global__ __launch_bounds__(256)
void detect_zero_kernel(const int* __restrict__ ei, const u16* __restrict__ xu,
                        int* flag, int* counts, float* logits, int* ghist) {
    int gid = blockIdx.x * 256 + threadIdx.x;
    for (int i = gid; i < N_NODES; i += gridDim.x * 256) { counts[i] = 0; logits[i] = 0.f; }
    for (int i = gid; i < DMAX; i += gridDim.x * 256) ghist[i] = 0;
    if (blockIdx.x != 0) return;
    __shared__ int s_or[256];
    __shared__ int s_cnt[256];
    int t = threadIdx.x;
    int v = 0;
    for (int k = t; k < 4096; k += 256) v |= ei[1 + 2 * k];
    int c = 0;
    for (int k = t; k < 4096; k += 256) {
        u16 u = xu[k];
        int ex = (u >> 7) & 0xFF;
        bool plaus = (u == 0) || (ex >= 64 && ex <= 191);
        if (!plaus) c++;
    }
    s_or[t] = v; s_cnt[t] = c;
    __syncthreads();
    for (int off = 128; off > 0; off >>= 1) {
        if (t < off) { s_or[t] |= s_or[t + off]; s_cnt[t] += s_cnt[t + off]; }
        __syncthreads();
    }
    if (t == 0) {
        flag[0] = (s_or[0] == 0) ? 1 : 0;
        flag[1] = (s_cnt[0] > 256) ? 1 : 0;
    }
}

// ---------------------------------------------------------------------------
// Fused preconversion; dl == nullptr -> hi only.
// ---------------------------------------------------------------------------
struct ConvJobs {
    const void* src[10];
    u16* dh[10];
    u16* dl[10];
    int rows[10], cols[10], trans[10];
    int cum[11];
    int njobs;
};

__global__ __launch_bounds__(256)
void convert_fused_kernel(ConvJobs jobs, const int* __restrict__ flag) {
    int idx = blockIdx.x * 256 + threadIdx.x;
    if (idx >= jobs.cum[jobs.njobs]) return;
    int fp32 = flag[1];
    int jb = 0;
    while (idx >= jobs.cum[jb + 1]) jb++;
    int local = idx - jobs.cum[jb];
    float v = inval(jobs.src[jb], fp32, local);
    u16 hi = f2bf(v);
    int o;
    if (jobs.trans[jb]) {
        int r = local / jobs.cols[jb], c = local % jobs.cols[jb];
        o = c * jobs.rows[jb] + r;
    } else o = local;
    jobs.dh[jb][o] = hi;
    if (jobs.dl[jb]) jobs.dl[jb][o] = f2bf(v - bf2f(hi));
}

// ---------------------------------------------------------------------------
// CSR build
// ---------------------------------------------------------------------------
__global__ void count_edges_kernel(const int* __restrict__ ei, const int* __restrict__ flag,
                                   int* counts) {
    int e = blockIdx.x * 256 + threadIdx.x;
    if (e < N_EDGES) atomicAdd(&counts[edge_dst(ei, flag[0], e)], 1);
}

__global__ __launch_bounds__(256)
void scan_counts_kernel(int* counts, int* rowptr) {
    __shared__ int part[256];
    int tid = threadIdx.x;
    const int CH = 40;
    int base = tid * CH;
    int loc[CH];
    int s = 0;
    #pragma unroll
    for (int i = 0; i < CH; i++) {
        int idx = base + i;
        int c = (idx < N_NODES) ? counts[idx] : 0;
        loc[i] = s; s += c;
    }
    part[tid] = s;
    __syncthreads();
    for (int off = 1; off < 256; off <<= 1) {
        int v = part[tid];
        int add = (tid >= off) ? part[tid - off] : 0;
        __syncthreads();
        part[tid] = v + add;
        __syncthreads();
    }
    int pre = (tid > 0) ? part[tid - 1] : 0;
    #pragma unroll
    for (int i = 0; i < CH; i++) {
        int idx = base + i;
        if (idx < N_NODES) { int v = pre + loc[i]; rowptr[idx] = v; counts[idx] = v; }
    }
    if (tid == 255) rowptr[N_NODES] = part[255];
}

__global__ void fill_esrcp_kernel(const int* __restrict__ ei, const int* __restrict__ flag,
                                  int* counts, int* esrcp) {
    int e = blockIdx.x * 256 + threadIdx.x;
    if (e < N_EDGES) {
        int flg = flag[0];
        int pos = atomicAdd(&counts[edge_dst(ei, flg, e)], 1);
        if (pos >= 0 && pos < N_EDGES) esrcp[pos] = edge_src(ei, flg, e);
    }
}

// ---------------------------------------------------------------------------
// Degree-descending node order (LPT), multi-block (one node per thread).
// ---------------------------------------------------------------------------
__global__ __launch_bounds__(256)
void lpt_hist_kernel(const int* __restrict__ rowptr, int* __restrict__ ghist) {
    __shared__ int lhist[DMAX];
    int t = threadIdx.x;
    for (int d = t; d < DMAX; d += 256) lhist[d] = 0;
    __syncthreads();
    int n = blockIdx.x * 256 + t;
    if (n < N_NODES) {
        int d = min(rowptr[n + 1] - rowptr[n], DMAX - 1);
        atomicAdd(&lhist[d], 1);
    }
    __syncthreads();
    for (int d = t; d < DMAX; d += 256) {
        int c = lhist[d];
        if (c > 0) atomicAdd(&ghist[d], c);
    }
}

// doff[d] = number of nodes with degree > d (descending exclusive scan)
__global__ __launch_bounds__(256)
void lpt_scan_kernel(const int* __restrict__ ghist, int* __restrict__ doff) {
    __shared__ int part[256];
    int t = threadIdx.x;
    int d0 = (DMAX - 1) - 2 * t;        // thread t owns degrees d0, d0-1
    int d1 = d0 - 1;
    int c0 = ghist[d0], c1 = ghist[d1];
    part[t] = c0 + c1;
    __syncthreads();
    for (int o = 1; o < 256; o <<= 1) {
        int v = part[t];
        int add = (t >= o) ? part[t - o] : 0;
        __syncthreads();
        part[t] = v + add;
        __syncthreads();
    }
    int pre = (t > 0) ? part[t - 1] : 0;
    doff[d0] = pre;
    doff[d1] = pre + c0;
}

__global__ __launch_bounds__(256)
void lpt_scatter_kernel(const int* __restrict__ rowptr, int* __restrict__ doff,
                        int* __restrict__ order) {
    __shared__ int lhist[DMAX];
    __shared__ int lbase[DMAX];
    int t = threadIdx.x;
    for (int d = t; d < DMAX; d += 256) lhist[d] = 0;
    __syncthreads();
    int n = blockIdx.x * 256 + t;
    int dg = 0;
    if (n < N_NODES) {
        dg = min(rowptr[n + 1] - rowptr[n], DMAX - 1);
        atomicAdd(&lhist[dg], 1);
    }
    __syncthreads();
    // reserve a contiguous chunk per nonempty bucket; reset lhist for ranking
    for (int d = t; d < DMAX; d += 256) {
        int c = lhist[d];
        lbase[d] = (c > 0) ? atomicAdd(&doff[d], c) : 0;
        lhist[d] = 0;
    }
    __syncthreads();
    if (n < N_NODES) {
        int rank = atomicAdd(&lhist[dg], 1);
        int pos = lbase[dg] + rank;
        if (pos >= 0 && pos < N_NODES) order[pos] = n;
    }
}

// ---------------------------------------------------------------------------
// Dual 128x128-tile GEMM. R22: TWO K-steps per barrier pair (2 LDS buffer
// sets, 48KB total) — halves the vmcnt(0)-drain barrier count, deepens the
// global_load_lds prefetch window. Swizzle math per set unchanged.
// ---------------------------------------------------------------------------
__global__ __launch_bounds__(256)
void gemm_dual_kernel(const u16* __restrict__ Ah, const u16* __restrict__ Al,
                      const u16* __restrict__ B0h, const u16* __restrict__ B1h,
                      u16* __restrict__ C0, float* __restrict__ C1,
                      int M, int N, int K)
{
    __shared__ u16 sAh[2][128 * 32];
    __shared__ u16 sAl[2][128 * 32];
    __shared__ u16 sBh[2][128 * 32];
    int nb = N >> 7;
    int half = (int)blockIdx.x >= nb;
    int bx = half ? (blockIdx.x - nb) : blockIdx.x;
    const u16* BTh = half ? B1h : B0h;

    int tid = threadIdx.x;
    int lane = tid & 63, wv = tid >> 6;
    int l15 = lane & 15, l4 = lane >> 4;
    int wr = (wv >> 1) * 64, wc = (wv & 1) * 64;
    int m0 = blockIdx.y * 128, n0 = bx * 128;

    int i0 = tid, i1 = tid + 256;
    int r0 = i0 >> 2, b0 = i0 & 3, sb0 = b0 ^ ((r0 >> 1) & 3);
    int r1 = i1 >> 2, b1 = i1 & 3, sb1 = b1 ^ ((r1 >> 1) & 3);
    int gr0 = min(m0 + r0, M - 1), gr1 = min(m0 + r1, M - 1);
    const u16* a0p = Ah + (size_t)gr0 * K + sb0 * 8;
    const u16* a1p = Ah + (size_t)gr1 * K + sb1 * 8;
    const u16* l0p = Al + (size_t)gr0 * K + sb0 * 8;
    const u16* l1p = Al + (size_t)gr1 * K + sb1 * 8;
    const u16* bb0p = BTh + (size_t)(n0 + r0) * K + sb0 * 8;
    const u16* bb1p = BTh + (size_t)(n0 + r1) * K + sb1 * 8;
    int lo0 = wv * 64 * 8;              // wave chunk (elements) within a set
    int lo1 = (256 + wv * 64) * 8;

    floatx4 acc[4][4];
    #pragma unroll
    for (int i = 0; i < 4; i++)
        #pragma unroll
        for (int j = 0; j < 4; j++) acc[i][j] = (floatx4){0.f, 0.f, 0.f, 0.f};

    int aoff[4], boff[4];
    #pragma unroll
    for (int i = 0; i < 4; i++) {
        int arow = wr + i * 16 + l15;
        aoff[i] = arow * 32 + ((l4 ^ ((arow >> 1) & 3)) << 3);
        int bcol = wc + i * 16 + l15;
        boff[i] = bcol * 32 + ((l4 ^ ((bcol >> 1) & 3)) << 3);
    }

    for (int kk = 0; kk < K; kk += 64) {
        __syncthreads();
        // set 0 <- kk
        gld_lds16(a0p + kk, &sAh[0][lo0]);
        gld_lds16(a1p + kk, &sAh[0][lo1]);
        gld_lds16(l0p + kk, &sAl[0][lo0]);
        gld_lds16(l1p + kk, &sAl[0][lo1]);
        gld_lds16(bb0p + kk, &sBh[0][lo0]);
        gld_lds16(bb1p + kk, &sBh[0][lo1]);
        // set 1 <- kk+32
        gld_lds16(a0p + kk + 32, &sAh[1][lo0]);
        gld_lds16(a1p + kk + 32, &sAh[1][lo1]);
        gld_lds16(l0p + kk + 32, &sAl[1][lo0]);
        gld_lds16(l1p + kk + 32, &sAl[1][lo1]);
        gld_lds16(bb0p + kk + 32, &sBh[1][lo0]);
        gld_lds16(bb1p + kk + 32, &sBh[1][lo1]);
        __syncthreads();

        #pragma unroll
        for (int s = 0; s < 2; s++) {
            short8 ah[4], al[4];
            #pragma unroll
            for (int i = 0; i < 4; i++) {
                ah[i] = *(const short8*)(&sAh[s][aoff[i]]);
                al[i] = *(const short8*)(&sAl[s][aoff[i]]);
            }
            #pragma unroll
            for (int j = 0; j < 4; j++) {
                short8 bh = *(const short8*)(&sBh[s][boff[j]]);
                #pragma unroll
                for (int i = 0; i < 4; i++) {
                    acc[i][j] = __builtin_amdgcn_mfma_f32_16x16x32_bf16(ah[i], bh, acc[i][j], 0, 0, 0);
                    acc[i][j] = __builtin_amdgcn_mfma_f32_16x16x32_bf16(al[i], bh, acc[i][j], 0, 0, 0);
                }
            }
        }
    }

    #pragma unroll
    for (int j = 0; j < 4; j++) {
        int col = n0 + wc + j * 16 + l15;
        #pragma unroll
        for (int i = 0; i < 4; i++) {
            #pragma unroll
            for (int r = 0; r < 4; r++) {
                int row = m0 + wr + i * 16 + l4 * 4 + r;
                if (row < M) {
                    if (half) C1[(size_t)row * N + col] = acc[i][j][r];
                    else      C0[(size_t)row * N + col] = f2bf(acc[i][j][r]);
                }
            }
        }
    }
}

// ---------------------------------------------------------------------------
// MLP GEMM, 64x64 tile. R22: two K-steps per barrier pair (2 LDS sets).
// FUSE=0: store hi/lo pair. FUSE=1: fused logit GEMV via atomics.
// ---------------------------------------------------------------------------
template<int FUSE>
__global__ __launch_bounds__(256)
void gemm_mlp64_kernel(const u16* __restrict__ Ah, const u16* __restrict__ Al,
                       const u16* __restrict__ BTh,
                       u16* __restrict__ Ch, u16* __restrict__ Cl,
                       const void* __restrict__ biasraw,
                       const void* __restrict__ A3raw, float* __restrict__ logits,
                       const int* __restrict__ flag,
                       int M, int N, int K)
{
    __shared__ u16 sAh[2][64 * 32];
    __shared__ u16 sAl[2][64 * 32];
    __shared__ u16 sBh[2][64 * 32];
    int tid = threadIdx.x;
    int lane = tid & 63, wv = tid >> 6;
    int l15 = lane & 15, l4 = lane >> 4;
    int m0 = blockIdx.y * 64, n0 = blockIdx.x * 64;

    int r = (tid >> 2), blk = tid & 3, sb = blk ^ ((r >> 1) & 3);
    int gr = min(m0 + r, M - 1);
    const u16* ap = Ah + (size_t)gr * K + sb * 8;
    const u16* lp = Al + (size_t)gr * K + sb * 8;
    const u16* bp = BTh + (size_t)(n0 + r) * K + sb * 8;
    int lo = wv * 64 * 8;

    floatx4 acc[4];
    #pragma unroll
    for (int j = 0; j < 4; j++) acc[j] = (floatx4){0.f, 0.f, 0.f, 0.f};

    int arow = wv * 16 + l15;
    int aoff = arow * 32 + ((l4 ^ ((arow >> 1) & 3)) << 3);
    int boff[4];
    #pragma unroll
    for (int j = 0; j < 4; j++) {
        int bcol = j * 16 + l15;
        boff[j] = bcol * 32 + ((l4 ^ ((bcol >> 1) & 3)) << 3);
    }

    for (int kk = 0; kk < K; kk += 64) {
        __syncthreads();
        gld_lds16(ap + kk, &sAh[0][lo]);
        gld_lds16(lp + kk, &sAl[0][lo]);
        gld_lds16(bp + kk, &sBh[0][lo]);
        gld_lds16(ap + kk + 32, &sAh[1][lo]);
        gld_lds16(lp + kk + 32, &sAl[1][lo]);
        gld_lds16(bp + kk + 32, &sBh[1][lo]);
        __syncthreads();

        #pragma unroll
        for (int s = 0; s < 2; s++) {
            short8 ah = *(const short8*)(&sAh[s][aoff]);
            short8 al = *(const short8*)(&sAl[s][aoff]);
            #pragma unroll
            for (int j = 0; j < 4; j++) {
                short8 bh = *(const short8*)(&sBh[s][boff[j]]);
                acc[j] = __builtin_amdgcn_mfma_f32_16x16x32_bf16(ah, bh, acc[j], 0, 0, 0);
                acc[j] = __builtin_amdgcn_mfma_f32_16x16x32_bf16(al, bh, acc[j], 0, 0, 0);
            }
        }
    }

    const int fp32 = flag[1];
    float lsum[4] = {0.f, 0.f, 0.f, 0.f};
    #pragma unroll
    for (int j = 0; j < 4; j++) {
        int col = n0 + j * 16 + l15;
        float bv = inval(biasraw, fp32, col);
        float a3 = FUSE ? inval(A3raw, fp32, col) : 0.f;
        #pragma unroll
        for (int rr = 0; rr < 4; rr++) {
            int row = m0 + wv * 16 + l4 * 4 + rr;
            if (row < M) {
                float v = acc[j][rr] + bv;
                v = v > 0.f ? v : 0.1f * v;
                if (FUSE) {
                    lsum[rr] += v * a3;
                } else {
                    u16 hi = f2bf(v);
                    Ch[(size_t)row * N + col] = hi;
                    Cl[(size_t)row * N + col] = f2bf(v - bf2f(hi));
                }
            }
        }
    }
    if (FUSE) {
        #pragma unroll
        for (int rr = 0; rr < 4; rr++) {
            float s = lsum[rr];
            s += __shfl_xor(s, 1);
            s += __shfl_xor(s, 2);
            s += __shfl_xor(s, 4);
            s += __shfl_xor(s, 8);
            int row = m0 + wv * 16 + l4 * 4 + rr;
            if (l15 == 0 && row < M) atomicAdd(&logits[row], s);
        }
    }
}

// ---------------------------------------------------------------------------
// GATv2 (R20 body, verbatim — measured best: ~44.5us, Occ 33%, VGPR 64):
// wave-per-node, LPT node order, depth-1 register pipeline, masked padding.
// R16/R17/R21 all proved TLP>ILP for this kernel; do not re-trade.
// ---------------------------------------------------------------------------
__global__ __launch_bounds__(256)
void gat_wave_kernel(const int* __restrict__ rowptr, const int* __restrict__ esrcp,
                     const int* __restrict__ order,
                     const u16* __restrict__ xlb, const float* __restrict__ xr,
                     const void* __restrict__ att, const void* __restrict__ bias,
                     const int* __restrict__ flag,
                     u16* __restrict__ hh, u16* __restrict__ hl)
{
    int lane = threadIdx.x & 63, wv = threadIdx.x >> 6;
    int slot = blockIdx.x * 4 + wv;
    if (slot >= N_NODES) return;
    int n = order[slot];
    n = min(max(n, 0), N_NODES - 1);
    int fp32 = flag[1];
    int d0 = lane * 8;
    int l3 = lane & 3;

    int beg = rowptr[n], end = rowptr[n + 1];
    int deg = end - beg;
    int ng = (deg + 3) >> 2;            // groups of up to 4 edges (padded)

    const u16* xbase = xlb + d0;        // lane's 16B chunk within any row

    const float* xrr = xr + (size_t)n * D_EMB;
    float4 r0 = *(const float4*)(xrr + d0);
    float4 r1 = *(const float4*)(xrr + d0 + 4);
    float xrv[8] = {r0.x, r0.y, r0.z, r0.w, r1.x, r1.y, r1.z, r1.w};
    float attv[8];
    #pragma unroll
    for (int k = 0; k < 8; k++) attv[k] = inval(att, fp32, d0 + k);

    float m_run = -3.4e38f, s_run = 0.f;
    float acc[8] = {0.f, 0.f, 0.f, 0.f, 0.f, 0.f, 0.f, 0.f};

    auto ldidx = [&](int g) -> int {
        return esrcp[min(beg + 4 * g + l3, N_EDGES - 1)];
    };

    if (ng > 0) {
        // prologue: idx group 0 -> rows group 0 in flight; idx group 1 in flight
        int i0 = ldidx(0);
        uint4 cu0, cu1, cu2, cu3;
        {
            int s0 = __shfl(i0, 0), s1 = __shfl(i0, 1), s2 = __shfl(i0, 2), s3 = __shfl(i0, 3);
            cu0 = *(const uint4*)(xbase + (size_t)s0 * D_EMB);
            cu1 = *(const uint4*)(xbase + (size_t)s1 * D_EMB);
            cu2 = *(const uint4*)(xbase + (size_t)s2 * D_EMB);
            cu3 = *(const uint4*)(xbase + (size_t)s3 * D_EMB);
        }
        int nidx = (ng > 1) ? ldidx(1) : 0;

        for (int g = 0; g < ng; g++) {
            // issue next group's row gathers + idx for group g+2 FIRST, so their
            // latency overlaps this group's compute.
            uint4 nu0, nu1, nu2, nu3;
            int nidx2 = 0;
            bool have_next = (g + 1 < ng);
            if (have_next) {
                int t0 = __shfl(nidx, 0), t1 = __shfl(nidx, 1),
                    t2 = __shfl(nidx, 2), t3 = __shfl(nidx, 3);
                nu0 = *(const uint4*)(xbase + (size_t)t0 * D_EMB);
                nu1 = *(const uint4*)(xbase + (size_t)t1 * D_EMB);
                nu2 = *(const uint4*)(xbase + (size_t)t2 * D_EMB);
                nu3 = *(const uint4*)(xbase + (size_t)t3 * D_EMB);
                if (g + 2 < ng) nidx2 = ldidx(g + 2);
            }

            // compute group g from registers loaded last iteration
            union { uint4 q; u16 us[8]; } u0, u1, u2, u3;
            u0.q = cu0; u1.q = cu1; u2.q = cu2; u3.q = cu3;
            float v0[8], v1[8], v2[8], v3[8];
            #pragma unroll
            for (int k = 0; k < 8; k++) {
                v0[k] = bf2f(u0.us[k]); v1[k] = bf2f(u1.us[k]);
                v2[k] = bf2f(u2.us[k]); v3[k] = bf2f(u3.us[k]);
            }
            float e0 = 0.f, e1 = 0.f, e2 = 0.f, e3 = 0.f;
            #pragma unroll
            for (int k = 0; k < 8; k++) {
                float t0 = v0[k] + xrv[k]; t0 = fmaxf(t0, 0.2f * t0); e0 += attv[k] * t0;
                float t1 = v1[k] + xrv[k]; t1 = fmaxf(t1, 0.2f * t1); e1 += attv[k] * t1;
                float t2 = v2[k] + xrv[k]; t2 = fmaxf(t2, 0.2f * t2); e2 += attv[k] * t2;
                float t3 = v3[k] + xrv[k]; t3 = fmaxf(t3, 0.2f * t3); e3 += attv[k] * t3;
            }
            #pragma unroll
            for (int o = 32; o > 0; o >>= 1) {
                e0 += __shfl_xor(e0, o);
                e1 += __shfl_xor(e1, o);
                e2 += __shfl_xor(e2, o);
                e3 += __shfl_xor(e3, o);
            }
            // mask padded (dead) edges of the final group
            int base = beg + 4 * g;
            if (base + 1 >= end) e1 = -3.4e38f;
            if (base + 2 >= end) e2 = -3.4e38f;
            if (base + 3 >= end) e3 = -3.4e38f;
            // group-batched online softmax: one rescale per 4 edges
            float m4 = fmaxf(fmaxf(e0, e1), fmaxf(e2, e3));
            float m_new = fmaxf(m_run, m4);
            float sc = __expf(m_run - m_new);          // 0 on first group
            float w0 = __expf(e0 - m_new), w1 = __expf(e1 - m_new);
            float w2 = __expf(e2 - m_new), w3 = __expf(e3 - m_new);
            s_run = s_run * sc + (w0 + w1) + (w2 + w3);
            #pragma unroll
            for (int k = 0; k < 8; k++)
                acc[k] = acc[k] * sc + w0 * v0[k] + w1 * v1[k] + w2 * v2[k] + w3 * v3[k];
            m_run = m_new;

            if (have_next) {
                cu0 = nu0; cu1 = nu1; cu2 = nu2; cu3 = nu3;
                nidx = nidx2;
            }
        }
    }

    float inv = 1.f / (s_run + 1e-16f);
    union { uint4 q; u16 us[8]; } ph, pl;
    #pragma unroll
    for (int k = 0; k < 8; k++) {
        float h = tanhf(acc[k] * inv + inval(bias, fp32, d0 + k));
        u16 hi = f2bf(h);
        ph.us[k] = hi;
        pl.us[k] = f2bf(h - bf2f(hi));
    }
    *(uint4*)(&hh[(size_t)n * D_EMB + d0]) = ph.q;
    *(uint4*)(&hl[(size_t)n * D_EMB + d0]) = pl.q;
}

// ---------------------------------------------------------------------------
__global__ __launch_bounds__(256)
void softmax_kernel(const float* __restrict__ logits, float* __restrict__ out)
{
    __shared__ float red[4];
    __shared__ float s_m, s_s;
    int tid = threadIdx.x, lane = tid & 63, wv = tid >> 6;
    float m = -3.4e38f;
    for (int i = tid; i < N_NODES; i += 256) m = fmaxf(m, logits[i]);
    #pragma unroll
    for (int o = 32; o > 0; o >>= 1) m = fmaxf(m, __shfl_down(m, o));
    if (lane == 0) red[wv] = m;
    __syncthreads();
    if (tid == 0) {
        float mm = red[0];
        for (int i = 1; i < 4; i++) mm = fmaxf(mm, red[i]);
        s_m = mm;
    }
    __syncthreads();
    float mm = s_m;
    float s = 0.f;
    for (int i = tid; i < N_NODES; i += 256) s += __expf(logits[i] - mm);
    #pragma unroll
    for (int o = 32; o > 0; o >>= 1) s += __shfl_down(s, o);
    if (lane == 0) red[wv] = s;
    __syncthreads();
    if (tid == 0) {
        float ss = 0.f;
        for (int i = 0; i < 4; i++) ss += red[i];
        s_s = ss;
    }
    __syncthreads();
    float invs = 1.f / s_s;
    for (int i = tid; i < N_NODES; i += 256) out[i] = __expf(logits[i] - mm) * invs;
}

// ---------------------------------------------------------------------------
extern "C" void kernel_launch(void* const* d_in, const int* in_sizes, int n_in,
                              void* d_out, int out_size, void* d_ws, size_t ws_size,
                              hipStream_t stream)
{
    const void* x   = d_in[0];
    const int*  ei  = (const int*)d_in[1];
    const void* Wl[3]  = {d_in[2],  d_in[6],  d_in[10]};
    const void* Wr[3]  = {d_in[3],  d_in[7],  d_in[11]};
    const void* att[3] = {d_in[4],  d_in[8],  d_in[12]};
    const void* bia[3] = {d_in[5],  d_in[9],  d_in[13]};
    const void* A1 = d_in[14];
    const void* c1 = d_in[15];
    const void* A2 = d_in[16];
    const void* c2 = d_in[17];
    const void* A3 = d_in[18];

    char* p = (char*)d_ws;
    auto alloc = [&](size_t bytes) {
        char* r = p;
        p += (bytes + 255) & ~(size_t)255;
        return r;
    };
    u16*   xlb    = (u16*)  alloc((size_t)N_NODES * D_EMB * 4);   // bf16 xl (first half) + MLP aliases
    float* xr     = (float*)alloc((size_t)N_NODES * D_EMB * 4);
    u16*   hh     = (u16*)  alloc((size_t)N_NODES * D_EMB * 2);
    u16*   hl     = (u16*)  alloc((size_t)N_NODES * D_EMB * 2);
    int*   esrcp  = (int*)  alloc((size_t)N_EDGES * 4);
    int*   rowptr = (int*)  alloc((size_t)(N_NODES + 1) * 4);
    int*   counts = (int*)  alloc((size_t)N_NODES * 4);
    int*   flag   = (int*)  alloc(256);
    float* logits = (float*)alloc((size_t)N_NODES * 4);
    int*   ghist  = (int*)  alloc(DMAX * 4);
    int*   doff   = (int*)  alloc(DMAX * 4);
    int*   order  = (int*)  alloc((size_t)N_NODES * 4);
    u16* wl1h = (u16*)alloc(D_EMB * D_IN  * 2);
    u16* wr1h = (u16*)alloc(D_EMB * D_IN  * 2);
    u16* wl2h = (u16*)alloc(D_EMB * D_EMB * 2);
    u16* wr2h = (u16*)alloc(D_EMB * D_EMB * 2);
    u16* wl3h = (u16*)alloc(D_EMB * D_EMB * 2);
    u16* wr3h = (u16*)alloc(D_EMB * D_EMB * 2);
    u16* a1h  = (u16*)alloc(D_EMB * D_HID * 2);
    u16* a2h  = (u16*)alloc(D_HID * D_HID * 2);
    u16* xph  = (u16*)alloc((size_t)N_NODES * D_IN * 2);
    u16* xpl  = (u16*)alloc((size_t)N_NODES * D_IN * 2);
    size_t needed = (size_t)(p - (char*)d_ws);

    if (ws_size < needed) {
        sentinel_kernel<<<(out_size + 255) / 256, 256, 0, stream>>>((float*)d_out, out_size);
        return;
    }

    u16* m1h = (u16*)xlb;
    u16* m1l = (u16*)((char*)xlb + 5120000);

    // detect + zero counts/logits/ghist fused
    detect_zero_kernel<<<40, 256, 0, stream>>>(ei, (const u16*)x, flag, counts, logits, ghist);
    count_edges_kernel<<<(N_EDGES + 255) / 256, 256, 0, stream>>>(ei, flag, counts);
    scan_counts_kernel<<<1, 256, 0, stream>>>(counts, rowptr);
    fill_esrcp_kernel<<<(N_EDGES + 255) / 256, 256, 0, stream>>>(ei, flag, counts, esrcp);

    // LPT node order, multi-block (one node per thread; reused by all 3 layers)
    int nblk = (N_NODES + 255) / 256;
    lpt_hist_kernel<<<nblk, 256, 0, stream>>>(rowptr, ghist);
    lpt_scan_kernel<<<1, 256, 0, stream>>>(ghist, doff);
    lpt_scatter_kernel<<<nblk, 256, 0, stream>>>(rowptr, doff, order);

    // fused preconversion: x -> hi/lo; weights -> hi only (transposed)
    ConvJobs jobs;
    auto setjob = [&](int i, const void* s, u16* dh, u16* dl, int r, int c, int tr) {
        jobs.src[i] = s; jobs.dh[i] = dh; jobs.dl[i] = dl;
        jobs.rows[i] = r; jobs.cols[i] = c; jobs.trans[i] = tr;
    };
    setjob(0, x,     xph,  xpl,     N_NODES, D_IN, 0);
    setjob(1, Wl[0], wl1h, nullptr, D_IN,  D_EMB, 1);
    setjob(2, Wr[0], wr1h, nullptr, D_IN,  D_EMB, 1);
    setjob(3, Wl[1], wl2h, nullptr, D_EMB, D_EMB, 1);
    setjob(4, Wr[1], wr2h, nullptr, D_EMB, D_EMB, 1);
    setjob(5, Wl[2], wl3h, nullptr, D_EMB, D_EMB, 1);
    setjob(6, Wr[2], wr3h, nullptr, D_EMB, D_EMB, 1);
    setjob(7, A1,    a1h,  nullptr, D_EMB, D_HID, 1);
    setjob(8, A2,    a2h,  nullptr, D_HID, D_HID, 1);
    jobs.njobs = 9;
    jobs.cum[0] = 0;
    for (int i = 0; i < 9; i++) jobs.cum[i + 1] = jobs.cum[i] + jobs.rows[i] * jobs.cols[i];
    int ctotal = jobs.cum[9];
    convert_fused_kernel<<<(ctotal + 255) / 256, 256, 0, stream>>>(jobs, flag);

    dim3 gdual(2 * D_EMB / 128, (N_NODES + 127) / 128);   // (8, 79)
    dim3 gmlp64(D_HID / 64, (N_NODES + 63) / 64);         // (4, 157)
    int gatgrid = (N_NODES + 3) / 4;

    // layer 1
    gemm_dual_kernel<<<gdual, 256, 0, stream>>>(xph, xpl, wl1h, wr1h, xlb, xr, N_NODES, D_EMB, D_IN);
    gat_wave_kernel<<<gatgrid, 256, 0, stream>>>(rowptr, esrcp, order, xlb, xr, att[0], bia[0], flag, hh, hl);
    // layer 2
    gemm_dual_kernel<<<gdual, 256, 0, stream>>>(hh, hl, wl2h, wr2h, xlb, xr, N_NODES, D_EMB, D_EMB);
    gat_wave_kernel<<<gatgrid, 256, 0, stream>>>(rowptr, esrcp, order, xlb, xr, att[1], bia[1], flag, hh, hl);
    // layer 3
    gemm_dual_kernel<<<gdual, 256, 0, stream>>>(hh, hl, wl3h, wr3h, xlb, xr, N_NODES, D_EMB, D_EMB);
    gat_wave_kernel<<<gatgrid, 256, 0, stream>>>(rowptr, esrcp, order, xlb, xr, att[2], bia[2], flag, hh, hl);

    // MLP: GEMM1 stores pair; GEMM2 fuses the A3 logit GEMV via atomics
    gemm_mlp64_kernel<0><<<gmlp64, 256, 0, stream>>>(hh, hl, a1h, m1h, m1l, c1, nullptr, nullptr, flag, N_NODES, D_HID, D_EMB);
    gemm_mlp64_kernel<1><<<gmlp64, 256, 0, stream>>>(m1h, m1l, a2h, nullptr, nullptr, c2, A3, logits, flag, N_NODES, D_HID, D_HID);
    softmax_kernel<<<1, 256, 0, stream>>>(logits, (float*)d_out);
}

// Round 10
// 397.890 us; speedup vs baseline: 1.1670x; 1.0592x over previous
//
#include <hip/hip_runtime.h>
#include <hip/hip_bf16.h>

#define N_NODES 10000
#define N_EDGES 160000
#define D_IN    128
#define D_EMB   512
#define D_HID   256
#define DMAX    512

typedef unsigned short u16;
typedef __attribute__((ext_vector_type(8))) short short8;
typedef __attribute__((ext_vector_type(4))) float floatx4;

__device__ __forceinline__ float bf2f(u16 u) {
    union { unsigned int i; float f; } v; v.i = ((unsigned int)u) << 16; return v.f;
}
__device__ __forceinline__ u16 f2bf(float f) {
    union { float f; unsigned int i; } v; v.f = f;
    unsigned int x = v.i;
    return (u16)((x + 0x7fffu + ((x >> 16) & 1u)) >> 16);  // RNE
}
__device__ __forceinline__ float inval(const void* p, int fp32, int idx) {
    return fp32 ? ((const float*)p)[idx] : bf2f(((const u16*)p)[idx]);
}

// async global->LDS, 16 bytes/lane; lds base must be wave-uniform.
__device__ __forceinline__ void gld_lds16(const u16* g, u16* l) {
    __builtin_amdgcn_global_load_lds((const __attribute__((address_space(1))) void*)g,
                                     (__attribute__((address_space(3))) void*)l,
                                     16, 0, 0);
}

// bijective XCD chunk remap (m204): blocks with bid%8==k get a contiguous
// range of work ids, so each XCD covers consecutive row-panels (A reuse in L2).
__device__ __forceinline__ int xcd_chunk(int bid, int total) {
    int q = total >> 3, r = total & 7;
    int xcd = bid & 7, idx = bid >> 3;
    return (xcd < r ? xcd * (q + 1) : r * (q + 1) + (xcd - r) * q) + idx;
}

// flag[0]: edge_index is int64-viewed-as-int32-pairs; flag[1]: floats are fp32
__device__ __forceinline__ int edge_src(const int* __restrict__ ei, int flg, int e) {
    int v = flg ? ei[2 * e] : ei[e];
    return min(max(v, 0), N_NODES - 1);
}
__device__ __forceinline__ int edge_dst(const int* __restrict__ ei, int flg, int e) {
    int v = flg ? ei[2 * N_EDGES + 2 * e] : ei[N_EDGES + e];
    return min(max(v, 0), N_NODES - 1);
}

// ---------------------------------------------------------------------------
__global__ void sentinel_kernel(float* out, int n) {
    int i = blockIdx.x * 256 + threadIdx.x;
    if (i < n) out[i] = 1.0f;   // => workspace too small
}

// detect dtypes + zero counts/logits/ghist, one dispatch (block 0 = census)
__global__ __launch_bounds__(256)
void detect_zero_kernel(const int* __restrict__ ei, const u16* __restrict__ xu,
                        int* flag, int* counts, float* logits, int* ghist) {
    int gid = blockIdx.x * 256 + threadIdx.x;
    for (int i = gid; i < N_NODES; i += gridDim.x * 256) { counts[i] = 0; logits[i] = 0.f; }
    for (int i = gid; i < DMAX; i += gridDim.x * 256) ghist[i] = 0;
    if (blockIdx.x != 0) return;
    __shared__ int s_or[256];
    __shared__ int s_cnt[256];
    int t = threadIdx.x;
    int v = 0;
    for (int k = t; k < 4096; k += 256) v |= ei[1 + 2 * k];
    int c = 0;
    for (int k = t; k < 4096; k += 256) {
        u16 u = xu[k];
        int ex = (u >> 7) & 0xFF;
        bool plaus = (u == 0) || (ex >= 64 && ex <= 191);
        if (!plaus) c++;
    }
    s_or[t] = v; s_cnt[t] = c;
    __syncthreads();
    for (int off = 128; off > 0; off >>= 1) {
        if (t < off) { s_or[t] |= s_or[t + off]; s_cnt[t] += s_cnt[t + off]; }
        __syncthreads();
    }
    if (t == 0) {
        flag[0] = (s_or[0] == 0) ? 1 : 0;
        flag[1] = (s_cnt[0] > 256) ? 1 : 0;
    }
}

// ---------------------------------------------------------------------------
// Fused preconversion; dl == nullptr -> hi only.
// ---------------------------------------------------------------------------
struct ConvJobs {
    const void* src[10];
    u16* dh[10];
    u16* dl[10];
    int rows[10], cols[10], trans[10];
    int cum[11];
    int njobs;
};

__global__ __launch_bounds__(256)
void convert_fused_kernel(ConvJobs jobs, const int* __restrict__ flag) {
    int idx = blockIdx.x * 256 + threadIdx.x;
    if (idx >= jobs.cum[jobs.njobs]) return;
    int fp32 = flag[1];
    int jb = 0;
    while (idx >= jobs.cum[jb + 1]) jb++;
    int local = idx - jobs.cum[jb];
    float v = inval(jobs.src[jb], fp32, local);
    u16 hi = f2bf(v);
    int o;
    if (jobs.trans[jb]) {
        int r = local / jobs.cols[jb], c = local % jobs.cols[jb];
        o = c * jobs.rows[jb] + r;
    } else o = local;
    jobs.dh[jb][o] = hi;
    if (jobs.dl[jb]) jobs.dl[jb][o] = f2bf(v - bf2f(hi));
}

// ---------------------------------------------------------------------------
// CSR build
// ---------------------------------------------------------------------------
__global__ void count_edges_kernel(const int* __restrict__ ei, const int* __restrict__ flag,
                                   int* counts) {
    int e = blockIdx.x * 256 + threadIdx.x;
    if (e < N_EDGES) atomicAdd(&counts[edge_dst(ei, flag[0], e)], 1);
}

__global__ __launch_bounds__(256)
void scan_counts_kernel(int* counts, int* rowptr) {
    __shared__ int part[256];
    int tid = threadIdx.x;
    const int CH = 40;
    int base = tid * CH;
    int loc[CH];
    int s = 0;
    #pragma unroll
    for (int i = 0; i < CH; i++) {
        int idx = base + i;
        int c = (idx < N_NODES) ? counts[idx] : 0;
        loc[i] = s; s += c;
    }
    part[tid] = s;
    __syncthreads();
    for (int off = 1; off < 256; off <<= 1) {
        int v = part[tid];
        int add = (tid >= off) ? part[tid - off] : 0;
        __syncthreads();
        part[tid] = v + add;
        __syncthreads();
    }
    int pre = (tid > 0) ? part[tid - 1] : 0;
    #pragma unroll
    for (int i = 0; i < CH; i++) {
        int idx = base + i;
        if (idx < N_NODES) { int v = pre + loc[i]; rowptr[idx] = v; counts[idx] = v; }
    }
    if (tid == 255) rowptr[N_NODES] = part[255];
}

__global__ void fill_esrcp_kernel(const int* __restrict__ ei, const int* __restrict__ flag,
                                  int* counts, int* esrcp) {
    int e = blockIdx.x * 256 + threadIdx.x;
    if (e < N_EDGES) {
        int flg = flag[0];
        int pos = atomicAdd(&counts[edge_dst(ei, flg, e)], 1);
        if (pos >= 0 && pos < N_EDGES) esrcp[pos] = edge_src(ei, flg, e);
    }
}

// ---------------------------------------------------------------------------
// Degree-descending node order (LPT), multi-block (one node per thread).
// ---------------------------------------------------------------------------
__global__ __launch_bounds__(256)
void lpt_hist_kernel(const int* __restrict__ rowptr, int* __restrict__ ghist) {
    __shared__ int lhist[DMAX];
    int t = threadIdx.x;
    for (int d = t; d < DMAX; d += 256) lhist[d] = 0;
    __syncthreads();
    int n = blockIdx.x * 256 + t;
    if (n < N_NODES) {
        int d = min(rowptr[n + 1] - rowptr[n], DMAX - 1);
        atomicAdd(&lhist[d], 1);
    }
    __syncthreads();
    for (int d = t; d < DMAX; d += 256) {
        int c = lhist[d];
        if (c > 0) atomicAdd(&ghist[d], c);
    }
}

// doff[d] = number of nodes with degree > d (descending exclusive scan)
__global__ __launch_bounds__(256)
void lpt_scan_kernel(const int* __restrict__ ghist, int* __restrict__ doff) {
    __shared__ int part[256];
    int t = threadIdx.x;
    int d0 = (DMAX - 1) - 2 * t;        // thread t owns degrees d0, d0-1
    int d1 = d0 - 1;
    int c0 = ghist[d0], c1 = ghist[d1];
    part[t] = c0 + c1;
    __syncthreads();
    for (int o = 1; o < 256; o <<= 1) {
        int v = part[t];
        int add = (t >= o) ? part[t - o] : 0;
        __syncthreads();
        part[t] = v + add;
        __syncthreads();
    }
    int pre = (t > 0) ? part[t - 1] : 0;
    doff[d0] = pre;
    doff[d1] = pre + c0;
}

__global__ __launch_bounds__(256)
void lpt_scatter_kernel(const int* __restrict__ rowptr, int* __restrict__ doff,
                        int* __restrict__ order) {
    __shared__ int lhist[DMAX];
    __shared__ int lbase[DMAX];
    int t = threadIdx.x;
    for (int d = t; d < DMAX; d += 256) lhist[d] = 0;
    __syncthreads();
    int n = blockIdx.x * 256 + t;
    int dg = 0;
    if (n < N_NODES) {
        dg = min(rowptr[n + 1] - rowptr[n], DMAX - 1);
        atomicAdd(&lhist[dg], 1);
    }
    __syncthreads();
    // reserve a contiguous chunk per nonempty bucket; reset lhist for ranking
    for (int d = t; d < DMAX; d += 256) {
        int c = lhist[d];
        lbase[d] = (c > 0) ? atomicAdd(&doff[d], c) : 0;
        lhist[d] = 0;
    }
    __syncthreads();
    if (n < N_NODES) {
        int rank = atomicAdd(&lhist[dg], 1);
        int pos = lbase[dg] + rank;
        if (pos >= 0 && pos < N_NODES) order[pos] = n;
    }
}

// ---------------------------------------------------------------------------
// Dual 128x128-tile GEMM, two K-steps per barrier pair (R22), 1D grid with
// XCD-chunk remap (R23): each XCD covers contiguous row-panels with ALL
// column tiles, so the A-panel (hi+lo) is fetched once into its L2 and
// reused by 8 column blocks instead of each XCD streaming the whole A.
// ---------------------------------------------------------------------------
__global__ __launch_bounds__(256)
void gemm_dual_kernel(const u16* __restrict__ Ah, const u16* __restrict__ Al,
                      const u16* __restrict__ B0h, const u16* __restrict__ B1h,
                      u16* __restrict__ C0, float* __restrict__ C1,
                      int M, int N, int K)
{
    __shared__ u16 sAh[2][128 * 32];
    __shared__ u16 sAl[2][128 * 32];
    __shared__ u16 sBh[2][128 * 32];
    int nb = N >> 7;
    int nx = 2 * nb;
    int ny = (M + 127) >> 7;
    int w = xcd_chunk((int)blockIdx.x, nx * ny);
    int by = w / nx;
    int bxh = w - by * nx;
    int half = bxh >= nb;
    int bx = half ? (bxh - nb) : bxh;
    const u16* BTh = half ? B1h : B0h;

    int tid = threadIdx.x;
    int lane = tid & 63, wv = tid >> 6;
    int l15 = lane & 15, l4 = lane >> 4;
    int wr = (wv >> 1) * 64, wc = (wv & 1) * 64;
    int m0 = by * 128, n0 = bx * 128;

    int i0 = tid, i1 = tid + 256;
    int r0 = i0 >> 2, b0 = i0 & 3, sb0 = b0 ^ ((r0 >> 1) & 3);
    int r1 = i1 >> 2, b1 = i1 & 3, sb1 = b1 ^ ((r1 >> 1) & 3);
    int gr0 = min(m0 + r0, M - 1), gr1 = min(m0 + r1, M - 1);
    const u16* a0p = Ah + (size_t)gr0 * K + sb0 * 8;
    const u16* a1p = Ah + (size_t)gr1 * K + sb1 * 8;
    const u16* l0p = Al + (size_t)gr0 * K + sb0 * 8;
    const u16* l1p = Al + (size_t)gr1 * K + sb1 * 8;
    const u16* bb0p = BTh + (size_t)(n0 + r0) * K + sb0 * 8;
    const u16* bb1p = BTh + (size_t)(n0 + r1) * K + sb1 * 8;
    int lo0 = wv * 64 * 8;              // wave chunk (elements) within a set
    int lo1 = (256 + wv * 64) * 8;

    floatx4 acc[4][4];
    #pragma unroll
    for (int i = 0; i < 4; i++)
        #pragma unroll
        for (int j = 0; j < 4; j++) acc[i][j] = (floatx4){0.f, 0.f, 0.f, 0.f};

    int aoff[4], boff[4];
    #pragma unroll
    for (int i = 0; i < 4; i++) {
        int arow = wr + i * 16 + l15;
        aoff[i] = arow * 32 + ((l4 ^ ((arow >> 1) & 3)) << 3);
        int bcol = wc + i * 16 + l15;
        boff[i] = bcol * 32 + ((l4 ^ ((bcol >> 1) & 3)) << 3);
    }

    for (int kk = 0; kk < K; kk += 64) {
        __syncthreads();
        // set 0 <- kk
        gld_lds16(a0p + kk, &sAh[0][lo0]);
        gld_lds16(a1p + kk, &sAh[0][lo1]);
        gld_lds16(l0p + kk, &sAl[0][lo0]);
        gld_lds16(l1p + kk, &sAl[0][lo1]);
        gld_lds16(bb0p + kk, &sBh[0][lo0]);
        gld_lds16(bb1p + kk, &sBh[0][lo1]);
        // set 1 <- kk+32
        gld_lds16(a0p + kk + 32, &sAh[1][lo0]);
        gld_lds16(a1p + kk + 32, &sAh[1][lo1]);
        gld_lds16(l0p + kk + 32, &sAl[1][lo0]);
        gld_lds16(l1p + kk + 32, &sAl[1][lo1]);
        gld_lds16(bb0p + kk + 32, &sBh[1][lo0]);
        gld_lds16(bb1p + kk + 32, &sBh[1][lo1]);
        __syncthreads();

        #pragma unroll
        for (int s = 0; s < 2; s++) {
            short8 ah[4], al[4];
            #pragma unroll
            for (int i = 0; i < 4; i++) {
                ah[i] = *(const short8*)(&sAh[s][aoff[i]]);
                al[i] = *(const short8*)(&sAl[s][aoff[i]]);
            }
            #pragma unroll
            for (int j = 0; j < 4; j++) {
                short8 bh = *(const short8*)(&sBh[s][boff[j]]);
                #pragma unroll
                for (int i = 0; i < 4; i++) {
                    acc[i][j] = __builtin_amdgcn_mfma_f32_16x16x32_bf16(ah[i], bh, acc[i][j], 0, 0, 0);
                    acc[i][j] = __builtin_amdgcn_mfma_f32_16x16x32_bf16(al[i], bh, acc[i][j], 0, 0, 0);
                }
            }
        }
    }

    #pragma unroll
    for (int j = 0; j < 4; j++) {
        int col = n0 + wc + j * 16 + l15;
        #pragma unroll
        for (int i = 0; i < 4; i++) {
            #pragma unroll
            for (int r = 0; r < 4; r++) {
                int row = m0 + wr + i * 16 + l4 * 4 + r;
                if (row < M) {
                    if (half) C1[(size_t)row * N + col] = acc[i][j][r];
                    else      C0[(size_t)row * N + col] = f2bf(acc[i][j][r]);
                }
            }
        }
    }
}

// ---------------------------------------------------------------------------
// MLP GEMM, 64x64 tile, two K-steps per barrier pair, XCD-chunk remap.
// FUSE=0: store hi/lo pair. FUSE=1: fused logit GEMV via atomics.
// ---------------------------------------------------------------------------
template<int FUSE>
__global__ __launch_bounds__(256)
void gemm_mlp64_kernel(const u16* __restrict__ Ah, const u16* __restrict__ Al,
                       const u16* __restrict__ BTh,
                       u16* __restrict__ Ch, u16* __restrict__ Cl,
                       const void* __restrict__ biasraw,
                       const void* __restrict__ A3raw, float* __restrict__ logits,
                       const int* __restrict__ flag,
                       int M, int N, int K)
{
    __shared__ u16 sAh[2][64 * 32];
    __shared__ u16 sAl[2][64 * 32];
    __shared__ u16 sBh[2][64 * 32];
    int tid = threadIdx.x;
    int lane = tid & 63, wv = tid >> 6;
    int l15 = lane & 15, l4 = lane >> 4;
    int nx = N >> 6;
    int ny = (M + 63) >> 6;
    int w = xcd_chunk((int)blockIdx.x, nx * ny);
    int by = w / nx;
    int bx = w - by * nx;
    int m0 = by * 64, n0 = bx * 64;

    int r = (tid >> 2), blk = tid & 3, sb = blk ^ ((r >> 1) & 3);
    int gr = min(m0 + r, M - 1);
    const u16* ap = Ah + (size_t)gr * K + sb * 8;
    const u16* lp = Al + (size_t)gr * K + sb * 8;
    const u16* bp = BTh + (size_t)(n0 + r) * K + sb * 8;
    int lo = wv * 64 * 8;

    floatx4 acc[4];
    #pragma unroll
    for (int j = 0; j < 4; j++) acc[j] = (floatx4){0.f, 0.f, 0.f, 0.f};

    int arow = wv * 16 + l15;
    int aoff = arow * 32 + ((l4 ^ ((arow >> 1) & 3)) << 3);
    int boff[4];
    #pragma unroll
    for (int j = 0; j < 4; j++) {
        int bcol = j * 16 + l15;
        boff[j] = bcol * 32 + ((l4 ^ ((bcol >> 1) & 3)) << 3);
    }

    for (int kk = 0; kk < K; kk += 64) {
        __syncthreads();
        gld_lds16(ap + kk, &sAh[0][lo]);
        gld_lds16(lp + kk, &sAl[0][lo]);
        gld_lds16(bp + kk, &sBh[0][lo]);
        gld_lds16(ap + kk + 32, &sAh[1][lo]);
        gld_lds16(lp + kk + 32, &sAl[1][lo]);
        gld_lds16(bp + kk + 32, &sBh[1][lo]);
        __syncthreads();

        #pragma unroll
        for (int s = 0; s < 2; s++) {
            short8 ah = *(const short8*)(&sAh[s][aoff]);
            short8 al = *(const short8*)(&sAl[s][aoff]);
            #pragma unroll
            for (int j = 0; j < 4; j++) {
                short8 bh = *(const short8*)(&sBh[s][boff[j]]);
                acc[j] = __builtin_amdgcn_mfma_f32_16x16x32_bf16(ah, bh, acc[j], 0, 0, 0);
                acc[j] = __builtin_amdgcn_mfma_f32_16x16x32_bf16(al, bh, acc[j], 0, 0, 0);
            }
        }
    }

    const int fp32 = flag[1];
    float lsum[4] = {0.f, 0.f, 0.f, 0.f};
    #pragma unroll
    for (int j = 0; j < 4; j++) {
        int col = n0 + j * 16 + l15;
        float bv = inval(biasraw, fp32, col);
        float a3 = FUSE ? inval(A3raw, fp32, col) : 0.f;
        #pragma unroll
        for (int rr = 0; rr < 4; rr++) {
            int row = m0 + wv * 16 + l4 * 4 + rr;
            if (row < M) {
                float v = acc[j][rr] + bv;
                v = v > 0.f ? v : 0.1f * v;
                if (FUSE) {
                    lsum[rr] += v * a3;
                } else {
                    u16 hi = f2bf(v);
                    Ch[(size_t)row * N + col] = hi;
                    Cl[(size_t)row * N + col] = f2bf(v - bf2f(hi));
                }
            }
        }
    }
    if (FUSE) {
        #pragma unroll
        for (int rr = 0; rr < 4; rr++) {
            float s = lsum[rr];
            s += __shfl_xor(s, 1);
            s += __shfl_xor(s, 2);
            s += __shfl_xor(s, 4);
            s += __shfl_xor(s, 8);
            int row = m0 + wv * 16 + l4 * 4 + rr;
            if (l15 == 0 && row < M) atomicAdd(&logits[row], s);
        }
    }
}

// ---------------------------------------------------------------------------
// GATv2 (R20 body, verbatim — measured best: ~44us, Occ 33%, VGPR 64):
// wave-per-node, LPT node order, depth-1 register pipeline, masked padding.
// R16/R17/R21 all proved TLP>ILP for this kernel; do not re-trade.
// ---------------------------------------------------------------------------
__global__ __launch_bounds__(256)
void gat_wave_kernel(const int* __restrict__ rowptr, const int* __restrict__ esrcp,
                     const int* __restrict__ order,
                     const u16* __restrict__ xlb, const float* __restrict__ xr,
                     const void* __restrict__ att, const void* __restrict__ bias,
                     const int* __restrict__ flag,
                     u16* __restrict__ hh, u16* __restrict__ hl)
{
    int lane = threadIdx.x & 63, wv = threadIdx.x >> 6;
    int slot = blockIdx.x * 4 + wv;
    if (slot >= N_NODES) return;
    int n = order[slot];
    n = min(max(n, 0), N_NODES - 1);
    int fp32 = flag[1];
    int d0 = lane * 8;
    int l3 = lane & 3;

    int beg = rowptr[n], end = rowptr[n + 1];
    int deg = end - beg;
    int ng = (deg + 3) >> 2;            // groups of up to 4 edges (padded)

    const u16* xbase = xlb + d0;        // lane's 16B chunk within any row

    const float* xrr = xr + (size_t)n * D_EMB;
    float4 r0 = *(const float4*)(xrr + d0);
    float4 r1 = *(const float4*)(xrr + d0 + 4);
    float xrv[8] = {r0.x, r0.y, r0.z, r0.w, r1.x, r1.y, r1.z, r1.w};
    float attv[8];
    #pragma unroll
    for (int k = 0; k < 8; k++) attv[k] = inval(att, fp32, d0 + k);

    float m_run = -3.4e38f, s_run = 0.f;
    float acc[8] = {0.f, 0.f, 0.f, 0.f, 0.f, 0.f, 0.f, 0.f};

    auto ldidx = [&](int g) -> int {
        return esrcp[min(beg + 4 * g + l3, N_EDGES - 1)];
    };

    if (ng > 0) {
        // prologue: idx group 0 -> rows group 0 in flight; idx group 1 in flight
        int i0 = ldidx(0);
        uint4 cu0, cu1, cu2, cu3;
        {
            int s0 = __shfl(i0, 0), s1 = __shfl(i0, 1), s2 = __shfl(i0, 2), s3 = __shfl(i0, 3);
            cu0 = *(const uint4*)(xbase + (size_t)s0 * D_EMB);
            cu1 = *(const uint4*)(xbase + (size_t)s1 * D_EMB);
            cu2 = *(const uint4*)(xbase + (size_t)s2 * D_EMB);
            cu3 = *(const uint4*)(xbase + (size_t)s3 * D_EMB);
        }
        int nidx = (ng > 1) ? ldidx(1) : 0;

        for (int g = 0; g < ng; g++) {
            // issue next group's row gathers + idx for group g+2 FIRST, so their
            // latency overlaps this group's compute.
            uint4 nu0, nu1, nu2, nu3;
            int nidx2 = 0;
            bool have_next = (g + 1 < ng);
            if (have_next) {
                int t0 = __shfl(nidx, 0), t1 = __shfl(nidx, 1),
                    t2 = __shfl(nidx, 2), t3 = __shfl(nidx, 3);
                nu0 = *(const uint4*)(xbase + (size_t)t0 * D_EMB);
                nu1 = *(const uint4*)(xbase + (size_t)t1 * D_EMB);
                nu2 = *(const uint4*)(xbase + (size_t)t2 * D_EMB);
                nu3 = *(const uint4*)(xbase + (size_t)t3 * D_EMB);
                if (g + 2 < ng) nidx2 = ldidx(g + 2);
            }

            // compute group g from registers loaded last iteration
            union { uint4 q; u16 us[8]; } u0, u1, u2, u3;
            u0.q = cu0; u1.q = cu1; u2.q = cu2; u3.q = cu3;
            float v0[8], v1[8], v2[8], v3[8];
            #pragma unroll
            for (int k = 0; k < 8; k++) {
                v0[k] = bf2f(u0.us[k]); v1[k] = bf2f(u1.us[k]);
                v2[k] = bf2f(u2.us[k]); v3[k] = bf2f(u3.us[k]);
            }
            float e0 = 0.f, e1 = 0.f, e2 = 0.f, e3 = 0.f;
            #pragma unroll
            for (int k = 0; k < 8; k++) {
                float t0 = v0[k] + xrv[k]; t0 = fmaxf(t0, 0.2f * t0); e0 += attv[k] * t0;
                float t1 = v1[k] + xrv[k]; t1 = fmaxf(t1, 0.2f * t1); e1 += attv[k] * t1;
                float t2 = v2[k] + xrv[k]; t2 = fmaxf(t2, 0.2f * t2); e2 += attv[k] * t2;
                float t3 = v3[k] + xrv[k]; t3 = fmaxf(t3, 0.2f * t3); e3 += attv[k] * t3;
            }
            #pragma unroll
            for (int o = 32; o > 0; o >>= 1) {
                e0 += __shfl_xor(e0, o);
                e1 += __shfl_xor(e1, o);
                e2 += __shfl_xor(e2, o);
                e3 += __shfl_xor(e3, o);
            }
            // mask padded (dead) edges of the final group
            int base = beg + 4 * g;
            if (base + 1 >= end) e1 = -3.4e38f;
            if (base + 2 >= end) e2 = -3.4e38f;
            if (base + 3 >= end) e3 = -3.4e38f;
            // group-batched online softmax: one rescale per 4 edges
            float m4 = fmaxf(fmaxf(e0, e1), fmaxf(e2, e3));
            float m_new = fmaxf(m_run, m4);
            float sc = __expf(m_run - m_new);          // 0 on first group
            float w0 = __expf(e0 - m_new), w1 = __expf(e1 - m_new);
            float w2 = __expf(e2 - m_new), w3 = __expf(e3 - m_new);
            s_run = s_run * sc + (w0 + w1) + (w2 + w3);
            #pragma unroll
            for (int k = 0; k < 8; k++)
                acc[k] = acc[k] * sc + w0 * v0[k] + w1 * v1[k] + w2 * v2[k] + w3 * v3[k];
            m_run = m_new;

            if (have_next) {
                cu0 = nu0; cu1 = nu1; cu2 = nu2; cu3 = nu3;
                nidx = nidx2;
            }
        }
    }

    float inv = 1.f / (s_run + 1e-16f);
    union { uint4 q; u16 us[8]; } ph, pl;
    #pragma unroll
    for (int k = 0; k < 8; k++) {
        float h = tanhf(acc[k] * inv + inval(bias, fp32, d0 + k));
        u16 hi = f2bf(h);
        ph.us[k] = hi;
        pl.us[k] = f2bf(h - bf2f(hi));
    }
    *(uint4*)(&hh[(size_t)n * D_EMB + d0]) = ph.q;
    *(uint4*)(&hl[(size_t)n * D_EMB + d0]) = pl.q;
}

// ---------------------------------------------------------------------------
__global__ __launch_bounds__(256)
void softmax_kernel(const float* __restrict__ logits, float* __restrict__ out)
{
    __shared__ float red[4];
    __shared__ float s_m, s_s;
    int tid = threadIdx.x, lane = tid & 63, wv = tid >> 6;
    float m = -3.4e38f;
    for (int i = tid; i < N_NODES; i += 256) m = fmaxf(m, logits[i]);
    #pragma unroll
    for (int o = 32; o > 0; o >>= 1) m = fmaxf(m, __shfl_down(m, o));
    if (lane == 0) red[wv] = m;
    __syncthreads();
    if (tid == 0) {
        float mm = red[0];
        for (int i = 1; i < 4; i++) mm = fmaxf(mm, red[i]);
        s_m = mm;
    }
    __syncthreads();
    float mm = s_m;
    float s = 0.f;
    for (int i = tid; i < N_NODES; i += 256) s += __expf(logits[i] - mm);
    #pragma unroll
    for (int o = 32; o > 0; o >>= 1) s += __shfl_down(s, o);
    if (lane == 0) red[wv] = s;
    __syncthreads();
    if (tid == 0) {
        float ss = 0.f;
        for (int i = 0; i < 4; i++) ss += red[i];
        s_s = ss;
    }
    __syncthreads();
    float invs = 1.f / s_s;
    for (int i = tid; i < N_NODES; i += 256) out[i] = __expf(logits[i] - mm) * invs;
}

// ---------------------------------------------------------------------------
extern "C" void kernel_launch(void* const* d_in, const int* in_sizes, int n_in,
                              void* d_out, int out_size, void* d_ws, size_t ws_size,
                              hipStream_t stream)
{
    const void* x   = d_in[0];
    const int*  ei  = (const int*)d_in[1];
    const void* Wl[3]  = {d_in[2],  d_in[6],  d_in[10]};
    const void* Wr[3]  = {d_in[3],  d_in[7],  d_in[11]};
    const void* att[3] = {d_in[4],  d_in[8],  d_in[12]};
    const void* bia[3] = {d_in[5],  d_in[9],  d_in[13]};
    const void* A1 = d_in[14];
    const void* c1 = d_in[15];
    const void* A2 = d_in[16];
    const void* c2 = d_in[17];
    const void* A3 = d_in[18];

    char* p = (char*)d_ws;
    auto alloc = [&](size_t bytes) {
        char* r = p;
        p += (bytes + 255) & ~(size_t)255;
        return r;
    };
    u16*   xlb    = (u16*)  alloc((size_t)N_NODES * D_EMB * 4);   // bf16 xl (first half) + MLP aliases
    float* xr     = (float*)alloc((size_t)N_NODES * D_EMB * 4);
    u16*   hh     = (u16*)  alloc((size_t)N_NODES * D_EMB * 2);
    u16*   hl     = (u16*)  alloc((size_t)N_NODES * D_EMB * 2);
    int*   esrcp  = (int*)  alloc((size_t)N_EDGES * 4);
    int*   rowptr = (int*)  alloc((size_t)(N_NODES + 1) * 4);
    int*   counts = (int*)  alloc((size_t)N_NODES * 4);
    int*   flag   = (int*)  alloc(256);
    float* logits = (float*)alloc((size_t)N_NODES * 4);
    int*   ghist  = (int*)  alloc(DMAX * 4);
    int*   doff   = (int*)  alloc(DMAX * 4);
    int*   order  = (int*)  alloc((size_t)N_NODES * 4);
    u16* wl1h = (u16*)alloc(D_EMB * D_IN  * 2);
    u16* wr1h = (u16*)alloc(D_EMB * D_IN  * 2);
    u16* wl2h = (u16*)alloc(D_EMB * D_EMB * 2);
    u16* wr2h = (u16*)alloc(D_EMB * D_EMB * 2);
    u16* wl3h = (u16*)alloc(D_EMB * D_EMB * 2);
    u16* wr3h = (u16*)alloc(D_EMB * D_EMB * 2);
    u16* a1h  = (u16*)alloc(D_EMB * D_HID * 2);
    u16* a2h  = (u16*)alloc(D_HID * D_HID * 2);
    u16* xph  = (u16*)alloc((size_t)N_NODES * D_IN * 2);
    u16* xpl  = (u16*)alloc((size_t)N_NODES * D_IN * 2);
    size_t needed = (size_t)(p - (char*)d_ws);

    if (ws_size < needed) {
        sentinel_kernel<<<(out_size + 255) / 256, 256, 0, stream>>>((float*)d_out, out_size);
        return;
    }

    u16* m1h = (u16*)xlb;
    u16* m1l = (u16*)((char*)xlb + 5120000);

    // detect + zero counts/logits/ghist fused
    detect_zero_kernel<<<40, 256, 0, stream>>>(ei, (const u16*)x, flag, counts, logits, ghist);
    count_edges_kernel<<<(N_EDGES + 255) / 256, 256, 0, stream>>>(ei, flag, counts);
    scan_counts_kernel<<<1, 256, 0, stream>>>(counts, rowptr);
    fill_esrcp_kernel<<<(N_EDGES + 255) / 256, 256, 0, stream>>>(ei, flag, counts, esrcp);

    // LPT node order, multi-block (one node per thread; reused by all 3 layers)
    int nblk = (N_NODES + 255) / 256;
    lpt_hist_kernel<<<nblk, 256, 0, stream>>>(rowptr, ghist);
    lpt_scan_kernel<<<1, 256, 0, stream>>>(ghist, doff);
    lpt_scatter_kernel<<<nblk, 256, 0, stream>>>(rowptr, doff, order);

    // fused preconversion: x -> hi/lo; weights -> hi only (transposed)
    ConvJobs jobs;
    auto setjob = [&](int i, const void* s, u16* dh, u16* dl, int r, int c, int tr) {
        jobs.src[i] = s; jobs.dh[i] = dh; jobs.dl[i] = dl;
        jobs.rows[i] = r; jobs.cols[i] = c; jobs.trans[i] = tr;
    };
    setjob(0, x,     xph,  xpl,     N_NODES, D_IN, 0);
    setjob(1, Wl[0], wl1h, nullptr, D_IN,  D_EMB, 1);
    setjob(2, Wr[0], wr1h, nullptr, D_IN,  D_EMB, 1);
    setjob(3, Wl[1], wl2h, nullptr, D_EMB, D_EMB, 1);
    setjob(4, Wr[1], wr2h, nullptr, D_EMB, D_EMB, 1);
    setjob(5, Wl[2], wl3h, nullptr, D_EMB, D_EMB, 1);
    setjob(6, Wr[2], wr3h, nullptr, D_EMB, D_EMB, 1);
    setjob(7, A1,    a1h,  nullptr, D_EMB, D_HID, 1);
    setjob(8, A2,    a2h,  nullptr, D_HID, D_HID, 1);
    jobs.njobs = 9;
    jobs.cum[0] = 0;
    for (int i = 0; i < 9; i++) jobs.cum[i + 1] = jobs.cum[i] + jobs.rows[i] * jobs.cols[i];
    int ctotal = jobs.cum[9];
    convert_fused_kernel<<<(ctotal + 255) / 256, 256, 0, stream>>>(jobs, flag);

    int gdual = (2 * D_EMB / 128) * ((N_NODES + 127) / 128);   // 8 * 79 = 632
    int gmlp  = (D_HID / 64) * ((N_NODES + 63) / 64);          // 4 * 157 = 628
    int gatgrid = (N_NODES + 3) / 4;

    // layer 1
    gemm_dual_kernel<<<gdual, 256, 0, stream>>>(xph, xpl, wl1h, wr1h, xlb, xr, N_NODES, D_EMB, D_IN);
    gat_wave_kernel<<<gatgrid, 256, 0, stream>>>(rowptr, esrcp, order, xlb, xr, att[0], bia[0], flag, hh, hl);
    // layer 2
    gemm_dual_kernel<<<gdual, 256, 0, stream>>>(hh, hl, wl2h, wr2h, xlb, xr, N_NODES, D_EMB, D_EMB);
    gat_wave_kernel<<<gatgrid, 256, 0, stream>>>(rowptr, esrcp, order, xlb, xr, att[1], bia[1], flag, hh, hl);
    // layer 3
    gemm_dual_kernel<<<gdual, 256, 0, stream>>>(hh, hl, wl3h, wr3h, xlb, xr, N_NODES, D_EMB, D_EMB);
    gat_wave_kernel<<<gatgrid, 256, 0, stream>>>(rowptr, esrcp, order, xlb, xr, att[2], bia[2], flag, hh, hl);

    // MLP: GEMM1 stores pair; GEMM2 fuses the A3 logit GEMV via atomics
    gemm_mlp64_kernel<0><<<gmlp, 256, 0, stream>>>(hh, hl, a1h, m1h, m1l, c1, nullptr, nullptr, flag, N_NODES, D_HID, D_EMB);
    gemm_mlp64_kernel<1><<<gmlp, 256, 0, stream>>>(m1h, m1l, a2h, nullptr, nullptr, c2, A3, logits, flag, N_NODES, D_HID, D_HID);
    softmax_kernel<<<1, 256, 0, stream>>>(logits, (float*)d_out);
}

// Round 11
// 373.114 us; speedup vs baseline: 1.2445x; 1.0664x over previous
//
#include <hip/hip_runtime.h>
#include <hip/hip_bf16.h>

#define N_NODES 10000
#define N_EDGES 160000
#define D_IN    128
#define D_EMB   512
#define D_HID   256
#define DMAX    512

typedef unsigned short u16;
typedef __attribute__((ext_vector_type(8))) short short8;
typedef __attribute__((ext_vector_type(4))) float floatx4;

__device__ __forceinline__ float bf2f(u16 u) {
    union { unsigned int i; float f; } v; v.i = ((unsigned int)u) << 16; return v.f;
}
__device__ __forceinline__ u16 f2bf(float f) {
    union { float f; unsigned int i; } v; v.f = f;
    unsigned int x = v.i;
    return (u16)((x + 0x7fffu + ((x >> 16) & 1u)) >> 16);  // RNE
}
__device__ __forceinline__ float inval(const void* p, int fp32, int idx) {
    return fp32 ? ((const float*)p)[idx] : bf2f(((const u16*)p)[idx]);
}

// async global->LDS, 16 bytes/lane; lds base must be wave-uniform.
__device__ __forceinline__ void gld_lds16(const u16* g, u16* l) {
    __builtin_amdgcn_global_load_lds((const __attribute__((address_space(1))) void*)g,
                                     (__attribute__((address_space(3))) void*)l,
                                     16, 0, 0);
}

// bijective XCD chunk remap (m204): blocks with bid%8==k get a contiguous
// range of work ids, so each XCD covers consecutive row-panels (A reuse in L2).
__device__ __forceinline__ int xcd_chunk(int bid, int total) {
    int q = total >> 3, r = total & 7;
    int xcd = bid & 7, idx = bid >> 3;
    return (xcd < r ? xcd * (q + 1) : r * (q + 1) + (xcd - r) * q) + idx;
}

// flag[0]: edge_index is int64-viewed-as-int32-pairs; flag[1]: floats are fp32
__device__ __forceinline__ int edge_src(const int* __restrict__ ei, int flg, int e) {
    int v = flg ? ei[2 * e] : ei[e];
    return min(max(v, 0), N_NODES - 1);
}
__device__ __forceinline__ int edge_dst(const int* __restrict__ ei, int flg, int e) {
    int v = flg ? ei[2 * N_EDGES + 2 * e] : ei[N_EDGES + e];
    return min(max(v, 0), N_NODES - 1);
}

// ---------------------------------------------------------------------------
__global__ void sentinel_kernel(float* out, int n) {
    int i = blockIdx.x * 256 + threadIdx.x;
    if (i < n) out[i] = 1.0f;   // => workspace too small
}

// detect dtypes + zero counts/logits/ghist, one dispatch (block 0 = census)
__global__ __launch_bounds__(256)
void detect_zero_kernel(const int* __restrict__ ei, const u16* __restrict__ xu,
                        int* flag, int* counts, float* logits, int* ghist) {
    int gid = blockIdx.x * 256 + threadIdx.x;
    for (int i = gid; i < N_NODES; i += gridDim.x * 256) { counts[i] = 0; logits[i] = 0.f; }
    for (int i = gid; i < DMAX; i += gridDim.x * 256) ghist[i] = 0;
    if (blockIdx.x != 0) return;
    __shared__ int s_or[256];
    __shared__ int s_cnt[256];
    int t = threadIdx.x;
    int v = 0;
    for (int k = t; k < 4096; k += 256) v |= ei[1 + 2 * k];
    int c = 0;
    for (int k = t; k < 4096; k += 256) {
        u16 u = xu[k];
        int ex = (u >> 7) & 0xFF;
        bool plaus = (u == 0) || (ex >= 64 && ex <= 191);
        if (!plaus) c++;
    }
    s_or[t] = v; s_cnt[t] = c;
    __syncthreads();
    for (int off = 128; off > 0; off >>= 1) {
        if (t < off) { s_or[t] |= s_or[t + off]; s_cnt[t] += s_cnt[t + off]; }
        __syncthreads();
    }
    if (t == 0) {
        flag[0] = (s_or[0] == 0) ? 1 : 0;
        flag[1] = (s_cnt[0] > 256) ? 1 : 0;
    }
}

// ---------------------------------------------------------------------------
// Fused preconversion (hi-only everywhere — R24 dropped the lo paths).
// ---------------------------------------------------------------------------
struct ConvJobs {
    const void* src[10];
    u16* dh[10];
    int rows[10], cols[10], trans[10];
    int cum[11];
    int njobs;
};

__global__ __launch_bounds__(256)
void convert_fused_kernel(ConvJobs jobs, const int* __restrict__ flag) {
    int idx = blockIdx.x * 256 + threadIdx.x;
    if (idx >= jobs.cum[jobs.njobs]) return;
    int fp32 = flag[1];
    int jb = 0;
    while (idx >= jobs.cum[jb + 1]) jb++;
    int local = idx - jobs.cum[jb];
    float v = inval(jobs.src[jb], fp32, local);
    u16 hi = f2bf(v);
    int o;
    if (jobs.trans[jb]) {
        int r = local / jobs.cols[jb], c = local % jobs.cols[jb];
        o = c * jobs.rows[jb] + r;
    } else o = local;
    jobs.dh[jb][o] = hi;
}

// ---------------------------------------------------------------------------
// CSR build
// ---------------------------------------------------------------------------
__global__ void count_edges_kernel(const int* __restrict__ ei, const int* __restrict__ flag,
                                   int* counts) {
    int e = blockIdx.x * 256 + threadIdx.x;
    if (e < N_EDGES) atomicAdd(&counts[edge_dst(ei, flag[0], e)], 1);
}

__global__ __launch_bounds__(256)
void scan_counts_kernel(int* counts, int* rowptr) {
    __shared__ int part[256];
    int tid = threadIdx.x;
    const int CH = 40;
    int base = tid * CH;
    int loc[CH];
    int s = 0;
    #pragma unroll
    for (int i = 0; i < CH; i++) {
        int idx = base + i;
        int c = (idx < N_NODES) ? counts[idx] : 0;
        loc[i] = s; s += c;
    }
    part[tid] = s;
    __syncthreads();
    for (int off = 1; off < 256; off <<= 1) {
        int v = part[tid];
        int add = (tid >= off) ? part[tid - off] : 0;
        __syncthreads();
        part[tid] = v + add;
        __syncthreads();
    }
    int pre = (tid > 0) ? part[tid - 1] : 0;
    #pragma unroll
    for (int i = 0; i < CH; i++) {
        int idx = base + i;
        if (idx < N_NODES) { int v = pre + loc[i]; rowptr[idx] = v; counts[idx] = v; }
    }
    if (tid == 255) rowptr[N_NODES] = part[255];
}

__global__ void fill_esrcp_kernel(const int* __restrict__ ei, const int* __restrict__ flag,
                                  int* counts, int* esrcp) {
    int e = blockIdx.x * 256 + threadIdx.x;
    if (e < N_EDGES) {
        int flg = flag[0];
        int pos = atomicAdd(&counts[edge_dst(ei, flg, e)], 1);
        if (pos >= 0 && pos < N_EDGES) esrcp[pos] = edge_src(ei, flg, e);
    }
}

// ---------------------------------------------------------------------------
// Degree-descending node order (LPT), multi-block (one node per thread).
// ---------------------------------------------------------------------------
__global__ __launch_bounds__(256)
void lpt_hist_kernel(const int* __restrict__ rowptr, int* __restrict__ ghist) {
    __shared__ int lhist[DMAX];
    int t = threadIdx.x;
    for (int d = t; d < DMAX; d += 256) lhist[d] = 0;
    __syncthreads();
    int n = blockIdx.x * 256 + t;
    if (n < N_NODES) {
        int d = min(rowptr[n + 1] - rowptr[n], DMAX - 1);
        atomicAdd(&lhist[d], 1);
    }
    __syncthreads();
    for (int d = t; d < DMAX; d += 256) {
        int c = lhist[d];
        if (c > 0) atomicAdd(&ghist[d], c);
    }
}

// doff[d] = number of nodes with degree > d (descending exclusive scan)
__global__ __launch_bounds__(256)
void lpt_scan_kernel(const int* __restrict__ ghist, int* __restrict__ doff) {
    __shared__ int part[256];
    int t = threadIdx.x;
    int d0 = (DMAX - 1) - 2 * t;        // thread t owns degrees d0, d0-1
    int d1 = d0 - 1;
    int c0 = ghist[d0], c1 = ghist[d1];
    part[t] = c0 + c1;
    __syncthreads();
    for (int o = 1; o < 256; o <<= 1) {
        int v = part[t];
        int add = (t >= o) ? part[t - o] : 0;
        __syncthreads();
        part[t] = v + add;
        __syncthreads();
    }
    int pre = (t > 0) ? part[t - 1] : 0;
    doff[d0] = pre;
    doff[d1] = pre + c0;
}

__global__ __launch_bounds__(256)
void lpt_scatter_kernel(const int* __restrict__ rowptr, int* __restrict__ doff,
                        int* __restrict__ order) {
    __shared__ int lhist[DMAX];
    __shared__ int lbase[DMAX];
    int t = threadIdx.x;
    for (int d = t; d < DMAX; d += 256) lhist[d] = 0;
    __syncthreads();
    int n = blockIdx.x * 256 + t;
    int dg = 0;
    if (n < N_NODES) {
        dg = min(rowptr[n + 1] - rowptr[n], DMAX - 1);
        atomicAdd(&lhist[dg], 1);
    }
    __syncthreads();
    // reserve a contiguous chunk per nonempty bucket; reset lhist for ranking
    for (int d = t; d < DMAX; d += 256) {
        int c = lhist[d];
        lbase[d] = (c > 0) ? atomicAdd(&doff[d], c) : 0;
        lhist[d] = 0;
    }
    __syncthreads();
    if (n < N_NODES) {
        int rank = atomicAdd(&lhist[dg], 1);
        int pos = lbase[dg] + rank;
        if (pos >= 0 && pos < N_NODES) order[pos] = n;
    }
}

// ---------------------------------------------------------------------------
// Dual 128x128-tile GEMM, single MFMA pass (R24: lo-path dropped), two
// K-steps per barrier pair (R22), XCD-chunk remap (R23). LDS 32KB -> 5/CU.
// ---------------------------------------------------------------------------
__global__ __launch_bounds__(256)
void gemm_dual_kernel(const u16* __restrict__ Ah,
                      const u16* __restrict__ B0h, const u16* __restrict__ B1h,
                      u16* __restrict__ C0, float* __restrict__ C1,
                      int M, int N, int K)
{
    __shared__ u16 sAh[2][128 * 32];
    __shared__ u16 sBh[2][128 * 32];
    int nb = N >> 7;
    int nx = 2 * nb;
    int ny = (M + 127) >> 7;
    int w = xcd_chunk((int)blockIdx.x, nx * ny);
    int by = w / nx;
    int bxh = w - by * nx;
    int half = bxh >= nb;
    int bx = half ? (bxh - nb) : bxh;
    const u16* BTh = half ? B1h : B0h;

    int tid = threadIdx.x;
    int lane = tid & 63, wv = tid >> 6;
    int l15 = lane & 15, l4 = lane >> 4;
    int wr = (wv >> 1) * 64, wc = (wv & 1) * 64;
    int m0 = by * 128, n0 = bx * 128;

    int i0 = tid, i1 = tid + 256;
    int r0 = i0 >> 2, b0 = i0 & 3, sb0 = b0 ^ ((r0 >> 1) & 3);
    int r1 = i1 >> 2, b1 = i1 & 3, sb1 = b1 ^ ((r1 >> 1) & 3);
    int gr0 = min(m0 + r0, M - 1), gr1 = min(m0 + r1, M - 1);
    const u16* a0p = Ah + (size_t)gr0 * K + sb0 * 8;
    const u16* a1p = Ah + (size_t)gr1 * K + sb1 * 8;
    const u16* bb0p = BTh + (size_t)(n0 + r0) * K + sb0 * 8;
    const u16* bb1p = BTh + (size_t)(n0 + r1) * K + sb1 * 8;
    int lo0 = wv * 64 * 8;              // wave chunk (elements) within a set
    int lo1 = (256 + wv * 64) * 8;

    floatx4 acc[4][4];
    #pragma unroll
    for (int i = 0; i < 4; i++)
        #pragma unroll
        for (int j = 0; j < 4; j++) acc[i][j] = (floatx4){0.f, 0.f, 0.f, 0.f};

    int aoff[4], boff[4];
    #pragma unroll
    for (int i = 0; i < 4; i++) {
        int arow = wr + i * 16 + l15;
        aoff[i] = arow * 32 + ((l4 ^ ((arow >> 1) & 3)) << 3);
        int bcol = wc + i * 16 + l15;
        boff[i] = bcol * 32 + ((l4 ^ ((bcol >> 1) & 3)) << 3);
    }

    for (int kk = 0; kk < K; kk += 64) {
        __syncthreads();
        // set 0 <- kk
        gld_lds16(a0p + kk, &sAh[0][lo0]);
        gld_lds16(a1p + kk, &sAh[0][lo1]);
        gld_lds16(bb0p + kk, &sBh[0][lo0]);
        gld_lds16(bb1p + kk, &sBh[0][lo1]);
        // set 1 <- kk+32
        gld_lds16(a0p + kk + 32, &sAh[1][lo0]);
        gld_lds16(a1p + kk + 32, &sAh[1][lo1]);
        gld_lds16(bb0p + kk + 32, &sBh[1][lo0]);
        gld_lds16(bb1p + kk + 32, &sBh[1][lo1]);
        __syncthreads();

        #pragma unroll
        for (int s = 0; s < 2; s++) {
            short8 ah[4];
            #pragma unroll
            for (int i = 0; i < 4; i++) ah[i] = *(const short8*)(&sAh[s][aoff[i]]);
            #pragma unroll
            for (int j = 0; j < 4; j++) {
                short8 bh = *(const short8*)(&sBh[s][boff[j]]);
                #pragma unroll
                for (int i = 0; i < 4; i++)
                    acc[i][j] = __builtin_amdgcn_mfma_f32_16x16x32_bf16(ah[i], bh, acc[i][j], 0, 0, 0);
            }
        }
    }

    #pragma unroll
    for (int j = 0; j < 4; j++) {
        int col = n0 + wc + j * 16 + l15;
        #pragma unroll
        for (int i = 0; i < 4; i++) {
            #pragma unroll
            for (int r = 0; r < 4; r++) {
                int row = m0 + wr + i * 16 + l4 * 4 + r;
                if (row < M) {
                    if (half) C1[(size_t)row * N + col] = acc[i][j][r];
                    else      C0[(size_t)row * N + col] = f2bf(acc[i][j][r]);
                }
            }
        }
    }
}

// ---------------------------------------------------------------------------
// MLP GEMM, 64x64 tile, single MFMA pass, two K-steps per barrier pair,
// XCD-chunk remap. FUSE=0: store hi. FUSE=1: fused logit GEMV via atomics.
// ---------------------------------------------------------------------------
template<int FUSE>
__global__ __launch_bounds__(256)
void gemm_mlp64_kernel(const u16* __restrict__ Ah,
                       const u16* __restrict__ BTh,
                       u16* __restrict__ Ch,
                       const void* __restrict__ biasraw,
                       const void* __restrict__ A3raw, float* __restrict__ logits,
                       const int* __restrict__ flag,
                       int M, int N, int K)
{
    __shared__ u16 sAh[2][64 * 32];
    __shared__ u16 sBh[2][64 * 32];
    int tid = threadIdx.x;
    int lane = tid & 63, wv = tid >> 6;
    int l15 = lane & 15, l4 = lane >> 4;
    int nx = N >> 6;
    int ny = (M + 63) >> 6;
    int w = xcd_chunk((int)blockIdx.x, nx * ny);
    int by = w / nx;
    int bx = w - by * nx;
    int m0 = by * 64, n0 = bx * 64;

    int r = (tid >> 2), blk = tid & 3, sb = blk ^ ((r >> 1) & 3);
    int gr = min(m0 + r, M - 1);
    const u16* ap = Ah + (size_t)gr * K + sb * 8;
    const u16* bp = BTh + (size_t)(n0 + r) * K + sb * 8;
    int lo = wv * 64 * 8;

    floatx4 acc[4];
    #pragma unroll
    for (int j = 0; j < 4; j++) acc[j] = (floatx4){0.f, 0.f, 0.f, 0.f};

    int arow = wv * 16 + l15;
    int aoff = arow * 32 + ((l4 ^ ((arow >> 1) & 3)) << 3);
    int boff[4];
    #pragma unroll
    for (int j = 0; j < 4; j++) {
        int bcol = j * 16 + l15;
        boff[j] = bcol * 32 + ((l4 ^ ((bcol >> 1) & 3)) << 3);
    }

    for (int kk = 0; kk < K; kk += 64) {
        __syncthreads();
        gld_lds16(ap + kk, &sAh[0][lo]);
        gld_lds16(bp + kk, &sBh[0][lo]);
        gld_lds16(ap + kk + 32, &sAh[1][lo]);
        gld_lds16(bp + kk + 32, &sBh[1][lo]);
        __syncthreads();

        #pragma unroll
        for (int s = 0; s < 2; s++) {
            short8 ah = *(const short8*)(&sAh[s][aoff]);
            #pragma unroll
            for (int j = 0; j < 4; j++) {
                short8 bh = *(const short8*)(&sBh[s][boff[j]]);
                acc[j] = __builtin_amdgcn_mfma_f32_16x16x32_bf16(ah, bh, acc[j], 0, 0, 0);
            }
        }
    }

    const int fp32 = flag[1];
    float lsum[4] = {0.f, 0.f, 0.f, 0.f};
    #pragma unroll
    for (int j = 0; j < 4; j++) {
        int col = n0 + j * 16 + l15;
        float bv = inval(biasraw, fp32, col);
        float a3 = FUSE ? inval(A3raw, fp32, col) : 0.f;
        #pragma unroll
        for (int rr = 0; rr < 4; rr++) {
            int row = m0 + wv * 16 + l4 * 4 + rr;
            if (row < M) {
                float v = acc[j][rr] + bv;
                v = v > 0.f ? v : 0.1f * v;
                if (FUSE) {
                    lsum[rr] += v * a3;
                } else {
                    Ch[(size_t)row * N + col] = f2bf(v);
                }
            }
        }
    }
    if (FUSE) {
        #pragma unroll
        for (int rr = 0; rr < 4; rr++) {
            float s = lsum[rr];
            s += __shfl_xor(s, 1);
            s += __shfl_xor(s, 2);
            s += __shfl_xor(s, 4);
            s += __shfl_xor(s, 8);
            int row = m0 + wv * 16 + l4 * 4 + rr;
            if (l15 == 0 && row < M) atomicAdd(&logits[row], s);
        }
    }
}

// ---------------------------------------------------------------------------
// GATv2 (R20 body; R24: hi-only output — pl pack/store dropped):
// wave-per-node, LPT node order, depth-1 register pipeline, masked padding.
// R16/R17/R21 all proved TLP>ILP for this kernel; do not re-trade.
// ---------------------------------------------------------------------------
__global__ __launch_bounds__(256)
void gat_wave_kernel(const int* __restrict__ rowptr, const int* __restrict__ esrcp,
                     const int* __restrict__ order,
                     const u16* __restrict__ xlb, const float* __restrict__ xr,
                     const void* __restrict__ att, const void* __restrict__ bias,
                     const int* __restrict__ flag,
                     u16* __restrict__ hh)
{
    int lane = threadIdx.x & 63, wv = threadIdx.x >> 6;
    int slot = blockIdx.x * 4 + wv;
    if (slot >= N_NODES) return;
    int n = order[slot];
    n = min(max(n, 0), N_NODES - 1);
    int fp32 = flag[1];
    int d0 = lane * 8;
    int l3 = lane & 3;

    int beg = rowptr[n], end = rowptr[n + 1];
    int deg = end - beg;
    int ng = (deg + 3) >> 2;            // groups of up to 4 edges (padded)

    const u16* xbase = xlb + d0;        // lane's 16B chunk within any row

    const float* xrr = xr + (size_t)n * D_EMB;
    float4 r0 = *(const float4*)(xrr + d0);
    float4 r1 = *(const float4*)(xrr + d0 + 4);
    float xrv[8] = {r0.x, r0.y, r0.z, r0.w, r1.x, r1.y, r1.z, r1.w};
    float attv[8];
    #pragma unroll
    for (int k = 0; k < 8; k++) attv[k] = inval(att, fp32, d0 + k);

    float m_run = -3.4e38f, s_run = 0.f;
    float acc[8] = {0.f, 0.f, 0.f, 0.f, 0.f, 0.f, 0.f, 0.f};

    auto ldidx = [&](int g) -> int {
        return esrcp[min(beg + 4 * g + l3, N_EDGES - 1)];
    };

    if (ng > 0) {
        // prologue: idx group 0 -> rows group 0 in flight; idx group 1 in flight
        int i0 = ldidx(0);
        uint4 cu0, cu1, cu2, cu3;
        {
            int s0 = __shfl(i0, 0), s1 = __shfl(i0, 1), s2 = __shfl(i0, 2), s3 = __shfl(i0, 3);
            cu0 = *(const uint4*)(xbase + (size_t)s0 * D_EMB);
            cu1 = *(const uint4*)(xbase + (size_t)s1 * D_EMB);
            cu2 = *(const uint4*)(xbase + (size_t)s2 * D_EMB);
            cu3 = *(const uint4*)(xbase + (size_t)s3 * D_EMB);
        }
        int nidx = (ng > 1) ? ldidx(1) : 0;

        for (int g = 0; g < ng; g++) {
            // issue next group's row gathers + idx for group g+2 FIRST, so their
            // latency overlaps this group's compute.
            uint4 nu0, nu1, nu2, nu3;
            int nidx2 = 0;
            bool have_next = (g + 1 < ng);
            if (have_next) {
                int t0 = __shfl(nidx, 0), t1 = __shfl(nidx, 1),
                    t2 = __shfl(nidx, 2), t3 = __shfl(nidx, 3);
                nu0 = *(const uint4*)(xbase + (size_t)t0 * D_EMB);
                nu1 = *(const uint4*)(xbase + (size_t)t1 * D_EMB);
                nu2 = *(const uint4*)(xbase + (size_t)t2 * D_EMB);
                nu3 = *(const uint4*)(xbase + (size_t)t3 * D_EMB);
                if (g + 2 < ng) nidx2 = ldidx(g + 2);
            }

            // compute group g from registers loaded last iteration
            union { uint4 q; u16 us[8]; } u0, u1, u2, u3;
            u0.q = cu0; u1.q = cu1; u2.q = cu2; u3.q = cu3;
            float v0[8], v1[8], v2[8], v3[8];
            #pragma unroll
            for (int k = 0; k < 8; k++) {
                v0[k] = bf2f(u0.us[k]); v1[k] = bf2f(u1.us[k]);
                v2[k] = bf2f(u2.us[k]); v3[k] = bf2f(u3.us[k]);
            }
            float e0 = 0.f, e1 = 0.f, e2 = 0.f, e3 = 0.f;
            #pragma unroll
            for (int k = 0; k < 8; k++) {
                float t0 = v0[k] + xrv[k]; t0 = fmaxf(t0, 0.2f * t0); e0 += attv[k] * t0;
                float t1 = v1[k] + xrv[k]; t1 = fmaxf(t1, 0.2f * t1); e1 += attv[k] * t1;
                float t2 = v2[k] + xrv[k]; t2 = fmaxf(t2, 0.2f * t2); e2 += attv[k] * t2;
                float t3 = v3[k] + xrv[k]; t3 = fmaxf(t3, 0.2f * t3); e3 += attv[k] * t3;
            }
            #pragma unroll
            for (int o = 32; o > 0; o >>= 1) {
                e0 += __shfl_xor(e0, o);
                e1 += __shfl_xor(e1, o);
                e2 += __shfl_xor(e2, o);
                e3 += __shfl_xor(e3, o);
            }
            // mask padded (dead) edges of the final group
            int base = beg + 4 * g;
            if (base + 1 >= end) e1 = -3.4e38f;
            if (base + 2 >= end) e2 = -3.4e38f;
            if (base + 3 >= end) e3 = -3.4e38f;
            // group-batched online softmax: one rescale per 4 edges
            float m4 = fmaxf(fmaxf(e0, e1), fmaxf(e2, e3));
            float m_new = fmaxf(m_run, m4);
            float sc = __expf(m_run - m_new);          // 0 on first group
            float w0 = __expf(e0 - m_new), w1 = __expf(e1 - m_new);
            float w2 = __expf(e2 - m_new), w3 = __expf(e3 - m_new);
            s_run = s_run * sc + (w0 + w1) + (w2 + w3);
            #pragma unroll
            for (int k = 0; k < 8; k++)
                acc[k] = acc[k] * sc + w0 * v0[k] + w1 * v1[k] + w2 * v2[k] + w3 * v3[k];
            m_run = m_new;

            if (have_next) {
                cu0 = nu0; cu1 = nu1; cu2 = nu2; cu3 = nu3;
                nidx = nidx2;
            }
        }
    }

    float inv = 1.f / (s_run + 1e-16f);
    union { uint4 q; u16 us[8]; } ph;
    #pragma unroll
    for (int k = 0; k < 8; k++) {
        float h = tanhf(acc[k] * inv + inval(bias, fp32, d0 + k));
        ph.us[k] = f2bf(h);
    }
    *(uint4*)(&hh[(size_t)n * D_EMB + d0]) = ph.q;
}

// ---------------------------------------------------------------------------
__global__ __launch_bounds__(256)
void softmax_kernel(const float* __restrict__ logits, float* __restrict__ out)
{
    __shared__ float red[4];
    __shared__ float s_m, s_s;
    int tid = threadIdx.x, lane = tid & 63, wv = tid >> 6;
    float m = -3.4e38f;
    for (int i = tid; i < N_NODES; i += 256) m = fmaxf(m, logits[i]);
    #pragma unroll
    for (int o = 32; o > 0; o >>= 1) m = fmaxf(m, __shfl_down(m, o));
    if (lane == 0) red[wv] = m;
    __syncthreads();
    if (tid == 0) {
        float mm = red[0];
        for (int i = 1; i < 4; i++) mm = fmaxf(mm, red[i]);
        s_m = mm;
    }
    __syncthreads();
    float mm = s_m;
    float s = 0.f;
    for (int i = tid; i < N_NODES; i += 256) s += __expf(logits[i] - mm);
    #pragma unroll
    for (int o = 32; o > 0; o >>= 1) s += __shfl_down(s, o);
    if (lane == 0) red[wv] = s;
    __syncthreads();
    if (tid == 0) {
        float ss = 0.f;
        for (int i = 0; i < 4; i++) ss += red[i];
        s_s = ss;
    }
    __syncthreads();
    float invs = 1.f / s_s;
    for (int i = tid; i < N_NODES; i += 256) out[i] = __expf(logits[i] - mm) * invs;
}

// ---------------------------------------------------------------------------
extern "C" void kernel_launch(void* const* d_in, const int* in_sizes, int n_in,
                              void* d_out, int out_size, void* d_ws, size_t ws_size,
                              hipStream_t stream)
{
    const void* x   = d_in[0];
    const int*  ei  = (const int*)d_in[1];
    const void* Wl[3]  = {d_in[2],  d_in[6],  d_in[10]};
    const void* Wr[3]  = {d_in[3],  d_in[7],  d_in[11]};
    const void* att[3] = {d_in[4],  d_in[8],  d_in[12]};
    const void* bia[3] = {d_in[5],  d_in[9],  d_in[13]};
    const void* A1 = d_in[14];
    const void* c1 = d_in[15];
    const void* A2 = d_in[16];
    const void* c2 = d_in[17];
    const void* A3 = d_in[18];

    char* p = (char*)d_ws;
    auto alloc = [&](size_t bytes) {
        char* r = p;
        p += (bytes + 255) & ~(size_t)255;
        return r;
    };
    u16*   xlb    = (u16*)  alloc((size_t)N_NODES * D_EMB * 4);   // bf16 xl (first half) + MLP aliases
    float* xr     = (float*)alloc((size_t)N_NODES * D_EMB * 4);
    u16*   hh     = (u16*)  alloc((size_t)N_NODES * D_EMB * 2);
    int*   esrcp  = (int*)  alloc((size_t)N_EDGES * 4);
    int*   rowptr = (int*)  alloc((size_t)(N_NODES + 1) * 4);
    int*   counts = (int*)  alloc((size_t)N_NODES * 4);
    int*   flag   = (int*)  alloc(256);
    float* logits = (float*)alloc((size_t)N_NODES * 4);
    int*   ghist  = (int*)  alloc(DMAX * 4);
    int*   doff   = (int*)  alloc(DMAX * 4);
    int*   order  = (int*)  alloc((size_t)N_NODES * 4);
    u16* wl1h = (u16*)alloc(D_EMB * D_IN  * 2);
    u16* wr1h = (u16*)alloc(D_EMB * D_IN  * 2);
    u16* wl2h = (u16*)alloc(D_EMB * D_EMB * 2);
    u16* wr2h = (u16*)alloc(D_EMB * D_EMB * 2);
    u16* wl3h = (u16*)alloc(D_EMB * D_EMB * 2);
    u16* wr3h = (u16*)alloc(D_EMB * D_EMB * 2);
    u16* a1h  = (u16*)alloc(D_EMB * D_HID * 2);
    u16* a2h  = (u16*)alloc(D_HID * D_HID * 2);
    u16* xph  = (u16*)alloc((size_t)N_NODES * D_IN * 2);
    size_t needed = (size_t)(p - (char*)d_ws);

    if (ws_size < needed) {
        sentinel_kernel<<<(out_size + 255) / 256, 256, 0, stream>>>((float*)d_out, out_size);
        return;
    }

    u16* m1h = (u16*)xlb;   // MLP hidden reuses xlb

    // detect + zero counts/logits/ghist fused
    detect_zero_kernel<<<40, 256, 0, stream>>>(ei, (const u16*)x, flag, counts, logits, ghist);
    count_edges_kernel<<<(N_EDGES + 255) / 256, 256, 0, stream>>>(ei, flag, counts);
    scan_counts_kernel<<<1, 256, 0, stream>>>(counts, rowptr);
    fill_esrcp_kernel<<<(N_EDGES + 255) / 256, 256, 0, stream>>>(ei, flag, counts, esrcp);

    // LPT node order, multi-block (one node per thread; reused by all 3 layers)
    int nblk = (N_NODES + 255) / 256;
    lpt_hist_kernel<<<nblk, 256, 0, stream>>>(rowptr, ghist);
    lpt_scan_kernel<<<1, 256, 0, stream>>>(ghist, doff);
    lpt_scatter_kernel<<<nblk, 256, 0, stream>>>(rowptr, doff, order);

    // fused preconversion: everything -> bf16 hi (weights transposed)
    ConvJobs jobs;
    auto setjob = [&](int i, const void* s, u16* dh, int r, int c, int tr) {
        jobs.src[i] = s; jobs.dh[i] = dh;
        jobs.rows[i] = r; jobs.cols[i] = c; jobs.trans[i] = tr;
    };
    setjob(0, x,     xph,  N_NODES, D_IN, 0);
    setjob(1, Wl[0], wl1h, D_IN,  D_EMB, 1);
    setjob(2, Wr[0], wr1h, D_IN,  D_EMB, 1);
    setjob(3, Wl[1], wl2h, D_EMB, D_EMB, 1);
    setjob(4, Wr[1], wr2h, D_EMB, D_EMB, 1);
    setjob(5, Wl[2], wl3h, D_EMB, D_EMB, 1);
    setjob(6, Wr[2], wr3h, D_EMB, D_EMB, 1);
    setjob(7, A1,    a1h,  D_EMB, D_HID, 1);
    setjob(8, A2,    a2h,  D_HID, D_HID, 1);
    jobs.njobs = 9;
    jobs.cum[0] = 0;
    for (int i = 0; i < 9; i++) jobs.cum[i + 1] = jobs.cum[i] + jobs.rows[i] * jobs.cols[i];
    int ctotal = jobs.cum[9];
    convert_fused_kernel<<<(ctotal + 255) / 256, 256, 0, stream>>>(jobs, flag);

    int gdual = (2 * D_EMB / 128) * ((N_NODES + 127) / 128);   // 8 * 79 = 632
    int gmlp  = (D_HID / 64) * ((N_NODES + 63) / 64);          // 4 * 157 = 628
    int gatgrid = (N_NODES + 3) / 4;

    // layer 1
    gemm_dual_kernel<<<gdual, 256, 0, stream>>>(xph, wl1h, wr1h, xlb, xr, N_NODES, D_EMB, D_IN);
    gat_wave_kernel<<<gatgrid, 256, 0, stream>>>(rowptr, esrcp, order, xlb, xr, att[0], bia[0], flag, hh);
    // layer 2
    gemm_dual_kernel<<<gdual, 256, 0, stream>>>(hh, wl2h, wr2h, xlb, xr, N_NODES, D_EMB, D_EMB);
    gat_wave_kernel<<<gatgrid, 256, 0, stream>>>(rowptr, esrcp, order, xlb, xr, att[1], bia[1], flag, hh);
    // layer 3
    gemm_dual_kernel<<<gdual, 256, 0, stream>>>(hh, wl3h, wr3h, xlb, xr, N_NODES, D_EMB, D_EMB);
    gat_wave_kernel<<<gatgrid, 256, 0, stream>>>(rowptr, esrcp, order, xlb, xr, att[2], bia[2], flag, hh);

    // MLP: GEMM1 stores hi; GEMM2 fuses the A3 logit GEMV via atomics
    gemm_mlp64_kernel<0><<<gmlp, 256, 0, stream>>>(hh, a1h, m1h, c1, nullptr, nullptr, flag, N_NODES, D_HID, D_EMB);
    gemm_mlp64_kernel<1><<<gmlp, 256, 0, stream>>>(m1h, a2h, nullptr, c2, A3, logits, flag, N_NODES, D_HID, D_HID);
    softmax_kernel<<<1, 256, 0, stream>>>(logits, (float*)d_out);
}

// Round 12
// 365.432 us; speedup vs baseline: 1.2706x; 1.0210x over previous
//
#include <hip/hip_runtime.h>
#include <hip/hip_bf16.h>

#define N_NODES 10000
#define N_EDGES 160000
#define D_IN    128
#define D_EMB   512
#define D_HID   256
#define DMAX    512

typedef unsigned short u16;
typedef __attribute__((ext_vector_type(8))) short short8;
typedef __attribute__((ext_vector_type(4))) float floatx4;

__device__ __forceinline__ float bf2f(u16 u) {
    union { unsigned int i; float f; } v; v.i = ((unsigned int)u) << 16; return v.f;
}
__device__ __forceinline__ u16 f2bf(float f) {
    union { float f; unsigned int i; } v; v.f = f;
    unsigned int x = v.i;
    return (u16)((x + 0x7fffu + ((x >> 16) & 1u)) >> 16);  // RNE
}
__device__ __forceinline__ float inval(const void* p, int fp32, int idx) {
    return fp32 ? ((const float*)p)[idx] : bf2f(((const u16*)p)[idx]);
}

// async global->LDS, 16 bytes/lane; lds base must be wave-uniform.
__device__ __forceinline__ void gld_lds16(const u16* g, u16* l) {
    __builtin_amdgcn_global_load_lds((const __attribute__((address_space(1))) void*)g,
                                     (__attribute__((address_space(3))) void*)l,
                                     16, 0, 0);
}

// bijective XCD chunk remap (m204): blocks with bid%8==k get a contiguous
// range of work ids, so each XCD covers consecutive row-panels (A reuse in L2).
__device__ __forceinline__ int xcd_chunk(int bid, int total) {
    int q = total >> 3, r = total & 7;
    int xcd = bid & 7, idx = bid >> 3;
    return (xcd < r ? xcd * (q + 1) : r * (q + 1) + (xcd - r) * q) + idx;
}

// flag[0]: edge_index is int64-viewed-as-int32-pairs; flag[1]: floats are fp32
__device__ __forceinline__ int edge_src(const int* __restrict__ ei, int flg, int e) {
    int v = flg ? ei[2 * e] : ei[e];
    return min(max(v, 0), N_NODES - 1);
}
__device__ __forceinline__ int edge_dst(const int* __restrict__ ei, int flg, int e) {
    int v = flg ? ei[2 * N_EDGES + 2 * e] : ei[N_EDGES + e];
    return min(max(v, 0), N_NODES - 1);
}

// ---------------------------------------------------------------------------
__global__ void sentinel_kernel(float* out, int n) {
    int i = blockIdx.x * 256 + threadIdx.x;
    if (i < n) out[i] = 1.0f;   // => workspace too small
}

// detect dtypes + zero counts/logits, one dispatch (block 0 = census)
__global__ __launch_bounds__(256)
void detect_zero_kernel(const int* __restrict__ ei, const u16* __restrict__ xu,
                        int* flag, int* counts, float* logits) {
    int gid = blockIdx.x * 256 + threadIdx.x;
    for (int i = gid; i < N_NODES; i += gridDim.x * 256) { counts[i] = 0; logits[i] = 0.f; }
    if (blockIdx.x != 0) return;
    __shared__ int s_or[256];
    __shared__ int s_cnt[256];
    int t = threadIdx.x;
    int v = 0;
    for (int k = t; k < 4096; k += 256) v |= ei[1 + 2 * k];
    int c = 0;
    for (int k = t; k < 4096; k += 256) {
        u16 u = xu[k];
        int ex = (u >> 7) & 0xFF;
        bool plaus = (u == 0) || (ex >= 64 && ex <= 191);
        if (!plaus) c++;
    }
    s_or[t] = v; s_cnt[t] = c;
    __syncthreads();
    for (int off = 128; off > 0; off >>= 1) {
        if (t < off) { s_or[t] |= s_or[t + off]; s_cnt[t] += s_cnt[t + off]; }
        __syncthreads();
    }
    if (t == 0) {
        flag[0] = (s_or[0] == 0) ? 1 : 0;
        flag[1] = (s_cnt[0] > 256) ? 1 : 0;
    }
}

// ---------------------------------------------------------------------------
// Fused edge-count + preconversion (R25): blocks [0,EBLK) count edges;
// blocks [EBLK, EBLK+convblocks) convert inputs to bf16 hi (weights transposed).
// Both depend only on detect_zero's flag.
// ---------------------------------------------------------------------------
#define EBLK ((N_EDGES + 255) / 256)

struct ConvJobs {
    const void* src[10];
    u16* dh[10];
    int rows[10], cols[10], trans[10];
    int cum[11];
    int njobs;
};

__global__ __launch_bounds__(256)
void count_convert_kernel(const int* __restrict__ ei, int* counts,
                          ConvJobs jobs, const int* __restrict__ flag) {
    int b = blockIdx.x;
    if (b < EBLK) {
        int e = b * 256 + threadIdx.x;
        if (e < N_EDGES) atomicAdd(&counts[edge_dst(ei, flag[0], e)], 1);
        return;
    }
    int idx = (b - EBLK) * 256 + threadIdx.x;
    if (idx >= jobs.cum[jobs.njobs]) return;
    int fp32 = flag[1];
    int jb = 0;
    while (idx >= jobs.cum[jb + 1]) jb++;
    int local = idx - jobs.cum[jb];
    float v = inval(jobs.src[jb], fp32, local);
    u16 hi = f2bf(v);
    int o;
    if (jobs.trans[jb]) {
        int r = local / jobs.cols[jb], c = local % jobs.cols[jb];
        o = c * jobs.rows[jb] + r;
    } else o = local;
    jobs.dh[jb][o] = hi;
}

// ---------------------------------------------------------------------------
// CSR scan + LPT degree-histogram + descending scan (R25 fusion of
// scan_counts + lpt_hist + lpt_scan; single block, all in LDS).
// Outputs: rowptr, counts(=running offsets), doff.
// ---------------------------------------------------------------------------
__global__ __launch_bounds__(256)
void scan_counts_kernel(int* counts, int* rowptr, int* doff) {
    __shared__ int part[256];
    __shared__ int hist[DMAX];
    int tid = threadIdx.x;
    for (int d = tid; d < DMAX; d += 256) hist[d] = 0;
    __syncthreads();
    const int CH = 40;
    int base = tid * CH;
    int loc[CH];
    int s = 0;
    #pragma unroll
    for (int i = 0; i < CH; i++) {
        int idx = base + i;
        int c = (idx < N_NODES) ? counts[idx] : 0;
        if (idx < N_NODES) atomicAdd(&hist[min(c, DMAX - 1)], 1);
        loc[i] = s; s += c;
    }
    part[tid] = s;
    __syncthreads();
    for (int off = 1; off < 256; off <<= 1) {
        int v = part[tid];
        int add = (tid >= off) ? part[tid - off] : 0;
        __syncthreads();
        part[tid] = v + add;
        __syncthreads();
    }
    int pre = (tid > 0) ? part[tid - 1] : 0;
    #pragma unroll
    for (int i = 0; i < CH; i++) {
        int idx = base + i;
        if (idx < N_NODES) { int v = pre + loc[i]; rowptr[idx] = v; counts[idx] = v; }
    }
    if (tid == 255) rowptr[N_NODES] = part[255];
    __syncthreads();
    // descending exclusive scan over hist: doff[d] = #nodes with degree > d
    int d0 = (DMAX - 1) - 2 * tid;      // thread owns degrees d0, d0-1
    int d1 = d0 - 1;
    int c0 = hist[d0], c1 = hist[d1];
    __syncthreads();
    part[tid] = c0 + c1;
    __syncthreads();
    for (int o = 1; o < 256; o <<= 1) {
        int v = part[tid];
        int add = (tid >= o) ? part[tid - o] : 0;
        __syncthreads();
        part[tid] = v + add;
        __syncthreads();
    }
    int pre2 = (tid > 0) ? part[tid - 1] : 0;
    doff[d0] = pre2;
    doff[d1] = pre2 + c0;
}

// ---------------------------------------------------------------------------
// Fused esrcp-fill + LPT scatter (R25): blocks [0,nblk) scatter order[];
// blocks [nblk, nblk+EBLK) fill esrcp. Both depend only on scan output.
// ---------------------------------------------------------------------------
__global__ __launch_bounds__(256)
void fill_scatter_kernel(const int* __restrict__ ei, const int* __restrict__ flag,
                         const int* __restrict__ rowptr,
                         int* counts, int* esrcp, int* doff, int* order) {
    int b = blockIdx.x;
    int nblk = (N_NODES + 255) / 256;
    int t = threadIdx.x;
    if (b < nblk) {
        __shared__ int lhist[DMAX];
        __shared__ int lbase[DMAX];
        for (int d = t; d < DMAX; d += 256) lhist[d] = 0;
        __syncthreads();
        int n = b * 256 + t;
        int dg = 0;
        if (n < N_NODES) {
            dg = min(rowptr[n + 1] - rowptr[n], DMAX - 1);
            atomicAdd(&lhist[dg], 1);
        }
        __syncthreads();
        for (int d = t; d < DMAX; d += 256) {
            int c = lhist[d];
            lbase[d] = (c > 0) ? atomicAdd(&doff[d], c) : 0;
            lhist[d] = 0;
        }
        __syncthreads();
        if (n < N_NODES) {
            int rank = atomicAdd(&lhist[dg], 1);
            int pos = lbase[dg] + rank;
            if (pos >= 0 && pos < N_NODES) order[pos] = n;
        }
        return;
    }
    int e = (b - nblk) * 256 + t;
    if (e < N_EDGES) {
        int flg = flag[0];
        int pos = atomicAdd(&counts[edge_dst(ei, flg, e)], 1);
        if (pos >= 0 && pos < N_EDGES) esrcp[pos] = edge_src(ei, flg, e);
    }
}

// ---------------------------------------------------------------------------
// Dual 128x128-tile GEMM, single MFMA pass (R24), two K-steps per barrier
// pair (R22), XCD-chunk remap (R23).
// ---------------------------------------------------------------------------
__global__ __launch_bounds__(256)
void gemm_dual_kernel(const u16* __restrict__ Ah,
                      const u16* __restrict__ B0h, const u16* __restrict__ B1h,
                      u16* __restrict__ C0, float* __restrict__ C1,
                      int M, int N, int K)
{
    __shared__ u16 sAh[2][128 * 32];
    __shared__ u16 sBh[2][128 * 32];
    int nb = N >> 7;
    int nx = 2 * nb;
    int ny = (M + 127) >> 7;
    int w = xcd_chunk((int)blockIdx.x, nx * ny);
    int by = w / nx;
    int bxh = w - by * nx;
    int half = bxh >= nb;
    int bx = half ? (bxh - nb) : bxh;
    const u16* BTh = half ? B1h : B0h;

    int tid = threadIdx.x;
    int lane = tid & 63, wv = tid >> 6;
    int l15 = lane & 15, l4 = lane >> 4;
    int wr = (wv >> 1) * 64, wc = (wv & 1) * 64;
    int m0 = by * 128, n0 = bx * 128;

    int i0 = tid, i1 = tid + 256;
    int r0 = i0 >> 2, b0 = i0 & 3, sb0 = b0 ^ ((r0 >> 1) & 3);
    int r1 = i1 >> 2, b1 = i1 & 3, sb1 = b1 ^ ((r1 >> 1) & 3);
    int gr0 = min(m0 + r0, M - 1), gr1 = min(m0 + r1, M - 1);
    const u16* a0p = Ah + (size_t)gr0 * K + sb0 * 8;
    const u16* a1p = Ah + (size_t)gr1 * K + sb1 * 8;
    const u16* bb0p = BTh + (size_t)(n0 + r0) * K + sb0 * 8;
    const u16* bb1p = BTh + (size_t)(n0 + r1) * K + sb1 * 8;
    int lo0 = wv * 64 * 8;              // wave chunk (elements) within a set
    int lo1 = (256 + wv * 64) * 8;

    floatx4 acc[4][4];
    #pragma unroll
    for (int i = 0; i < 4; i++)
        #pragma unroll
        for (int j = 0; j < 4; j++) acc[i][j] = (floatx4){0.f, 0.f, 0.f, 0.f};

    int aoff[4], boff[4];
    #pragma unroll
    for (int i = 0; i < 4; i++) {
        int arow = wr + i * 16 + l15;
        aoff[i] = arow * 32 + ((l4 ^ ((arow >> 1) & 3)) << 3);
        int bcol = wc + i * 16 + l15;
        boff[i] = bcol * 32 + ((l4 ^ ((bcol >> 1) & 3)) << 3);
    }

    for (int kk = 0; kk < K; kk += 64) {
        __syncthreads();
        // set 0 <- kk
        gld_lds16(a0p + kk, &sAh[0][lo0]);
        gld_lds16(a1p + kk, &sAh[0][lo1]);
        gld_lds16(bb0p + kk, &sBh[0][lo0]);
        gld_lds16(bb1p + kk, &sBh[0][lo1]);
        // set 1 <- kk+32
        gld_lds16(a0p + kk + 32, &sAh[1][lo0]);
        gld_lds16(a1p + kk + 32, &sAh[1][lo1]);
        gld_lds16(bb0p + kk + 32, &sBh[1][lo0]);
        gld_lds16(bb1p + kk + 32, &sBh[1][lo1]);
        __syncthreads();

        #pragma unroll
        for (int s = 0; s < 2; s++) {
            short8 ah[4];
            #pragma unroll
            for (int i = 0; i < 4; i++) ah[i] = *(const short8*)(&sAh[s][aoff[i]]);
            #pragma unroll
            for (int j = 0; j < 4; j++) {
                short8 bh = *(const short8*)(&sBh[s][boff[j]]);
                #pragma unroll
                for (int i = 0; i < 4; i++)
                    acc[i][j] = __builtin_amdgcn_mfma_f32_16x16x32_bf16(ah[i], bh, acc[i][j], 0, 0, 0);
            }
        }
    }

    #pragma unroll
    for (int j = 0; j < 4; j++) {
        int col = n0 + wc + j * 16 + l15;
        #pragma unroll
        for (int i = 0; i < 4; i++) {
            #pragma unroll
            for (int r = 0; r < 4; r++) {
                int row = m0 + wr + i * 16 + l4 * 4 + r;
                if (row < M) {
                    if (half) C1[(size_t)row * N + col] = acc[i][j][r];
                    else      C0[(size_t)row * N + col] = f2bf(acc[i][j][r]);
                }
            }
        }
    }
}

// ---------------------------------------------------------------------------
// MLP GEMM, 64x64 tile, single MFMA pass, two K-steps per barrier pair,
// XCD-chunk remap. FUSE=0: store hi. FUSE=1: fused logit GEMV via atomics.
// ---------------------------------------------------------------------------
template<int FUSE>
__global__ __launch_bounds__(256)
void gemm_mlp64_kernel(const u16* __restrict__ Ah,
                       const u16* __restrict__ BTh,
                       u16* __restrict__ Ch,
                       const void* __restrict__ biasraw,
                       const void* __restrict__ A3raw, float* __restrict__ logits,
                       const int* __restrict__ flag,
                       int M, int N, int K)
{
    __shared__ u16 sAh[2][64 * 32];
    __shared__ u16 sBh[2][64 * 32];
    int tid = threadIdx.x;
    int lane = tid & 63, wv = tid >> 6;
    int l15 = lane & 15, l4 = lane >> 4;
    int nx = N >> 6;
    int ny = (M + 63) >> 6;
    int w = xcd_chunk((int)blockIdx.x, nx * ny);
    int by = w / nx;
    int bx = w - by * nx;
    int m0 = by * 64, n0 = bx * 64;

    int r = (tid >> 2), blk = tid & 3, sb = blk ^ ((r >> 1) & 3);
    int gr = min(m0 + r, M - 1);
    const u16* ap = Ah + (size_t)gr * K + sb * 8;
    const u16* bp = BTh + (size_t)(n0 + r) * K + sb * 8;
    int lo = wv * 64 * 8;

    floatx4 acc[4];
    #pragma unroll
    for (int j = 0; j < 4; j++) acc[j] = (floatx4){0.f, 0.f, 0.f, 0.f};

    int arow = wv * 16 + l15;
    int aoff = arow * 32 + ((l4 ^ ((arow >> 1) & 3)) << 3);
    int boff[4];
    #pragma unroll
    for (int j = 0; j < 4; j++) {
        int bcol = j * 16 + l15;
        boff[j] = bcol * 32 + ((l4 ^ ((bcol >> 1) & 3)) << 3);
    }

    for (int kk = 0; kk < K; kk += 64) {
        __syncthreads();
        gld_lds16(ap + kk, &sAh[0][lo]);
        gld_lds16(bp + kk, &sBh[0][lo]);
        gld_lds16(ap + kk + 32, &sAh[1][lo]);
        gld_lds16(bp + kk + 32, &sBh[1][lo]);
        __syncthreads();

        #pragma unroll
        for (int s = 0; s < 2; s++) {
            short8 ah = *(const short8*)(&sAh[s][aoff]);
            #pragma unroll
            for (int j = 0; j < 4; j++) {
                short8 bh = *(const short8*)(&sBh[s][boff[j]]);
                acc[j] = __builtin_amdgcn_mfma_f32_16x16x32_bf16(ah, bh, acc[j], 0, 0, 0);
            }
        }
    }

    const int fp32 = flag[1];
    float lsum[4] = {0.f, 0.f, 0.f, 0.f};
    #pragma unroll
    for (int j = 0; j < 4; j++) {
        int col = n0 + j * 16 + l15;
        float bv = inval(biasraw, fp32, col);
        float a3 = FUSE ? inval(A3raw, fp32, col) : 0.f;
        #pragma unroll
        for (int rr = 0; rr < 4; rr++) {
            int row = m0 + wv * 16 + l4 * 4 + rr;
            if (row < M) {
                float v = acc[j][rr] + bv;
                v = v > 0.f ? v : 0.1f * v;
                if (FUSE) {
                    lsum[rr] += v * a3;
                } else {
                    Ch[(size_t)row * N + col] = f2bf(v);
                }
            }
        }
    }
    if (FUSE) {
        #pragma unroll
        for (int rr = 0; rr < 4; rr++) {
            float s = lsum[rr];
            s += __shfl_xor(s, 1);
            s += __shfl_xor(s, 2);
            s += __shfl_xor(s, 4);
            s += __shfl_xor(s, 8);
            int row = m0 + wv * 16 + l4 * 4 + rr;
            if (l15 == 0 && row < M) atomicAdd(&logits[row], s);
        }
    }
}

// ---------------------------------------------------------------------------
// GATv2 (R20 body, hi-only output): wave-per-node, LPT node order, depth-1
// register pipeline, masked padding. R16/R17/R21 proved TLP>ILP here.
// ---------------------------------------------------------------------------
__global__ __launch_bounds__(256)
void gat_wave_kernel(const int* __restrict__ rowptr, const int* __restrict__ esrcp,
                     const int* __restrict__ order,
                     const u16* __restrict__ xlb, const float* __restrict__ xr,
                     const void* __restrict__ att, const void* __restrict__ bias,
                     const int* __restrict__ flag,
                     u16* __restrict__ hh)
{
    int lane = threadIdx.x & 63, wv = threadIdx.x >> 6;
    int slot = blockIdx.x * 4 + wv;
    if (slot >= N_NODES) return;
    int n = order[slot];
    n = min(max(n, 0), N_NODES - 1);
    int fp32 = flag[1];
    int d0 = lane * 8;
    int l3 = lane & 3;

    int beg = rowptr[n], end = rowptr[n + 1];
    int deg = end - beg;
    int ng = (deg + 3) >> 2;            // groups of up to 4 edges (padded)

    const u16* xbase = xlb + d0;        // lane's 16B chunk within any row

    const float* xrr = xr + (size_t)n * D_EMB;
    float4 r0 = *(const float4*)(xrr + d0);
    float4 r1 = *(const float4*)(xrr + d0 + 4);
    float xrv[8] = {r0.x, r0.y, r0.z, r0.w, r1.x, r1.y, r1.z, r1.w};
    float attv[8];
    #pragma unroll
    for (int k = 0; k < 8; k++) attv[k] = inval(att, fp32, d0 + k);

    float m_run = -3.4e38f, s_run = 0.f;
    float acc[8] = {0.f, 0.f, 0.f, 0.f, 0.f, 0.f, 0.f, 0.f};

    auto ldidx = [&](int g) -> int {
        return esrcp[min(beg + 4 * g + l3, N_EDGES - 1)];
    };

    if (ng > 0) {
        // prologue: idx group 0 -> rows group 0 in flight; idx group 1 in flight
        int i0 = ldidx(0);
        uint4 cu0, cu1, cu2, cu3;
        {
            int s0 = __shfl(i0, 0), s1 = __shfl(i0, 1), s2 = __shfl(i0, 2), s3 = __shfl(i0, 3);
            cu0 = *(const uint4*)(xbase + (size_t)s0 * D_EMB);
            cu1 = *(const uint4*)(xbase + (size_t)s1 * D_EMB);
            cu2 = *(const uint4*)(xbase + (size_t)s2 * D_EMB);
            cu3 = *(const uint4*)(xbase + (size_t)s3 * D_EMB);
        }
        int nidx = (ng > 1) ? ldidx(1) : 0;

        for (int g = 0; g < ng; g++) {
            // issue next group's row gathers + idx for group g+2 FIRST, so their
            // latency overlaps this group's compute.
            uint4 nu0, nu1, nu2, nu3;
            int nidx2 = 0;
            bool have_next = (g + 1 < ng);
            if (have_next) {
                int t0 = __shfl(nidx, 0), t1 = __shfl(nidx, 1),
                    t2 = __shfl(nidx, 2), t3 = __shfl(nidx, 3);
                nu0 = *(const uint4*)(xbase + (size_t)t0 * D_EMB);
                nu1 = *(const uint4*)(xbase + (size_t)t1 * D_EMB);
                nu2 = *(const uint4*)(xbase + (size_t)t2 * D_EMB);
                nu3 = *(const uint4*)(xbase + (size_t)t3 * D_EMB);
                if (g + 2 < ng) nidx2 = ldidx(g + 2);
            }

            // compute group g from registers loaded last iteration
            union { uint4 q; u16 us[8]; } u0, u1, u2, u3;
            u0.q = cu0; u1.q = cu1; u2.q = cu2; u3.q = cu3;
            float v0[8], v1[8], v2[8], v3[8];
            #pragma unroll
            for (int k = 0; k < 8; k++) {
                v0[k] = bf2f(u0.us[k]); v1[k] = bf2f(u1.us[k]);
                v2[k] = bf2f(u2.us[k]); v3[k] = bf2f(u3.us[k]);
            }
            float e0 = 0.f, e1 = 0.f, e2 = 0.f, e3 = 0.f;
            #pragma unroll
            for (int k = 0; k < 8; k++) {
                float t0 = v0[k] + xrv[k]; t0 = fmaxf(t0, 0.2f * t0); e0 += attv[k] * t0;
                float t1 = v1[k] + xrv[k]; t1 = fmaxf(t1, 0.2f * t1); e1 += attv[k] * t1;
                float t2 = v2[k] + xrv[k]; t2 = fmaxf(t2, 0.2f * t2); e2 += attv[k] * t2;
                float t3 = v3[k] + xrv[k]; t3 = fmaxf(t3, 0.2f * t3); e3 += attv[k] * t3;
            }
            #pragma unroll
            for (int o = 32; o > 0; o >>= 1) {
                e0 += __shfl_xor(e0, o);
                e1 += __shfl_xor(e1, o);
                e2 += __shfl_xor(e2, o);
                e3 += __shfl_xor(e3, o);
            }
            // mask padded (dead) edges of the final group
            int base = beg + 4 * g;
            if (base + 1 >= end) e1 = -3.4e38f;
            if (base + 2 >= end) e2 = -3.4e38f;
            if (base + 3 >= end) e3 = -3.4e38f;
            // group-batched online softmax: one rescale per 4 edges
            float m4 = fmaxf(fmaxf(e0, e1), fmaxf(e2, e3));
            float m_new = fmaxf(m_run, m4);
            float sc = __expf(m_run - m_new);          // 0 on first group
            float w0 = __expf(e0 - m_new), w1 = __expf(e1 - m_new);
            float w2 = __expf(e2 - m_new), w3 = __expf(e3 - m_new);
            s_run = s_run * sc + (w0 + w1) + (w2 + w3);
            #pragma unroll
            for (int k = 0; k < 8; k++)
                acc[k] = acc[k] * sc + w0 * v0[k] + w1 * v1[k] + w2 * v2[k] + w3 * v3[k];
            m_run = m_new;

            if (have_next) {
                cu0 = nu0; cu1 = nu1; cu2 = nu2; cu3 = nu3;
                nidx = nidx2;
            }
        }
    }

    float inv = 1.f / (s_run + 1e-16f);
    union { uint4 q; u16 us[8]; } ph;
    #pragma unroll
    for (int k = 0; k < 8; k++) {
        float h = tanhf(acc[k] * inv + inval(bias, fp32, d0 + k));
        ph.us[k] = f2bf(h);
    }
    *(uint4*)(&hh[(size_t)n * D_EMB + d0]) = ph.q;
}

// ---------------------------------------------------------------------------
__global__ __launch_bounds__(256)
void softmax_kernel(const float* __restrict__ logits, float* __restrict__ out)
{
    __shared__ float red[4];
    __shared__ float s_m, s_s;
    int tid = threadIdx.x, lane = tid & 63, wv = tid >> 6;
    float m = -3.4e38f;
    for (int i = tid; i < N_NODES; i += 256) m = fmaxf(m, logits[i]);
    #pragma unroll
    for (int o = 32; o > 0; o >>= 1) m = fmaxf(m, __shfl_down(m, o));
    if (lane == 0) red[wv] = m;
    __syncthreads();
    if (tid == 0) {
        float mm = red[0];
        for (int i = 1; i < 4; i++) mm = fmaxf(mm, red[i]);
        s_m = mm;
    }
    __syncthreads();
    float mm = s_m;
    float s = 0.f;
    for (int i = tid; i < N_NODES; i += 256) s += __expf(logits[i] - mm);
    #pragma unroll
    for (int o = 32; o > 0; o >>= 1) s += __shfl_down(s, o);
    if (lane == 0) red[wv] = s;
    __syncthreads();
    if (tid == 0) {
        float ss = 0.f;
        for (int i = 0; i < 4; i++) ss += red[i];
        s_s = ss;
    }
    __syncthreads();
    float invs = 1.f / s_s;
    for (int i = tid; i < N_NODES; i += 256) out[i] = __expf(logits[i] - mm) * invs;
}

// ---------------------------------------------------------------------------
extern "C" void kernel_launch(void* const* d_in, const int* in_sizes, int n_in,
                              void* d_out, int out_size, void* d_ws, size_t ws_size,
                              hipStream_t stream)
{
    const void* x   = d_in[0];
    const int*  ei  = (const int*)d_in[1];
    const void* Wl[3]  = {d_in[2],  d_in[6],  d_in[10]};
    const void* Wr[3]  = {d_in[3],  d_in[7],  d_in[11]};
    const void* att[3] = {d_in[4],  d_in[8],  d_in[12]};
    const void* bia[3] = {d_in[5],  d_in[9],  d_in[13]};
    const void* A1 = d_in[14];
    const void* c1 = d_in[15];
    const void* A2 = d_in[16];
    const void* c2 = d_in[17];
    const void* A3 = d_in[18];

    char* p = (char*)d_ws;
    auto alloc = [&](size_t bytes) {
        char* r = p;
        p += (bytes + 255) & ~(size_t)255;
        return r;
    };
    u16*   xlb    = (u16*)  alloc((size_t)N_NODES * D_EMB * 4);   // bf16 xl (first half) + MLP aliases
    float* xr     = (float*)alloc((size_t)N_NODES * D_EMB * 4);
    u16*   hh     = (u16*)  alloc((size_t)N_NODES * D_EMB * 2);
    int*   esrcp  = (int*)  alloc((size_t)N_EDGES * 4);
    int*   rowptr = (int*)  alloc((size_t)(N_NODES + 1) * 4);
    int*   counts = (int*)  alloc((size_t)N_NODES * 4);
    int*   flag   = (int*)  alloc(256);
    float* logits = (float*)alloc((size_t)N_NODES * 4);
    int*   doff   = (int*)  alloc(DMAX * 4);
    int*   order  = (int*)  alloc((size_t)N_NODES * 4);
    u16* wl1h = (u16*)alloc(D_EMB * D_IN  * 2);
    u16* wr1h = (u16*)alloc(D_EMB * D_IN  * 2);
    u16* wl2h = (u16*)alloc(D_EMB * D_EMB * 2);
    u16* wr2h = (u16*)alloc(D_EMB * D_EMB * 2);
    u16* wl3h = (u16*)alloc(D_EMB * D_EMB * 2);
    u16* wr3h = (u16*)alloc(D_EMB * D_EMB * 2);
    u16* a1h  = (u16*)alloc(D_EMB * D_HID * 2);
    u16* a2h  = (u16*)alloc(D_HID * D_HID * 2);
    u16* xph  = (u16*)alloc((size_t)N_NODES * D_IN * 2);
    size_t needed = (size_t)(p - (char*)d_ws);

    if (ws_size < needed) {
        sentinel_kernel<<<(out_size + 255) / 256, 256, 0, stream>>>((float*)d_out, out_size);
        return;
    }

    u16* m1h = (u16*)xlb;   // MLP hidden reuses xlb

    // 1) detect + zero counts/logits
    detect_zero_kernel<<<40, 256, 0, stream>>>(ei, (const u16*)x, flag, counts, logits);

    // 2) fused: count edges + preconvert everything to bf16 hi
    ConvJobs jobs;
    auto setjob = [&](int i, const void* s, u16* dh, int r, int c, int tr) {
        jobs.src[i] = s; jobs.dh[i] = dh;
        jobs.rows[i] = r; jobs.cols[i] = c; jobs.trans[i] = tr;
    };
    setjob(0, x,     xph,  N_NODES, D_IN, 0);
    setjob(1, Wl[0], wl1h, D_IN,  D_EMB, 1);
    setjob(2, Wr[0], wr1h, D_IN,  D_EMB, 1);
    setjob(3, Wl[1], wl2h, D_EMB, D_EMB, 1);
    setjob(4, Wr[1], wr2h, D_EMB, D_EMB, 1);
    setjob(5, Wl[2], wl3h, D_EMB, D_EMB, 1);
    setjob(6, Wr[2], wr3h, D_EMB, D_EMB, 1);
    setjob(7, A1,    a1h,  D_EMB, D_HID, 1);
    setjob(8, A2,    a2h,  D_HID, D_HID, 1);
    jobs.njobs = 9;
    jobs.cum[0] = 0;
    for (int i = 0; i < 9; i++) jobs.cum[i + 1] = jobs.cum[i] + jobs.rows[i] * jobs.cols[i];
    int ctotal = jobs.cum[9];
    int convblk = (ctotal + 255) / 256;
    count_convert_kernel<<<EBLK + convblk, 256, 0, stream>>>(ei, counts, jobs, flag);

    // 3) scan + degree hist + descending scan (single block)
    scan_counts_kernel<<<1, 256, 0, stream>>>(counts, rowptr, doff);

    // 4) fused: esrcp fill + LPT scatter
    int nblk = (N_NODES + 255) / 256;
    fill_scatter_kernel<<<nblk + EBLK, 256, 0, stream>>>(ei, flag, rowptr, counts, esrcp, doff, order);

    int gdual = (2 * D_EMB / 128) * ((N_NODES + 127) / 128);   // 8 * 79 = 632
    int gmlp  = (D_HID / 64) * ((N_NODES + 63) / 64);          // 4 * 157 = 628
    int gatgrid = (N_NODES + 3) / 4;

    // layer 1
    gemm_dual_kernel<<<gdual, 256, 0, stream>>>(xph, wl1h, wr1h, xlb, xr, N_NODES, D_EMB, D_IN);
    gat_wave_kernel<<<gatgrid, 256, 0, stream>>>(rowptr, esrcp, order, xlb, xr, att[0], bia[0], flag, hh);
    // layer 2
    gemm_dual_kernel<<<gdual, 256, 0, stream>>>(hh, wl2h, wr2h, xlb, xr, N_NODES, D_EMB, D_EMB);
    gat_wave_kernel<<<gatgrid, 256, 0, stream>>>(rowptr, esrcp, order, xlb, xr, att[1], bia[1], flag, hh);
    // layer 3
    gemm_dual_kernel<<<gdual, 256, 0, stream>>>(hh, wl3h, wr3h, xlb, xr, N_NODES, D_EMB, D_EMB);
    gat_wave_kernel<<<gatgrid, 256, 0, stream>>>(rowptr, esrcp, order, xlb, xr, att[2], bia[2], flag, hh);

    // MLP: GEMM1 stores hi; GEMM2 fuses the A3 logit GEMV via atomics
    gemm_mlp64_kernel<0><<<gmlp, 256, 0, stream>>>(hh, a1h, m1h, c1, nullptr, nullptr, flag, N_NODES, D_HID, D_EMB);
    gemm_mlp64_kernel<1><<<gmlp, 256, 0, stream>>>(m1h, a2h, nullptr, c2, A3, logits, flag, N_NODES, D_HID, D_HID);
    softmax_kernel<<<1, 256, 0, stream>>>(logits, (float*)d_out);
}

// Round 13
// 359.103 us; speedup vs baseline: 1.2930x; 1.0176x over previous
//
#include <hip/hip_runtime.h>
#include <hip/hip_bf16.h>

#define N_NODES 10000
#define N_EDGES 160000
#define D_IN    128
#define D_EMB   512
#define D_HID   256
#define DMAX    512

typedef unsigned short u16;
typedef __attribute__((ext_vector_type(8))) short short8;
typedef __attribute__((ext_vector_type(4))) float floatx4;

__device__ __forceinline__ float bf2f(u16 u) {
    union { unsigned int i; float f; } v; v.i = ((unsigned int)u) << 16; return v.f;
}
__device__ __forceinline__ u16 f2bf(float f) {
    union { float f; unsigned int i; } v; v.f = f;
    unsigned int x = v.i;
    return (u16)((x + 0x7fffu + ((x >> 16) & 1u)) >> 16);  // RNE
}
__device__ __forceinline__ float inval(const void* p, int fp32, int idx) {
    return fp32 ? ((const float*)p)[idx] : bf2f(((const u16*)p)[idx]);
}

// async global->LDS, 16 bytes/lane; lds base must be wave-uniform.
__device__ __forceinline__ void gld_lds16(const u16* g, u16* l) {
    __builtin_amdgcn_global_load_lds((const __attribute__((address_space(1))) void*)g,
                                     (__attribute__((address_space(3))) void*)l,
                                     16, 0, 0);
}

// bijective XCD chunk remap (m204): blocks with bid%8==k get a contiguous
// range of work ids, so each XCD covers consecutive row-panels (A reuse in L2).
__device__ __forceinline__ int xcd_chunk(int bid, int total) {
    int q = total >> 3, r = total & 7;
    int xcd = bid & 7, idx = bid >> 3;
    return (xcd < r ? xcd * (q + 1) : r * (q + 1) + (xcd - r) * q) + idx;
}

// flag[0]: edge_index is int64-viewed-as-int32-pairs; flag[1]: floats are fp32
__device__ __forceinline__ int edge_src(const int* __restrict__ ei, int flg, int e) {
    int v = flg ? ei[2 * e] : ei[e];
    return min(max(v, 0), N_NODES - 1);
}
__device__ __forceinline__ int edge_dst(const int* __restrict__ ei, int flg, int e) {
    int v = flg ? ei[2 * N_EDGES + 2 * e] : ei[N_EDGES + e];
    return min(max(v, 0), N_NODES - 1);
}

// ---------------------------------------------------------------------------
__global__ void sentinel_kernel(float* out, int n) {
    int i = blockIdx.x * 256 + threadIdx.x;
    if (i < n) out[i] = 1.0f;   // => workspace too small
}

// detect dtypes + zero counts/logits, one dispatch (block 0 = census)
__global__ __launch_bounds__(256)
void detect_zero_kernel(const int* __restrict__ ei, const u16* __restrict__ xu,
                        int* flag, int* counts, float* logits) {
    int gid = blockIdx.x * 256 + threadIdx.x;
    for (int i = gid; i < N_NODES; i += gridDim.x * 256) { counts[i] = 0; logits[i] = 0.f; }
    if (blockIdx.x != 0) return;
    __shared__ int s_or[256];
    __shared__ int s_cnt[256];
    int t = threadIdx.x;
    int v = 0;
    for (int k = t; k < 4096; k += 256) v |= ei[1 + 2 * k];
    int c = 0;
    for (int k = t; k < 4096; k += 256) {
        u16 u = xu[k];
        int ex = (u >> 7) & 0xFF;
        bool plaus = (u == 0) || (ex >= 64 && ex <= 191);
        if (!plaus) c++;
    }
    s_or[t] = v; s_cnt[t] = c;
    __syncthreads();
    for (int off = 128; off > 0; off >>= 1) {
        if (t < off) { s_or[t] |= s_or[t + off]; s_cnt[t] += s_cnt[t + off]; }
        __syncthreads();
    }
    if (t == 0) {
        flag[0] = (s_or[0] == 0) ? 1 : 0;
        flag[1] = (s_cnt[0] > 256) ? 1 : 0;
    }
}

// ---------------------------------------------------------------------------
// Fused edge-count + preconversion (R25): blocks [0,EBLK) count edges;
// blocks [EBLK, EBLK+convblocks) convert inputs to bf16 hi (weights transposed).
// ---------------------------------------------------------------------------
#define EBLK ((N_EDGES + 255) / 256)

struct ConvJobs {
    const void* src[10];
    u16* dh[10];
    int rows[10], cols[10], trans[10];
    int cum[11];
    int njobs;
};

__global__ __launch_bounds__(256)
void count_convert_kernel(const int* __restrict__ ei, int* counts,
                          ConvJobs jobs, const int* __restrict__ flag) {
    int b = blockIdx.x;
    if (b < EBLK) {
        int e = b * 256 + threadIdx.x;
        if (e < N_EDGES) atomicAdd(&counts[edge_dst(ei, flag[0], e)], 1);
        return;
    }
    int idx = (b - EBLK) * 256 + threadIdx.x;
    if (idx >= jobs.cum[jobs.njobs]) return;
    int fp32 = flag[1];
    int jb = 0;
    while (idx >= jobs.cum[jb + 1]) jb++;
    int local = idx - jobs.cum[jb];
    float v = inval(jobs.src[jb], fp32, local);
    u16 hi = f2bf(v);
    int o;
    if (jobs.trans[jb]) {
        int r = local / jobs.cols[jb], c = local % jobs.cols[jb];
        o = c * jobs.rows[jb] + r;
    } else o = local;
    jobs.dh[jb][o] = hi;
}

// ---------------------------------------------------------------------------
// CSR scan + LPT degree-histogram + descending scan (single block, all LDS).
// Outputs: rowptr, counts(=running offsets), doff.
// ---------------------------------------------------------------------------
__global__ __launch_bounds__(256)
void scan_counts_kernel(int* counts, int* rowptr, int* doff) {
    __shared__ int part[256];
    __shared__ int hist[DMAX];
    int tid = threadIdx.x;
    for (int d = tid; d < DMAX; d += 256) hist[d] = 0;
    __syncthreads();
    const int CH = 40;
    int base = tid * CH;
    int loc[CH];
    int s = 0;
    #pragma unroll
    for (int i = 0; i < CH; i++) {
        int idx = base + i;
        int c = (idx < N_NODES) ? counts[idx] : 0;
        if (idx < N_NODES) atomicAdd(&hist[min(c, DMAX - 1)], 1);
        loc[i] = s; s += c;
    }
    part[tid] = s;
    __syncthreads();
    for (int off = 1; off < 256; off <<= 1) {
        int v = part[tid];
        int add = (tid >= off) ? part[tid - off] : 0;
        __syncthreads();
        part[tid] = v + add;
        __syncthreads();
    }
    int pre = (tid > 0) ? part[tid - 1] : 0;
    #pragma unroll
    for (int i = 0; i < CH; i++) {
        int idx = base + i;
        if (idx < N_NODES) { int v = pre + loc[i]; rowptr[idx] = v; counts[idx] = v; }
    }
    if (tid == 255) rowptr[N_NODES] = part[255];
    __syncthreads();
    // descending exclusive scan over hist: doff[d] = #nodes with degree > d
    int d0 = (DMAX - 1) - 2 * tid;      // thread owns degrees d0, d0-1
    int d1 = d0 - 1;
    int c0 = hist[d0], c1 = hist[d1];
    __syncthreads();
    part[tid] = c0 + c1;
    __syncthreads();
    for (int o = 1; o < 256; o <<= 1) {
        int v = part[tid];
        int add = (tid >= o) ? part[tid - o] : 0;
        __syncthreads();
        part[tid] = v + add;
        __syncthreads();
    }
    int pre2 = (tid > 0) ? part[tid - 1] : 0;
    doff[d0] = pre2;
    doff[d1] = pre2 + c0;
}

// ---------------------------------------------------------------------------
// Fused esrcp-fill + LPT scatter: blocks [0,nblk) scatter order[];
// blocks [nblk, nblk+EBLK) fill esrcp.
// ---------------------------------------------------------------------------
__global__ __launch_bounds__(256)
void fill_scatter_kernel(const int* __restrict__ ei, const int* __restrict__ flag,
                         const int* __restrict__ rowptr,
                         int* counts, int* esrcp, int* doff, int* order) {
    int b = blockIdx.x;
    int nblk = (N_NODES + 255) / 256;
    int t = threadIdx.x;
    if (b < nblk) {
        __shared__ int lhist[DMAX];
        __shared__ int lbase[DMAX];
        for (int d = t; d < DMAX; d += 256) lhist[d] = 0;
        __syncthreads();
        int n = b * 256 + t;
        int dg = 0;
        if (n < N_NODES) {
            dg = min(rowptr[n + 1] - rowptr[n], DMAX - 1);
            atomicAdd(&lhist[dg], 1);
        }
        __syncthreads();
        for (int d = t; d < DMAX; d += 256) {
            int c = lhist[d];
            lbase[d] = (c > 0) ? atomicAdd(&doff[d], c) : 0;
            lhist[d] = 0;
        }
        __syncthreads();
        if (n < N_NODES) {
            int rank = atomicAdd(&lhist[dg], 1);
            int pos = lbase[dg] + rank;
            if (pos >= 0 && pos < N_NODES) order[pos] = n;
        }
        return;
    }
    int e = (b - nblk) * 256 + t;
    if (e < N_EDGES) {
        int flg = flag[0];
        int pos = atomicAdd(&counts[edge_dst(ei, flg, e)], 1);
        if (pos >= 0 && pos < N_EDGES) esrcp[pos] = edge_src(ei, flg, e);
    }
}

// ---------------------------------------------------------------------------
// Dual 128x128-tile GEMM, single MFMA pass (R24), two K-steps per barrier
// pair (R22), XCD-chunk remap (R23). R26: BOTH outputs stored bf16 (xr was
// the last fp32 hot stream; xl on the same numeric path is already bf16).
// ---------------------------------------------------------------------------
__global__ __launch_bounds__(256)
void gemm_dual_kernel(const u16* __restrict__ Ah,
                      const u16* __restrict__ B0h, const u16* __restrict__ B1h,
                      u16* __restrict__ C0, u16* __restrict__ C1,
                      int M, int N, int K)
{
    __shared__ u16 sAh[2][128 * 32];
    __shared__ u16 sBh[2][128 * 32];
    int nb = N >> 7;
    int nx = 2 * nb;
    int ny = (M + 127) >> 7;
    int w = xcd_chunk((int)blockIdx.x, nx * ny);
    int by = w / nx;
    int bxh = w - by * nx;
    int half = bxh >= nb;
    int bx = half ? (bxh - nb) : bxh;
    const u16* BTh = half ? B1h : B0h;
    u16* Cout = half ? C1 : C0;

    int tid = threadIdx.x;
    int lane = tid & 63, wv = tid >> 6;
    int l15 = lane & 15, l4 = lane >> 4;
    int wr = (wv >> 1) * 64, wc = (wv & 1) * 64;
    int m0 = by * 128, n0 = bx * 128;

    int i0 = tid, i1 = tid + 256;
    int r0 = i0 >> 2, b0 = i0 & 3, sb0 = b0 ^ ((r0 >> 1) & 3);
    int r1 = i1 >> 2, b1 = i1 & 3, sb1 = b1 ^ ((r1 >> 1) & 3);
    int gr0 = min(m0 + r0, M - 1), gr1 = min(m0 + r1, M - 1);
    const u16* a0p = Ah + (size_t)gr0 * K + sb0 * 8;
    const u16* a1p = Ah + (size_t)gr1 * K + sb1 * 8;
    const u16* bb0p = BTh + (size_t)(n0 + r0) * K + sb0 * 8;
    const u16* bb1p = BTh + (size_t)(n0 + r1) * K + sb1 * 8;
    int lo0 = wv * 64 * 8;              // wave chunk (elements) within a set
    int lo1 = (256 + wv * 64) * 8;

    floatx4 acc[4][4];
    #pragma unroll
    for (int i = 0; i < 4; i++)
        #pragma unroll
        for (int j = 0; j < 4; j++) acc[i][j] = (floatx4){0.f, 0.f, 0.f, 0.f};

    int aoff[4], boff[4];
    #pragma unroll
    for (int i = 0; i < 4; i++) {
        int arow = wr + i * 16 + l15;
        aoff[i] = arow * 32 + ((l4 ^ ((arow >> 1) & 3)) << 3);
        int bcol = wc + i * 16 + l15;
        boff[i] = bcol * 32 + ((l4 ^ ((bcol >> 1) & 3)) << 3);
    }

    for (int kk = 0; kk < K; kk += 64) {
        __syncthreads();
        // set 0 <- kk
        gld_lds16(a0p + kk, &sAh[0][lo0]);
        gld_lds16(a1p + kk, &sAh[0][lo1]);
        gld_lds16(bb0p + kk, &sBh[0][lo0]);
        gld_lds16(bb1p + kk, &sBh[0][lo1]);
        // set 1 <- kk+32
        gld_lds16(a0p + kk + 32, &sAh[1][lo0]);
        gld_lds16(a1p + kk + 32, &sAh[1][lo1]);
        gld_lds16(bb0p + kk + 32, &sBh[1][lo0]);
        gld_lds16(bb1p + kk + 32, &sBh[1][lo1]);
        __syncthreads();

        #pragma unroll
        for (int s = 0; s < 2; s++) {
            short8 ah[4];
            #pragma unroll
            for (int i = 0; i < 4; i++) ah[i] = *(const short8*)(&sAh[s][aoff[i]]);
            #pragma unroll
            for (int j = 0; j < 4; j++) {
                short8 bh = *(const short8*)(&sBh[s][boff[j]]);
                #pragma unroll
                for (int i = 0; i < 4; i++)
                    acc[i][j] = __builtin_amdgcn_mfma_f32_16x16x32_bf16(ah[i], bh, acc[i][j], 0, 0, 0);
            }
        }
    }

    #pragma unroll
    for (int j = 0; j < 4; j++) {
        int col = n0 + wc + j * 16 + l15;
        #pragma unroll
        for (int i = 0; i < 4; i++) {
            #pragma unroll
            for (int r = 0; r < 4; r++) {
                int row = m0 + wr + i * 16 + l4 * 4 + r;
                if (row < M) Cout[(size_t)row * N + col] = f2bf(acc[i][j][r]);
            }
        }
    }
}

// ---------------------------------------------------------------------------
// MLP GEMM, 64x64 tile, single MFMA pass, two K-steps per barrier pair,
// XCD-chunk remap. FUSE=0: store hi. FUSE=1: fused logit GEMV via atomics.
// ---------------------------------------------------------------------------
template<int FUSE>
__global__ __launch_bounds__(256)
void gemm_mlp64_kernel(const u16* __restrict__ Ah,
                       const u16* __restrict__ BTh,
                       u16* __restrict__ Ch,
                       const void* __restrict__ biasraw,
                       const void* __restrict__ A3raw, float* __restrict__ logits,
                       const int* __restrict__ flag,
                       int M, int N, int K)
{
    __shared__ u16 sAh[2][64 * 32];
    __shared__ u16 sBh[2][64 * 32];
    int tid = threadIdx.x;
    int lane = tid & 63, wv = tid >> 6;
    int l15 = lane & 15, l4 = lane >> 4;
    int nx = N >> 6;
    int ny = (M + 63) >> 6;
    int w = xcd_chunk((int)blockIdx.x, nx * ny);
    int by = w / nx;
    int bx = w - by * nx;
    int m0 = by * 64, n0 = bx * 64;

    int r = (tid >> 2), blk = tid & 3, sb = blk ^ ((r >> 1) & 3);
    int gr = min(m0 + r, M - 1);
    const u16* ap = Ah + (size_t)gr * K + sb * 8;
    const u16* bp = BTh + (size_t)(n0 + r) * K + sb * 8;
    int lo = wv * 64 * 8;

    floatx4 acc[4];
    #pragma unroll
    for (int j = 0; j < 4; j++) acc[j] = (floatx4){0.f, 0.f, 0.f, 0.f};

    int arow = wv * 16 + l15;
    int aoff = arow * 32 + ((l4 ^ ((arow >> 1) & 3)) << 3);
    int boff[4];
    #pragma unroll
    for (int j = 0; j < 4; j++) {
        int bcol = j * 16 + l15;
        boff[j] = bcol * 32 + ((l4 ^ ((bcol >> 1) & 3)) << 3);
    }

    for (int kk = 0; kk < K; kk += 64) {
        __syncthreads();
        gld_lds16(ap + kk, &sAh[0][lo]);
        gld_lds16(bp + kk, &sBh[0][lo]);
        gld_lds16(ap + kk + 32, &sAh[1][lo]);
        gld_lds16(bp + kk + 32, &sBh[1][lo]);
        __syncthreads();

        #pragma unroll
        for (int s = 0; s < 2; s++) {
            short8 ah = *(const short8*)(&sAh[s][aoff]);
            #pragma unroll
            for (int j = 0; j < 4; j++) {
                short8 bh = *(const short8*)(&sBh[s][boff[j]]);
                acc[j] = __builtin_amdgcn_mfma_f32_16x16x32_bf16(ah, bh, acc[j], 0, 0, 0);
            }
        }
    }

    const int fp32 = flag[1];
    float lsum[4] = {0.f, 0.f, 0.f, 0.f};
    #pragma unroll
    for (int j = 0; j < 4; j++) {
        int col = n0 + j * 16 + l15;
        float bv = inval(biasraw, fp32, col);
        float a3 = FUSE ? inval(A3raw, fp32, col) : 0.f;
        #pragma unroll
        for (int rr = 0; rr < 4; rr++) {
            int row = m0 + wv * 16 + l4 * 4 + rr;
            if (row < M) {
                float v = acc[j][rr] + bv;
                v = v > 0.f ? v : 0.1f * v;
                if (FUSE) {
                    lsum[rr] += v * a3;
                } else {
                    Ch[(size_t)row * N + col] = f2bf(v);
                }
            }
        }
    }
    if (FUSE) {
        #pragma unroll
        for (int rr = 0; rr < 4; rr++) {
            float s = lsum[rr];
            s += __shfl_xor(s, 1);
            s += __shfl_xor(s, 2);
            s += __shfl_xor(s, 4);
            s += __shfl_xor(s, 8);
            int row = m0 + wv * 16 + l4 * 4 + rr;
            if (l15 == 0 && row < M) atomicAdd(&logits[row], s);
        }
    }
}

// ---------------------------------------------------------------------------
// GATv2 (R20 body, hi-only output; R26: xr read as bf16): wave-per-node,
// LPT node order, depth-1 register pipeline, masked padding.
// ---------------------------------------------------------------------------
__global__ __launch_bounds__(256)
void gat_wave_kernel(const int* __restrict__ rowptr, const int* __restrict__ esrcp,
                     const int* __restrict__ order,
                     const u16* __restrict__ xlb, const u16* __restrict__ xr,
                     const void* __restrict__ att, const void* __restrict__ bias,
                     const int* __restrict__ flag,
                     u16* __restrict__ hh)
{
    int lane = threadIdx.x & 63, wv = threadIdx.x >> 6;
    int slot = blockIdx.x * 4 + wv;
    if (slot >= N_NODES) return;
    int n = order[slot];
    n = min(max(n, 0), N_NODES - 1);
    int fp32 = flag[1];
    int d0 = lane * 8;
    int l3 = lane & 3;

    int beg = rowptr[n], end = rowptr[n + 1];
    int deg = end - beg;
    int ng = (deg + 3) >> 2;            // groups of up to 4 edges (padded)

    const u16* xbase = xlb + d0;        // lane's 16B chunk within any row

    union { uint4 q; u16 us[8]; } xru;
    xru.q = *(const uint4*)(xr + (size_t)n * D_EMB + d0);
    float xrv[8];
    #pragma unroll
    for (int k = 0; k < 8; k++) xrv[k] = bf2f(xru.us[k]);
    float attv[8];
    #pragma unroll
    for (int k = 0; k < 8; k++) attv[k] = inval(att, fp32, d0 + k);

    float m_run = -3.4e38f, s_run = 0.f;
    float acc[8] = {0.f, 0.f, 0.f, 0.f, 0.f, 0.f, 0.f, 0.f};

    auto ldidx = [&](int g) -> int {
        return esrcp[min(beg + 4 * g + l3, N_EDGES - 1)];
    };

    if (ng > 0) {
        // prologue: idx group 0 -> rows group 0 in flight; idx group 1 in flight
        int i0 = ldidx(0);
        uint4 cu0, cu1, cu2, cu3;
        {
            int s0 = __shfl(i0, 0), s1 = __shfl(i0, 1), s2 = __shfl(i0, 2), s3 = __shfl(i0, 3);
            cu0 = *(const uint4*)(xbase + (size_t)s0 * D_EMB);
            cu1 = *(const uint4*)(xbase + (size_t)s1 * D_EMB);
            cu2 = *(const uint4*)(xbase + (size_t)s2 * D_EMB);
            cu3 = *(const uint4*)(xbase + (size_t)s3 * D_EMB);
        }
        int nidx = (ng > 1) ? ldidx(1) : 0;

        for (int g = 0; g < ng; g++) {
            // issue next group's row gathers + idx for group g+2 FIRST, so their
            // latency overlaps this group's compute.
            uint4 nu0, nu1, nu2, nu3;
            int nidx2 = 0;
            bool have_next = (g + 1 < ng);
            if (have_next) {
                int t0 = __shfl(nidx, 0), t1 = __shfl(nidx, 1),
                    t2 = __shfl(nidx, 2), t3 = __shfl(nidx, 3);
                nu0 = *(const uint4*)(xbase + (size_t)t0 * D_EMB);
                nu1 = *(const uint4*)(xbase + (size_t)t1 * D_EMB);
                nu2 = *(const uint4*)(xbase + (size_t)t2 * D_EMB);
                nu3 = *(const uint4*)(xbase + (size_t)t3 * D_EMB);
                if (g + 2 < ng) nidx2 = ldidx(g + 2);
            }

            // compute group g from registers loaded last iteration
            union { uint4 q; u16 us[8]; } u0, u1, u2, u3;
            u0.q = cu0; u1.q = cu1; u2.q = cu2; u3.q = cu3;
            float v0[8], v1[8], v2[8], v3[8];
            #pragma unroll
            for (int k = 0; k < 8; k++) {
                v0[k] = bf2f(u0.us[k]); v1[k] = bf2f(u1.us[k]);
                v2[k] = bf2f(u2.us[k]); v3[k] = bf2f(u3.us[k]);
            }
            float e0 = 0.f, e1 = 0.f, e2 = 0.f, e3 = 0.f;
            #pragma unroll
            for (int k = 0; k < 8; k++) {
                float t0 = v0[k] + xrv[k]; t0 = fmaxf(t0, 0.2f * t0); e0 += attv[k] * t0;
                float t1 = v1[k] + xrv[k]; t1 = fmaxf(t1, 0.2f * t1); e1 += attv[k] * t1;
                float t2 = v2[k] + xrv[k]; t2 = fmaxf(t2, 0.2f * t2); e2 += attv[k] * t2;
                float t3 = v3[k] + xrv[k]; t3 = fmaxf(t3, 0.2f * t3); e3 += attv[k] * t3;
            }
            #pragma unroll
            for (int o = 32; o > 0; o >>= 1) {
                e0 += __shfl_xor(e0, o);
                e1 += __shfl_xor(e1, o);
                e2 += __shfl_xor(e2, o);
                e3 += __shfl_xor(e3, o);
            }
            // mask padded (dead) edges of the final group
            int base = beg + 4 * g;
            if (base + 1 >= end) e1 = -3.4e38f;
            if (base + 2 >= end) e2 = -3.4e38f;
            if (base + 3 >= end) e3 = -3.4e38f;
            // group-batched online softmax: one rescale per 4 edges
            float m4 = fmaxf(fmaxf(e0, e1), fmaxf(e2, e3));
            float m_new = fmaxf(m_run, m4);
            float sc = __expf(m_run - m_new);          // 0 on first group
            float w0 = __expf(e0 - m_new), w1 = __expf(e1 - m_new);
            float w2 = __expf(e2 - m_new), w3 = __expf(e3 - m_new);
            s_run = s_run * sc + (w0 + w1) + (w2 + w3);
            #pragma unroll
            for (int k = 0; k < 8; k++)
                acc[k] = acc[k] * sc + w0 * v0[k] + w1 * v1[k] + w2 * v2[k] + w3 * v3[k];
            m_run = m_new;

            if (have_next) {
                cu0 = nu0; cu1 = nu1; cu2 = nu2; cu3 = nu3;
                nidx = nidx2;
            }
        }
    }

    float inv = 1.f / (s_run + 1e-16f);
    union { uint4 q; u16 us[8]; } ph;
    #pragma unroll
    for (int k = 0; k < 8; k++) {
        float h = tanhf(acc[k] * inv + inval(bias, fp32, d0 + k));
        ph.us[k] = f2bf(h);
    }
    *(uint4*)(&hh[(size_t)n * D_EMB + d0]) = ph.q;
}

// ---------------------------------------------------------------------------
__global__ __launch_bounds__(256)
void softmax_kernel(const float* __restrict__ logits, float* __restrict__ out)
{
    __shared__ float red[4];
    __shared__ float s_m, s_s;
    int tid = threadIdx.x, lane = tid & 63, wv = tid >> 6;
    float m = -3.4e38f;
    for (int i = tid; i < N_NODES; i += 256) m = fmaxf(m, logits[i]);
    #pragma unroll
    for (int o = 32; o > 0; o >>= 1) m = fmaxf(m, __shfl_down(m, o));
    if (lane == 0) red[wv] = m;
    __syncthreads();
    if (tid == 0) {
        float mm = red[0];
        for (int i = 1; i < 4; i++) mm = fmaxf(mm, red[i]);
        s_m = mm;
    }
    __syncthreads();
    float mm = s_m;
    float s = 0.f;
    for (int i = tid; i < N_NODES; i += 256) s += __expf(logits[i] - mm);
    #pragma unroll
    for (int o = 32; o > 0; o >>= 1) s += __shfl_down(s, o);
    if (lane == 0) red[wv] = s;
    __syncthreads();
    if (tid == 0) {
        float ss = 0.f;
        for (int i = 0; i < 4; i++) ss += red[i];
        s_s = ss;
    }
    __syncthreads();
    float invs = 1.f / s_s;
    for (int i = tid; i < N_NODES; i += 256) out[i] = __expf(logits[i] - mm) * invs;
}

// ---------------------------------------------------------------------------
extern "C" void kernel_launch(void* const* d_in, const int* in_sizes, int n_in,
                              void* d_out, int out_size, void* d_ws, size_t ws_size,
                              hipStream_t stream)
{
    const void* x   = d_in[0];
    const int*  ei  = (const int*)d_in[1];
    const void* Wl[3]  = {d_in[2],  d_in[6],  d_in[10]};
    const void* Wr[3]  = {d_in[3],  d_in[7],  d_in[11]};
    const void* att[3] = {d_in[4],  d_in[8],  d_in[12]};
    const void* bia[3] = {d_in[5],  d_in[9],  d_in[13]};
    const void* A1 = d_in[14];
    const void* c1 = d_in[15];
    const void* A2 = d_in[16];
    const void* c2 = d_in[17];
    const void* A3 = d_in[18];

    char* p = (char*)d_ws;
    auto alloc = [&](size_t bytes) {
        char* r = p;
        p += (bytes + 255) & ~(size_t)255;
        return r;
    };
    u16*   xlb    = (u16*)  alloc((size_t)N_NODES * D_EMB * 4);   // bf16 xl (first half) + MLP aliases
    u16*   xr     = (u16*)  alloc((size_t)N_NODES * D_EMB * 2);   // bf16 xr (R26)
    u16*   hh     = (u16*)  alloc((size_t)N_NODES * D_EMB * 2);
    int*   esrcp  = (int*)  alloc((size_t)N_EDGES * 4);
    int*   rowptr = (int*)  alloc((size_t)(N_NODES + 1) * 4);
    int*   counts = (int*)  alloc((size_t)N_NODES * 4);
    int*   flag   = (int*)  alloc(256);
    float* logits = (float*)alloc((size_t)N_NODES * 4);
    int*   doff   = (int*)  alloc(DMAX * 4);
    int*   order  = (int*)  alloc((size_t)N_NODES * 4);
    u16* wl1h = (u16*)alloc(D_EMB * D_IN  * 2);
    u16* wr1h = (u16*)alloc(D_EMB * D_IN  * 2);
    u16* wl2h = (u16*)alloc(D_EMB * D_EMB * 2);
    u16* wr2h = (u16*)alloc(D_EMB * D_EMB * 2);
    u16* wl3h = (u16*)alloc(D_EMB * D_EMB * 2);
    u16* wr3h = (u16*)alloc(D_EMB * D_EMB * 2);
    u16* a1h  = (u16*)alloc(D_EMB * D_HID * 2);
    u16* a2h  = (u16*)alloc(D_HID * D_HID * 2);
    u16* xph  = (u16*)alloc((size_t)N_NODES * D_IN * 2);
    size_t needed = (size_t)(p - (char*)d_ws);

    if (ws_size < needed) {
        sentinel_kernel<<<(out_size + 255) / 256, 256, 0, stream>>>((float*)d_out, out_size);
        return;
    }

    u16* m1h = (u16*)xlb;   // MLP hidden reuses xlb

    // 1) detect + zero counts/logits
    detect_zero_kernel<<<40, 256, 0, stream>>>(ei, (const u16*)x, flag, counts, logits);

    // 2) fused: count edges + preconvert everything to bf16 hi
    ConvJobs jobs;
    auto setjob = [&](int i, const void* s, u16* dh, int r, int c, int tr) {
        jobs.src[i] = s; jobs.dh[i] = dh;
        jobs.rows[i] = r; jobs.cols[i] = c; jobs.trans[i] = tr;
    };
    setjob(0, x,     xph,  N_NODES, D_IN, 0);
    setjob(1, Wl[0], wl1h, D_IN,  D_EMB, 1);
    setjob(2, Wr[0], wr1h, D_IN,  D_EMB, 1);
    setjob(3, Wl[1], wl2h, D_EMB, D_EMB, 1);
    setjob(4, Wr[1], wr2h, D_EMB, D_EMB, 1);
    setjob(5, Wl[2], wl3h, D_EMB, D_EMB, 1);
    setjob(6, Wr[2], wr3h, D_EMB, D_EMB, 1);
    setjob(7, A1,    a1h,  D_EMB, D_HID, 1);
    setjob(8, A2,    a2h,  D_HID, D_HID, 1);
    jobs.njobs = 9;
    jobs.cum[0] = 0;
    for (int i = 0; i < 9; i++) jobs.cum[i + 1] = jobs.cum[i] + jobs.rows[i] * jobs.cols[i];
    int ctotal = jobs.cum[9];
    int convblk = (ctotal + 255) / 256;
    count_convert_kernel<<<EBLK + convblk, 256, 0, stream>>>(ei, counts, jobs, flag);

    // 3) scan + degree hist + descending scan (single block)
    scan_counts_kernel<<<1, 256, 0, stream>>>(counts, rowptr, doff);

    // 4) fused: esrcp fill + LPT scatter
    int nblk = (N_NODES + 255) / 256;
    fill_scatter_kernel<<<nblk + EBLK, 256, 0, stream>>>(ei, flag, rowptr, counts, esrcp, doff, order);

    int gdual = (2 * D_EMB / 128) * ((N_NODES + 127) / 128);   // 8 * 79 = 632
    int gmlp  = (D_HID / 64) * ((N_NODES + 63) / 64);          // 4 * 157 = 628
    int gatgrid = (N_NODES + 3) / 4;

    // layer 1
    gemm_dual_kernel<<<gdual, 256, 0, stream>>>(xph, wl1h, wr1h, xlb, xr, N_NODES, D_EMB, D_IN);
    gat_wave_kernel<<<gatgrid, 256, 0, stream>>>(rowptr, esrcp, order, xlb, xr, att[0], bia[0], flag, hh);
    // layer 2
    gemm_dual_kernel<<<gdual, 256, 0, stream>>>(hh, wl2h, wr2h, xlb, xr, N_NODES, D_EMB, D_EMB);
    gat_wave_kernel<<<gatgrid, 256, 0, stream>>>(rowptr, esrcp, order, xlb, xr, att[1], bia[1], flag, hh);
    // layer 3
    gemm_dual_kernel<<<gdual, 256, 0, stream>>>(hh, wl3h, wr3h, xlb, xr, N_NODES, D_EMB, D_EMB);
    gat_wave_kernel<<<gatgrid, 256, 0, stream>>>(rowptr, esrcp, order, xlb, xr, att[2], bia[2], flag, hh);

    // MLP: GEMM1 stores hi; GEMM2 fuses the A3 logit GEMV via atomics
    gemm_mlp64_kernel<0><<<gmlp, 256, 0, stream>>>(hh, a1h, m1h, c1, nullptr, nullptr, flag, N_NODES, D_HID, D_EMB);
    gemm_mlp64_kernel<1><<<gmlp, 256, 0, stream>>>(m1h, a2h, nullptr, c2, A3, logits, flag, N_NODES, D_HID, D_HID);
    softmax_kernel<<<1, 256, 0, stream>>>(logits, (float*)d_out);
}

// Round 14
// 358.266 us; speedup vs baseline: 1.2961x; 1.0023x over previous
//
#include <hip/hip_runtime.h>
#include <hip/hip_bf16.h>

#define N_NODES 10000
#define N_EDGES 160000
#define D_IN    128
#define D_EMB   512
#define D_HID   256
#define DMAX    512

typedef unsigned short u16;
typedef __attribute__((ext_vector_type(8))) short short8;
typedef __attribute__((ext_vector_type(4))) float floatx4;

__device__ __forceinline__ float bf2f(u16 u) {
    union { unsigned int i; float f; } v; v.i = ((unsigned int)u) << 16; return v.f;
}
__device__ __forceinline__ u16 f2bf(float f) {
    union { float f; unsigned int i; } v; v.f = f;
    unsigned int x = v.i;
    return (u16)((x + 0x7fffu + ((x >> 16) & 1u)) >> 16);  // RNE
}
__device__ __forceinline__ float inval(const void* p, int fp32, int idx) {
    return fp32 ? ((const float*)p)[idx] : bf2f(((const u16*)p)[idx]);
}

// async global->LDS, 16 bytes/lane; lds base must be wave-uniform.
__device__ __forceinline__ void gld_lds16(const u16* g, u16* l) {
    __builtin_amdgcn_global_load_lds((const __attribute__((address_space(1))) void*)g,
                                     (__attribute__((address_space(3))) void*)l,
                                     16, 0, 0);
}

// bijective XCD chunk remap (m204): blocks with bid%8==k get a contiguous
// range of work ids, so each XCD covers consecutive row-panels (A reuse in L2).
__device__ __forceinline__ int xcd_chunk(int bid, int total) {
    int q = total >> 3, r = total & 7;
    int xcd = bid & 7, idx = bid >> 3;
    return (xcd < r ? xcd * (q + 1) : r * (q + 1) + (xcd - r) * q) + idx;
}

// flag[0]: edge_index is int64-viewed-as-int32-pairs; flag[1]: floats are fp32
__device__ __forceinline__ int edge_src(const int* __restrict__ ei, int flg, int e) {
    int v = flg ? ei[2 * e] : ei[e];
    return min(max(v, 0), N_NODES - 1);
}
__device__ __forceinline__ int edge_dst(const int* __restrict__ ei, int flg, int e) {
    int v = flg ? ei[2 * N_EDGES + 2 * e] : ei[N_EDGES + e];
    return min(max(v, 0), N_NODES - 1);
}

// ---------------------------------------------------------------------------
__global__ void sentinel_kernel(float* out, int n) {
    int i = blockIdx.x * 256 + threadIdx.x;
    if (i < n) out[i] = 1.0f;   // => workspace too small
}

// detect dtypes + zero counts/logits, one dispatch (block 0 = census)
__global__ __launch_bounds__(256)
void detect_zero_kernel(const int* __restrict__ ei, const u16* __restrict__ xu,
                        int* flag, int* counts, float* logits) {
    int gid = blockIdx.x * 256 + threadIdx.x;
    for (int i = gid; i < N_NODES; i += gridDim.x * 256) { counts[i] = 0; logits[i] = 0.f; }
    if (blockIdx.x != 0) return;
    __shared__ int s_or[256];
    __shared__ int s_cnt[256];
    int t = threadIdx.x;
    int v = 0;
    for (int k = t; k < 4096; k += 256) v |= ei[1 + 2 * k];
    int c = 0;
    for (int k = t; k < 4096; k += 256) {
        u16 u = xu[k];
        int ex = (u >> 7) & 0xFF;
        bool plaus = (u == 0) || (ex >= 64 && ex <= 191);
        if (!plaus) c++;
    }
    s_or[t] = v; s_cnt[t] = c;
    __syncthreads();
    for (int off = 128; off > 0; off >>= 1) {
        if (t < off) { s_or[t] |= s_or[t + off]; s_cnt[t] += s_cnt[t + off]; }
        __syncthreads();
    }
    if (t == 0) {
        flag[0] = (s_or[0] == 0) ? 1 : 0;
        flag[1] = (s_cnt[0] > 256) ? 1 : 0;
    }
}

// ---------------------------------------------------------------------------
// Fused edge-count + preconversion: blocks [0,EBLK) count edges;
// blocks [EBLK, EBLK+convblocks) convert inputs to bf16 hi (weights transposed).
// ---------------------------------------------------------------------------
#define EBLK ((N_EDGES + 255) / 256)

struct ConvJobs {
    const void* src[10];
    u16* dh[10];
    int rows[10], cols[10], trans[10];
    int cum[11];
    int njobs;
};

__global__ __launch_bounds__(256)
void count_convert_kernel(const int* __restrict__ ei, int* counts,
                          ConvJobs jobs, const int* __restrict__ flag) {
    int b = blockIdx.x;
    if (b < EBLK) {
        int e = b * 256 + threadIdx.x;
        if (e < N_EDGES) atomicAdd(&counts[edge_dst(ei, flag[0], e)], 1);
        return;
    }
    int idx = (b - EBLK) * 256 + threadIdx.x;
    if (idx >= jobs.cum[jobs.njobs]) return;
    int fp32 = flag[1];
    int jb = 0;
    while (idx >= jobs.cum[jb + 1]) jb++;
    int local = idx - jobs.cum[jb];
    float v = inval(jobs.src[jb], fp32, local);
    u16 hi = f2bf(v);
    int o;
    if (jobs.trans[jb]) {
        int r = local / jobs.cols[jb], c = local % jobs.cols[jb];
        o = c * jobs.rows[jb] + r;
    } else o = local;
    jobs.dh[jb][o] = hi;
}

// ---------------------------------------------------------------------------
// CSR scan + LPT degree-histogram + descending scan (single block, all LDS).
// Outputs: rowptr, counts(=running offsets), doff.
// ---------------------------------------------------------------------------
__global__ __launch_bounds__(256)
void scan_counts_kernel(int* counts, int* rowptr, int* doff) {
    __shared__ int part[256];
    __shared__ int hist[DMAX];
    int tid = threadIdx.x;
    for (int d = tid; d < DMAX; d += 256) hist[d] = 0;
    __syncthreads();
    const int CH = 40;
    int base = tid * CH;
    int loc[CH];
    int s = 0;
    #pragma unroll
    for (int i = 0; i < CH; i++) {
        int idx = base + i;
        int c = (idx < N_NODES) ? counts[idx] : 0;
        if (idx < N_NODES) atomicAdd(&hist[min(c, DMAX - 1)], 1);
        loc[i] = s; s += c;
    }
    part[tid] = s;
    __syncthreads();
    for (int off = 1; off < 256; off <<= 1) {
        int v = part[tid];
        int add = (tid >= off) ? part[tid - off] : 0;
        __syncthreads();
        part[tid] = v + add;
        __syncthreads();
    }
    int pre = (tid > 0) ? part[tid - 1] : 0;
    #pragma unroll
    for (int i = 0; i < CH; i++) {
        int idx = base + i;
        if (idx < N_NODES) { int v = pre + loc[i]; rowptr[idx] = v; counts[idx] = v; }
    }
    if (tid == 255) rowptr[N_NODES] = part[255];
    __syncthreads();
    // descending exclusive scan over hist: doff[d] = #nodes with degree > d
    int d0 = (DMAX - 1) - 2 * tid;      // thread owns degrees d0, d0-1
    int d1 = d0 - 1;
    int c0 = hist[d0], c1 = hist[d1];
    __syncthreads();
    part[tid] = c0 + c1;
    __syncthreads();
    for (int o = 1; o < 256; o <<= 1) {
        int v = part[tid];
        int add = (tid >= o) ? part[tid - o] : 0;
        __syncthreads();
        part[tid] = v + add;
        __syncthreads();
    }
    int pre2 = (tid > 0) ? part[tid - 1] : 0;
    doff[d0] = pre2;
    doff[d1] = pre2 + c0;
}

// ---------------------------------------------------------------------------
// Fused esrcp-fill + LPT scatter: blocks [0,nblk) scatter order[];
// blocks [nblk, nblk+EBLK) fill esrcp.
// ---------------------------------------------------------------------------
__global__ __launch_bounds__(256)
void fill_scatter_kernel(const int* __restrict__ ei, const int* __restrict__ flag,
                         const int* __restrict__ rowptr,
                         int* counts, int* esrcp, int* doff, int* order) {
    int b = blockIdx.x;
    int nblk = (N_NODES + 255) / 256;
    int t = threadIdx.x;
    if (b < nblk) {
        __shared__ int lhist[DMAX];
        __shared__ int lbase[DMAX];
        for (int d = t; d < DMAX; d += 256) lhist[d] = 0;
        __syncthreads();
        int n = b * 256 + t;
        int dg = 0;
        if (n < N_NODES) {
            dg = min(rowptr[n + 1] - rowptr[n], DMAX - 1);
            atomicAdd(&lhist[dg], 1);
        }
        __syncthreads();
        for (int d = t; d < DMAX; d += 256) {
            int c = lhist[d];
            lbase[d] = (c > 0) ? atomicAdd(&doff[d], c) : 0;
            lhist[d] = 0;
        }
        __syncthreads();
        if (n < N_NODES) {
            int rank = atomicAdd(&lhist[dg], 1);
            int pos = lbase[dg] + rank;
            if (pos >= 0 && pos < N_NODES) order[pos] = n;
        }
        return;
    }
    int e = (b - nblk) * 256 + t;
    if (e < N_EDGES) {
        int flg = flag[0];
        int pos = atomicAdd(&counts[edge_dst(ei, flg, e)], 1);
        if (pos >= 0 && pos < N_EDGES) esrcp[pos] = edge_src(ei, flg, e);
    }
}

// ---------------------------------------------------------------------------
// Dual 128x128-tile GEMM, single MFMA pass (R24), XCD-chunk remap (R23),
// bf16 outputs (R26). R27: stage-ahead pipeline — each 32-K iteration issues
// the NEXT window's global_load_lds into the other LDS set BEFORE computing
// the current set; the end-of-iteration __syncthreads (vmcnt+lgkm drain)
// lands after a full window of compute instead of right after issue.
// Buffer safety: set written in iter i was last read in iter i-1, fenced by
// that iteration's barrier.
// ---------------------------------------------------------------------------
__global__ __launch_bounds__(256)
void gemm_dual_kernel(const u16* __restrict__ Ah,
                      const u16* __restrict__ B0h, const u16* __restrict__ B1h,
                      u16* __restrict__ C0, u16* __restrict__ C1,
                      int M, int N, int K)
{
    __shared__ u16 sAh[2][128 * 32];
    __shared__ u16 sBh[2][128 * 32];
    int nb = N >> 7;
    int nx = 2 * nb;
    int ny = (M + 127) >> 7;
    int w = xcd_chunk((int)blockIdx.x, nx * ny);
    int by = w / nx;
    int bxh = w - by * nx;
    int half = bxh >= nb;
    int bx = half ? (bxh - nb) : bxh;
    const u16* BTh = half ? B1h : B0h;
    u16* Cout = half ? C1 : C0;

    int tid = threadIdx.x;
    int lane = tid & 63, wv = tid >> 6;
    int l15 = lane & 15, l4 = lane >> 4;
    int wr = (wv >> 1) * 64, wc = (wv & 1) * 64;
    int m0 = by * 128, n0 = bx * 128;

    int i0 = tid, i1 = tid + 256;
    int r0 = i0 >> 2, b0 = i0 & 3, sb0 = b0 ^ ((r0 >> 1) & 3);
    int r1 = i1 >> 2, b1 = i1 & 3, sb1 = b1 ^ ((r1 >> 1) & 3);
    int gr0 = min(m0 + r0, M - 1), gr1 = min(m0 + r1, M - 1);
    const u16* a0p = Ah + (size_t)gr0 * K + sb0 * 8;
    const u16* a1p = Ah + (size_t)gr1 * K + sb1 * 8;
    const u16* bb0p = BTh + (size_t)(n0 + r0) * K + sb0 * 8;
    const u16* bb1p = BTh + (size_t)(n0 + r1) * K + sb1 * 8;
    int lo0 = wv * 64 * 8;              // wave chunk (elements) within a set
    int lo1 = (256 + wv * 64) * 8;

    floatx4 acc[4][4];
    #pragma unroll
    for (int i = 0; i < 4; i++)
        #pragma unroll
        for (int j = 0; j < 4; j++) acc[i][j] = (floatx4){0.f, 0.f, 0.f, 0.f};

    int aoff[4], boff[4];
    #pragma unroll
    for (int i = 0; i < 4; i++) {
        int arow = wr + i * 16 + l15;
        aoff[i] = arow * 32 + ((l4 ^ ((arow >> 1) & 3)) << 3);
        int bcol = wc + i * 16 + l15;
        boff[i] = bcol * 32 + ((l4 ^ ((bcol >> 1) & 3)) << 3);
    }

    int nt = K >> 5;                    // 32-K windows
    // prologue: stage set 0 <- window 0
    gld_lds16(a0p, &sAh[0][lo0]);
    gld_lds16(a1p, &sAh[0][lo1]);
    gld_lds16(bb0p, &sBh[0][lo0]);
    gld_lds16(bb1p, &sBh[0][lo1]);
    __syncthreads();                    // drains vmcnt: set0 ready

    for (int it = 0; it < nt; it++) {
        int cur = it & 1, nxt = cur ^ 1;
        if (it + 1 < nt) {              // issue next window FIRST (overlaps compute)
            int kk = (it + 1) << 5;
            gld_lds16(a0p + kk, &sAh[nxt][lo0]);
            gld_lds16(a1p + kk, &sAh[nxt][lo1]);
            gld_lds16(bb0p + kk, &sBh[nxt][lo0]);
            gld_lds16(bb1p + kk, &sBh[nxt][lo1]);
        }
        short8 ah[4];
        #pragma unroll
        for (int i = 0; i < 4; i++) ah[i] = *(const short8*)(&sAh[cur][aoff[i]]);
        #pragma unroll
        for (int j = 0; j < 4; j++) {
            short8 bh = *(const short8*)(&sBh[cur][boff[j]]);
            #pragma unroll
            for (int i = 0; i < 4; i++)
                acc[i][j] = __builtin_amdgcn_mfma_f32_16x16x32_bf16(ah[i], bh, acc[i][j], 0, 0, 0);
        }
        __syncthreads();                // drains next-window loads; fences cur reads
    }

    #pragma unroll
    for (int j = 0; j < 4; j++) {
        int col = n0 + wc + j * 16 + l15;
        #pragma unroll
        for (int i = 0; i < 4; i++) {
            #pragma unroll
            for (int r = 0; r < 4; r++) {
                int row = m0 + wr + i * 16 + l4 * 4 + r;
                if (row < M) Cout[(size_t)row * N + col] = f2bf(acc[i][j][r]);
            }
        }
    }
}

// ---------------------------------------------------------------------------
// MLP GEMM, 64x64 tile, single MFMA pass, stage-ahead pipeline (R27),
// XCD-chunk remap. FUSE=0: store hi. FUSE=1: fused logit GEMV via atomics.
// ---------------------------------------------------------------------------
template<int FUSE>
__global__ __launch_bounds__(256)
void gemm_mlp64_kernel(const u16* __restrict__ Ah,
                       const u16* __restrict__ BTh,
                       u16* __restrict__ Ch,
                       const void* __restrict__ biasraw,
                       const void* __restrict__ A3raw, float* __restrict__ logits,
                       const int* __restrict__ flag,
                       int M, int N, int K)
{
    __shared__ u16 sAh[2][64 * 32];
    __shared__ u16 sBh[2][64 * 32];
    int tid = threadIdx.x;
    int lane = tid & 63, wv = tid >> 6;
    int l15 = lane & 15, l4 = lane >> 4;
    int nx = N >> 6;
    int ny = (M + 63) >> 6;
    int w = xcd_chunk((int)blockIdx.x, nx * ny);
    int by = w / nx;
    int bx = w - by * nx;
    int m0 = by * 64, n0 = bx * 64;

    int r = (tid >> 2), blk = tid & 3, sb = blk ^ ((r >> 1) & 3);
    int gr = min(m0 + r, M - 1);
    const u16* ap = Ah + (size_t)gr * K + sb * 8;
    const u16* bp = BTh + (size_t)(n0 + r) * K + sb * 8;
    int lo = wv * 64 * 8;

    floatx4 acc[4];
    #pragma unroll
    for (int j = 0; j < 4; j++) acc[j] = (floatx4){0.f, 0.f, 0.f, 0.f};

    int arow = wv * 16 + l15;
    int aoff = arow * 32 + ((l4 ^ ((arow >> 1) & 3)) << 3);
    int boff[4];
    #pragma unroll
    for (int j = 0; j < 4; j++) {
        int bcol = j * 16 + l15;
        boff[j] = bcol * 32 + ((l4 ^ ((bcol >> 1) & 3)) << 3);
    }

    int nt = K >> 5;                    // 32-K windows
    gld_lds16(ap, &sAh[0][lo]);
    gld_lds16(bp, &sBh[0][lo]);
    __syncthreads();

    for (int it = 0; it < nt; it++) {
        int cur = it & 1, nxt = cur ^ 1;
        if (it + 1 < nt) {
            int kk = (it + 1) << 5;
            gld_lds16(ap + kk, &sAh[nxt][lo]);
            gld_lds16(bp + kk, &sBh[nxt][lo]);
        }
        short8 ah = *(const short8*)(&sAh[cur][aoff]);
        #pragma unroll
        for (int j = 0; j < 4; j++) {
            short8 bh = *(const short8*)(&sBh[cur][boff[j]]);
            acc[j] = __builtin_amdgcn_mfma_f32_16x16x32_bf16(ah, bh, acc[j], 0, 0, 0);
        }
        __syncthreads();
    }

    const int fp32 = flag[1];
    float lsum[4] = {0.f, 0.f, 0.f, 0.f};
    #pragma unroll
    for (int j = 0; j < 4; j++) {
        int col = n0 + j * 16 + l15;
        float bv = inval(biasraw, fp32, col);
        float a3 = FUSE ? inval(A3raw, fp32, col) : 0.f;
        #pragma unroll
        for (int rr = 0; rr < 4; rr++) {
            int row = m0 + wv * 16 + l4 * 4 + rr;
            if (row < M) {
                float v = acc[j][rr] + bv;
                v = v > 0.f ? v : 0.1f * v;
                if (FUSE) {
                    lsum[rr] += v * a3;
                } else {
                    Ch[(size_t)row * N + col] = f2bf(v);
                }
            }
        }
    }
    if (FUSE) {
        #pragma unroll
        for (int rr = 0; rr < 4; rr++) {
            float s = lsum[rr];
            s += __shfl_xor(s, 1);
            s += __shfl_xor(s, 2);
            s += __shfl_xor(s, 4);
            s += __shfl_xor(s, 8);
            int row = m0 + wv * 16 + l4 * 4 + rr;
            if (l15 == 0 && row < M) atomicAdd(&logits[row], s);
        }
    }
}

// ---------------------------------------------------------------------------
// GATv2 (R20 body, hi-only output; xr bf16): wave-per-node, LPT node order,
// depth-1 register pipeline, masked padding. R16/R17/R21 proved TLP>ILP here.
// ---------------------------------------------------------------------------
__global__ __launch_bounds__(256)
void gat_wave_kernel(const int* __restrict__ rowptr, const int* __restrict__ esrcp,
                     const int* __restrict__ order,
                     const u16* __restrict__ xlb, const u16* __restrict__ xr,
                     const void* __restrict__ att, const void* __restrict__ bias,
                     const int* __restrict__ flag,
                     u16* __restrict__ hh)
{
    int lane = threadIdx.x & 63, wv = threadIdx.x >> 6;
    int slot = blockIdx.x * 4 + wv;
    if (slot >= N_NODES) return;
    int n = order[slot];
    n = min(max(n, 0), N_NODES - 1);
    int fp32 = flag[1];
    int d0 = lane * 8;
    int l3 = lane & 3;

    int beg = rowptr[n], end = rowptr[n + 1];
    int deg = end - beg;
    int ng = (deg + 3) >> 2;            // groups of up to 4 edges (padded)

    const u16* xbase = xlb + d0;        // lane's 16B chunk within any row

    union { uint4 q; u16 us[8]; } xru;
    xru.q = *(const uint4*)(xr + (size_t)n * D_EMB + d0);
    float xrv[8];
    #pragma unroll
    for (int k = 0; k < 8; k++) xrv[k] = bf2f(xru.us[k]);
    float attv[8];
    #pragma unroll
    for (int k = 0; k < 8; k++) attv[k] = inval(att, fp32, d0 + k);

    float m_run = -3.4e38f, s_run = 0.f;
    float acc[8] = {0.f, 0.f, 0.f, 0.f, 0.f, 0.f, 0.f, 0.f};

    auto ldidx = [&](int g) -> int {
        return esrcp[min(beg + 4 * g + l3, N_EDGES - 1)];
    };

    if (ng > 0) {
        // prologue: idx group 0 -> rows group 0 in flight; idx group 1 in flight
        int i0 = ldidx(0);
        uint4 cu0, cu1, cu2, cu3;
        {
            int s0 = __shfl(i0, 0), s1 = __shfl(i0, 1), s2 = __shfl(i0, 2), s3 = __shfl(i0, 3);
            cu0 = *(const uint4*)(xbase + (size_t)s0 * D_EMB);
            cu1 = *(const uint4*)(xbase + (size_t)s1 * D_EMB);
            cu2 = *(const uint4*)(xbase + (size_t)s2 * D_EMB);
            cu3 = *(const uint4*)(xbase + (size_t)s3 * D_EMB);
        }
        int nidx = (ng > 1) ? ldidx(1) : 0;

        for (int g = 0; g < ng; g++) {
            // issue next group's row gathers + idx for group g+2 FIRST, so their
            // latency overlaps this group's compute.
            uint4 nu0, nu1, nu2, nu3;
            int nidx2 = 0;
            bool have_next = (g + 1 < ng);
            if (have_next) {
                int t0 = __shfl(nidx, 0), t1 = __shfl(nidx, 1),
                    t2 = __shfl(nidx, 2), t3 = __shfl(nidx, 3);
                nu0 = *(const uint4*)(xbase + (size_t)t0 * D_EMB);
                nu1 = *(const uint4*)(xbase + (size_t)t1 * D_EMB);
                nu2 = *(const uint4*)(xbase + (size_t)t2 * D_EMB);
                nu3 = *(const uint4*)(xbase + (size_t)t3 * D_EMB);
                if (g + 2 < ng) nidx2 = ldidx(g + 2);
            }

            // compute group g from registers loaded last iteration
            union { uint4 q; u16 us[8]; } u0, u1, u2, u3;
            u0.q = cu0; u1.q = cu1; u2.q = cu2; u3.q = cu3;
            float v0[8], v1[8], v2[8], v3[8];
            #pragma unroll
            for (int k = 0; k < 8; k++) {
                v0[k] = bf2f(u0.us[k]); v1[k] = bf2f(u1.us[k]);
                v2[k] = bf2f(u2.us[k]); v3[k] = bf2f(u3.us[k]);
            }
            float e0 = 0.f, e1 = 0.f, e2 = 0.f, e3 = 0.f;
            #pragma unroll
            for (int k = 0; k < 8; k++) {
                float t0 = v0[k] + xrv[k]; t0 = fmaxf(t0, 0.2f * t0); e0 += attv[k] * t0;
                float t1 = v1[k] + xrv[k]; t1 = fmaxf(t1, 0.2f * t1); e1 += attv[k] * t1;
                float t2 = v2[k] + xrv[k]; t2 = fmaxf(t2, 0.2f * t2); e2 += attv[k] * t2;
                float t3 = v3[k] + xrv[k]; t3 = fmaxf(t3, 0.2f * t3); e3 += attv[k] * t3;
            }
            #pragma unroll
            for (int o = 32; o > 0; o >>= 1) {
                e0 += __shfl_xor(e0, o);
                e1 += __shfl_xor(e1, o);
                e2 += __shfl_xor(e2, o);
                e3 += __shfl_xor(e3, o);
            }
            // mask padded (dead) edges of the final group
            int base = beg + 4 * g;
            if (base + 1 >= end) e1 = -3.4e38f;
            if (base + 2 >= end) e2 = -3.4e38f;
            if (base + 3 >= end) e3 = -3.4e38f;
            // group-batched online softmax: one rescale per 4 edges
            float m4 = fmaxf(fmaxf(e0, e1), fmaxf(e2, e3));
            float m_new = fmaxf(m_run, m4);
            float sc = __expf(m_run - m_new);          // 0 on first group
            float w0 = __expf(e0 - m_new), w1 = __expf(e1 - m_new);
            float w2 = __expf(e2 - m_new), w3 = __expf(e3 - m_new);
            s_run = s_run * sc + (w0 + w1) + (w2 + w3);
            #pragma unroll
            for (int k = 0; k < 8; k++)
                acc[k] = acc[k] * sc + w0 * v0[k] + w1 * v1[k] + w2 * v2[k] + w3 * v3[k];
            m_run = m_new;

            if (have_next) {
                cu0 = nu0; cu1 = nu1; cu2 = nu2; cu3 = nu3;
                nidx = nidx2;
            }
        }
    }

    float inv = 1.f / (s_run + 1e-16f);
    union { uint4 q; u16 us[8]; } ph;
    #pragma unroll
    for (int k = 0; k < 8; k++) {
        float h = tanhf(acc[k] * inv + inval(bias, fp32, d0 + k));
        ph.us[k] = f2bf(h);
    }
    *(uint4*)(&hh[(size_t)n * D_EMB + d0]) = ph.q;
}

// ---------------------------------------------------------------------------
__global__ __launch_bounds__(256)
void softmax_kernel(const float* __restrict__ logits, float* __restrict__ out)
{
    __shared__ float red[4];
    __shared__ float s_m, s_s;
    int tid = threadIdx.x, lane = tid & 63, wv = tid >> 6;
    float m = -3.4e38f;
    for (int i = tid; i < N_NODES; i += 256) m = fmaxf(m, logits[i]);
    #pragma unroll
    for (int o = 32; o > 0; o >>= 1) m = fmaxf(m, __shfl_down(m, o));
    if (lane == 0) red[wv] = m;
    __syncthreads();
    if (tid == 0) {
        float mm = red[0];
        for (int i = 1; i < 4; i++) mm = fmaxf(mm, red[i]);
        s_m = mm;
    }
    __syncthreads();
    float mm = s_m;
    float s = 0.f;
    for (int i = tid; i < N_NODES; i += 256) s += __expf(logits[i] - mm);
    #pragma unroll
    for (int o = 32; o > 0; o >>= 1) s += __shfl_down(s, o);
    if (lane == 0) red[wv] = s;
    __syncthreads();
    if (tid == 0) {
        float ss = 0.f;
        for (int i = 0; i < 4; i++) ss += red[i];
        s_s = ss;
    }
    __syncthreads();
    float invs = 1.f / s_s;
    for (int i = tid; i < N_NODES; i += 256) out[i] = __expf(logits[i] - mm) * invs;
}

// ---------------------------------------------------------------------------
extern "C" void kernel_launch(void* const* d_in, const int* in_sizes, int n_in,
                              void* d_out, int out_size, void* d_ws, size_t ws_size,
                              hipStream_t stream)
{
    const void* x   = d_in[0];
    const int*  ei  = (const int*)d_in[1];
    const void* Wl[3]  = {d_in[2],  d_in[6],  d_in[10]};
    const void* Wr[3]  = {d_in[3],  d_in[7],  d_in[11]};
    const void* att[3] = {d_in[4],  d_in[8],  d_in[12]};
    const void* bia[3] = {d_in[5],  d_in[9],  d_in[13]};
    const void* A1 = d_in[14];
    const void* c1 = d_in[15];
    const void* A2 = d_in[16];
    const void* c2 = d_in[17];
    const void* A3 = d_in[18];

    char* p = (char*)d_ws;
    auto alloc = [&](size_t bytes) {
        char* r = p;
        p += (bytes + 255) & ~(size_t)255;
        return r;
    };
    u16*   xlb    = (u16*)  alloc((size_t)N_NODES * D_EMB * 4);   // bf16 xl (first half) + MLP aliases
    u16*   xr     = (u16*)  alloc((size_t)N_NODES * D_EMB * 2);   // bf16 xr
    u16*   hh     = (u16*)  alloc((size_t)N_NODES * D_EMB * 2);
    int*   esrcp  = (int*)  alloc((size_t)N_EDGES * 4);
    int*   rowptr = (int*)  alloc((size_t)(N_NODES + 1) * 4);
    int*   counts = (int*)  alloc((size_t)N_NODES * 4);
    int*   flag   = (int*)  alloc(256);
    float* logits = (float*)alloc((size_t)N_NODES * 4);
    int*   doff   = (int*)  alloc(DMAX * 4);
    int*   order  = (int*)  alloc((size_t)N_NODES * 4);
    u16* wl1h = (u16*)alloc(D_EMB * D_IN  * 2);
    u16* wr1h = (u16*)alloc(D_EMB * D_IN  * 2);
    u16* wl2h = (u16*)alloc(D_EMB * D_EMB * 2);
    u16* wr2h = (u16*)alloc(D_EMB * D_EMB * 2);
    u16* wl3h = (u16*)alloc(D_EMB * D_EMB * 2);
    u16* wr3h = (u16*)alloc(D_EMB * D_EMB * 2);
    u16* a1h  = (u16*)alloc(D_EMB * D_HID * 2);
    u16* a2h  = (u16*)alloc(D_HID * D_HID * 2);
    u16* xph  = (u16*)alloc((size_t)N_NODES * D_IN * 2);
    size_t needed = (size_t)(p - (char*)d_ws);

    if (ws_size < needed) {
        sentinel_kernel<<<(out_size + 255) / 256, 256, 0, stream>>>((float*)d_out, out_size);
        return;
    }

    u16* m1h = (u16*)xlb;   // MLP hidden reuses xlb

    // 1) detect + zero counts/logits
    detect_zero_kernel<<<40, 256, 0, stream>>>(ei, (const u16*)x, flag, counts, logits);

    // 2) fused: count edges + preconvert everything to bf16 hi
    ConvJobs jobs;
    auto setjob = [&](int i, const void* s, u16* dh, int r, int c, int tr) {
        jobs.src[i] = s; jobs.dh[i] = dh;
        jobs.rows[i] = r; jobs.cols[i] = c; jobs.trans[i] = tr;
    };
    setjob(0, x,     xph,  N_NODES, D_IN, 0);
    setjob(1, Wl[0], wl1h, D_IN,  D_EMB, 1);
    setjob(2, Wr[0], wr1h, D_IN,  D_EMB, 1);
    setjob(3, Wl[1], wl2h, D_EMB, D_EMB, 1);
    setjob(4, Wr[1], wr2h, D_EMB, D_EMB, 1);
    setjob(5, Wl[2], wl3h, D_EMB, D_EMB, 1);
    setjob(6, Wr[2], wr3h, D_EMB, D_EMB, 1);
    setjob(7, A1,    a1h,  D_EMB, D_HID, 1);
    setjob(8, A2,    a2h,  D_HID, D_HID, 1);
    jobs.njobs = 9;
    jobs.cum[0] = 0;
    for (int i = 0; i < 9; i++) jobs.cum[i + 1] = jobs.cum[i] + jobs.rows[i] * jobs.cols[i];
    int ctotal = jobs.cum[9];
    int convblk = (ctotal + 255) / 256;
    count_convert_kernel<<<EBLK + convblk, 256, 0, stream>>>(ei, counts, jobs, flag);

    // 3) scan + degree hist + descending scan (single block)
    scan_counts_kernel<<<1, 256, 0, stream>>>(counts, rowptr, doff);

    // 4) fused: esrcp fill + LPT scatter
    int nblk = (N_NODES + 255) / 256;
    fill_scatter_kernel<<<nblk + EBLK, 256, 0, stream>>>(ei, flag, rowptr, counts, esrcp, doff, order);

    int gdual = (2 * D_EMB / 128) * ((N_NODES + 127) / 128);   // 8 * 79 = 632
    int gmlp  = (D_HID / 64) * ((N_NODES + 63) / 64);          // 4 * 157 = 628
    int gatgrid = (N_NODES + 3) / 4;

    // layer 1
    gemm_dual_kernel<<<gdual, 256, 0, stream>>>(xph, wl1h, wr1h, xlb, xr, N_NODES, D_EMB, D_IN);
    gat_wave_kernel<<<gatgrid, 256, 0, stream>>>(rowptr, esrcp, order, xlb, xr, att[0], bia[0], flag, hh);
    // layer 2
    gemm_dual_kernel<<<gdual, 256, 0, stream>>>(hh, wl2h, wr2h, xlb, xr, N_NODES, D_EMB, D_EMB);
    gat_wave_kernel<<<gatgrid, 256, 0, stream>>>(rowptr, esrcp, order, xlb, xr, att[1], bia[1], flag, hh);
    // layer 3
    gemm_dual_kernel<<<gdual, 256, 0, stream>>>(hh, wl3h, wr3h, xlb, xr, N_NODES, D_EMB, D_EMB);
    gat_wave_kernel<<<gatgrid, 256, 0, stream>>>(rowptr, esrcp, order, xlb, xr, att[2], bia[2], flag, hh);

    // MLP: GEMM1 stores hi; GEMM2 fuses the A3 logit GEMV via atomics
    gemm_mlp64_kernel<0><<<gmlp, 256, 0, stream>>>(hh, a1h, m1h, c1, nullptr, nullptr, flag, N_NODES, D_HID, D_EMB);
    gemm_mlp64_kernel<1><<<gmlp, 256, 0, stream>>>(m1h, a2h, nullptr, c2, A3, logits, flag, N_NODES, D_HID, D_HID);
    softmax_kernel<<<1, 256, 0, stream>>>(logits, (float*)d_out);
}